// Round 1
// 234.275 us; speedup vs baseline: 1.4079x; 1.4079x over previous
//
#include <hip/hip_runtime.h>
#include <hip/hip_bf16.h>

// Problem constants
#define BQ    2
#define LQ    2048
#define DMQ   1024
#define HQ    4
#define DHQ   128
#define TOTQ  512
#define BLQ   4096      // B*L
#define NPROJ 2688      // padded concat: Wq(512) Wk(512) Wv(1024) Wg(512) Wa(4) Wb(4) pad(120)
#define KPROJ 1024
#define CT    64        // scan chunk length
#define NCH   32        // chunks (LQ/CT)

typedef short bf16x8 __attribute__((ext_vector_type(8)));
typedef short s16x4  __attribute__((ext_vector_type(4)));
typedef float f32x4  __attribute__((ext_vector_type(4)));

#define MFMA16(a, b, c) __builtin_amdgcn_mfma_f32_16x16x32_bf16(a, b, c, 0, 0, 0)

__device__ __forceinline__ float siluf(float x) { return x / (1.f + __expf(-x)); }
__device__ __forceinline__ float sigf(float x)  { return 1.f / (1.f + __expf(-x)); }
__device__ __forceinline__ short bf16s(float x) {
  return __builtin_bit_cast(short, __float2bfloat16(x));
}
__device__ __forceinline__ bf16x8 pack8(f32x4 a, f32x4 b) {
  bf16x8 r;
  r[0] = bf16s(a.x); r[1] = bf16s(a.y); r[2] = bf16s(a.z); r[3] = bf16s(a.w);
  r[4] = bf16s(b.x); r[5] = bf16s(b.y); r[6] = bf16s(b.z); r[7] = bf16s(b.w);
  return r;
}

// global -> LDS direct load, 16B per lane. LDS dest must be wave-uniform base;
// HW writes base + lane*16.
__device__ __forceinline__ void gload_lds16(const void* g, void* l) {
  __builtin_amdgcn_global_load_lds(
      (__attribute__((address_space(1))) void*)(unsigned long long)g,
      (__attribute__((address_space(3))) void*)(unsigned int)(unsigned long long)l,
      16, 0, 0);
}

// ---------------- casts ----------------
__global__ __launch_bounds__(256)
void cast_f32_bf16_kernel(const float* __restrict__ src, __hip_bfloat16* __restrict__ dst, int n4)
{
  int i = blockIdx.x * 256 + threadIdx.x;
  if (i < n4) {
    float4 v = ((const float4*)src)[i];
    __hip_bfloat16 o[4] = { __float2bfloat16(v.x), __float2bfloat16(v.y),
                            __float2bfloat16(v.z), __float2bfloat16(v.w) };
    *(ushort4*)((unsigned short*)dst + (size_t)i * 4) = *(ushort4*)o;
  }
}

__global__ __launch_bounds__(256)
void cast_wcat_kernel(const float* __restrict__ Wq, const float* __restrict__ Wk,
                      const float* __restrict__ Wv, const float* __restrict__ Wg,
                      const float* __restrict__ Wa, const float* __restrict__ Wb,
                      __hip_bfloat16* __restrict__ Wcat)
{
  int idx = blockIdx.x * 256 + threadIdx.x;      // 0 .. 2688*1024-1
  int row = idx >> 10, col = idx & 1023;
  float v;
  if      (row < 512)  v = Wq[idx];
  else if (row < 1024) v = Wk[idx - 512 * 1024];
  else if (row < 2048) v = Wv[idx - 1024 * 1024];
  else if (row < 2560) v = Wg[idx - 2048 * 1024];
  else if (row < 2564) v = Wa[(row - 2560) * 1024 + col];
  else if (row < 2568) v = Wb[(row - 2564) * 1024 + col];
  else                 v = 0.f;
  Wcat[idx] = __float2bfloat16(v);
}

// ---------------- bf16 MFMA GEMM: C(f32, MxN) = A(M,K) * B(N,K)^T ----------------
__global__ __launch_bounds__(256)
void gemm_bt_kernel(const __hip_bfloat16* __restrict__ A,
                    const __hip_bfloat16* __restrict__ Bw,
                    float* __restrict__ C, int M, int N, int K)
{
  __shared__ __hip_bfloat16 As[128 * 32];
  __shared__ __hip_bfloat16 Bs[128 * 32];
  const int tid  = threadIdx.x;
  const int lane = tid & 63;
  const int w    = tid >> 6;
  const int wm   = w >> 1, wn = w & 1;
  const int tm   = blockIdx.x, tn = blockIdx.y;
  const int lr   = lane & 15, lk = lane >> 4;

  f32x4 acc[4][4] = {};

  const int e0   = tid * 8;
  const int srow = e0 >> 5;        // 0..63
  const int scol = e0 & 31;
  const __hip_bfloat16* Ap = A  + (size_t)(tm * 128 + srow) * K + scol;
  const __hip_bfloat16* Bp = Bw + (size_t)(tn * 128 + srow) * K + scol;
  char* AsB  = (char*)As;
  char* BsB  = (char*)Bs;
  char* AsD0 = AsB + w * 1024;
  char* BsD0 = BsB + w * 1024;
  const size_t half = (size_t)64 * K;

  for (int kk = 0; kk < K; kk += 32) {
    __syncthreads();
    gload_lds16(Ap + kk,        AsD0);
    gload_lds16(Ap + half + kk, AsD0 + 4096);
    gload_lds16(Bp + kk,        BsD0);
    gload_lds16(Bp + half + kk, BsD0 + 4096);
    __syncthreads();
    bf16x8 af[4], bfv[4];
#pragma unroll
    for (int m = 0; m < 4; ++m)
      af[m]  = *(const bf16x8*)(AsB + ((wm * 64 + m * 16 + lr) * 32 + lk * 8) * 2);
#pragma unroll
    for (int n = 0; n < 4; ++n)
      bfv[n] = *(const bf16x8*)(BsB + ((wn * 64 + n * 16 + lr) * 32 + lk * 8) * 2);
#pragma unroll
    for (int m = 0; m < 4; ++m)
#pragma unroll
      for (int n = 0; n < 4; ++n)
        acc[m][n] = MFMA16(af[m], bfv[n], acc[m][n]);
  }

  const int crow0 = tm * 128 + wm * 64 + (lane >> 4) * 4;
  const int ccol0 = tn * 128 + wn * 64 + lr;
#pragma unroll
  for (int m = 0; m < 4; ++m)
#pragma unroll
    for (int n = 0; n < 4; ++n)
#pragma unroll
      for (int j = 0; j < 4; ++j)
        C[(size_t)(crow0 + m * 16 + j) * N + ccol0 + n * 16] = acc[m][n][j];
}

// ---------------- conv(4-tap causal) + silu + l2norm + sigmoid(a,b) ----------------
__global__ __launch_bounds__(256)
void conv_act_kernel(const float* __restrict__ C,
                     const float* __restrict__ qcw, const float* __restrict__ qcb,
                     const float* __restrict__ kcw, const float* __restrict__ kcb,
                     const float* __restrict__ vcw, const float* __restrict__ vcb,
                     float* __restrict__ qh, float* __restrict__ kh,
                     float* __restrict__ vm, float* __restrict__ vg,
                     float* __restrict__ al, float* __restrict__ be)
{
  const int bl  = blockIdx.x;
  const int t   = bl & (LQ - 1);
  const int tid = threadIdx.x;
  const float* Crow = C + (size_t)bl * NPROJ;
  __shared__ float red[8];

  float qv[2], kv[2];
  float sq = 0.f, sk = 0.f;
#pragma unroll
  for (int i = 0; i < 2; ++i) {
    const int c = tid + i * 256;
    float accq = qcb[c];
    float acck = kcb[c];
    const float4 wq = *(const float4*)(qcw + 4 * c);
    const float4 wk = *(const float4*)(kcw + 4 * c);
#pragma unroll
    for (int j = 0; j < 4; ++j) {
      const int tt = t - 3 + j;
      if (tt >= 0) {
        const float* Cr = Crow + (size_t)(j - 3) * NPROJ;
        accq = fmaf(((const float*)&wq)[j], Cr[c],       accq);
        acck = fmaf(((const float*)&wk)[j], Cr[512 + c], acck);
      }
    }
    qv[i] = siluf(accq); sq = fmaf(qv[i], qv[i], sq);
    kv[i] = siluf(acck); sk = fmaf(kv[i], kv[i], sk);
  }
  float2 pr = make_float2(sq, sk);
#pragma unroll
  for (int m = 1; m < 64; m <<= 1) { pr.x += __shfl_xor(pr.x, m); pr.y += __shfl_xor(pr.y, m); }
  if ((tid & 63) == 0) { red[(tid >> 6) * 2] = pr.x; red[(tid >> 6) * 2 + 1] = pr.y; }
  __syncthreads();
  const float SQ = red[0] + red[2] + red[4] + red[6];
  const float SK = red[1] + red[3] + red[5] + red[7];
  const float rnq = 1.f / fmaxf(sqrtf(SQ), 1e-12f);
  const float rnk = 1.f / fmaxf(sqrtf(SK), 1e-12f);
#pragma unroll
  for (int i = 0; i < 2; ++i) {
    const int c = tid + i * 256;
    qh[(size_t)bl * 512 + c] = qv[i] * rnq;
    kh[(size_t)bl * 512 + c] = kv[i] * rnk;
  }
#pragma unroll
  for (int i = 0; i < 4; ++i) {
    const int c = tid + i * 256;
    float accv = vcb[c];
    const float4 wv = *(const float4*)(vcw + 4 * c);
#pragma unroll
    for (int j = 0; j < 4; ++j) {
      const int tt = t - 3 + j;
      if (tt >= 0)
        accv = fmaf(((const float*)&wv)[j], Crow[(size_t)(j - 3) * NPROJ + 1024 + c], accv);
    }
    const float vvv = siluf(accv);
    if (c < 512) vm[(size_t)bl * 512 + c]         = vvv;
    else         vg[(size_t)bl * 512 + (c - 512)] = vvv;
  }
  if (tid < 4)       al[(size_t)bl * 4 + tid]       = sigf(Crow[2560 + tid]);
  else if (tid < 8)  be[(size_t)bl * 4 + (tid - 4)] = sigf(Crow[2564 + (tid - 4)]);
}

// ---------------- scan phase A: per-chunk WY decomposition ----------------
// 256 blocks = 32 chunks x 8 (b,h). Computes per chunk:
//   d_t = cumsum log a;  G = K K^T, Pq = Q K^T (MFMA bf16)
//   L_{ts} = b_t e^{d_t-d_s} G_{ts} (t>s)
//   solve (I+L)[W~|Z] = [diag(b e^d) K | diag(b) V]  (f32 fwd substitution)
//   store W~ (bf16), Z (bf16), Phat = tril(Pq o e^{d_t-d_s}) (bf16),
//         KT = K^T (bf16), gamma_t = e^{d_t}, gc = e^{d_63}
//   NEW: also store f-scaled transposes for the transition kernel:
//         WTF(m,s) = f_s W~(s,m), ZF(i,s) = f_s Z(s,i), f_s = e^{d_63-d_s}
__global__ __launch_bounds__(256)
void scan_phaseA_kernel(const float* __restrict__ qh, const float* __restrict__ kh,
                        const float* __restrict__ vm, const float* __restrict__ al,
                        const float* __restrict__ be,
                        short* __restrict__ WTB, short* __restrict__ ZB,
                        short* __restrict__ PHB, short* __restrict__ KTB,
                        float* __restrict__ GV, float* __restrict__ GC,
                        short* __restrict__ WTFB, short* __restrict__ ZFB)
{
  __shared__ char sm[53248];
  __hip_bfloat16* KBl = (__hip_bfloat16*)(sm);          // [64][136]
  __hip_bfloat16* QBl = (__hip_bfloat16*)(sm + 17408);  // [64][136]
  float* Ll  = (float*)(sm + 34816);                    // [64][68]
  float* dv  = (float*)(sm + 52224);                    // [64]
  float* bv  = (float*)(sm + 52480);                    // [64]
  float* gbv = (float*)(sm + 52736);                    // [64]
  float* fvs = (float*)(sm + 52992);                    // [64]

  const int cb = blockIdx.x;
  const int bh = cb & 7, c = cb >> 3;
  const int b = bh >> 2, h = bh & 3;
  const int tid = threadIdx.x;
  const int lane = tid & 63;
  const int w = tid >> 6;
  const int lr = lane & 15, lk = lane >> 4;
  const size_t rowbase = (size_t)(b * LQ + c * CT) * 512 + h * 128;

  // stage K,Q -> LDS bf16 (padded rows of 136)
#pragma unroll
  for (int rep = 0; rep < 4; ++rep) {
    const int fid = tid + rep * 256;       // 0..1023
    const int r = fid >> 4;
    const int cg = (fid & 15) * 8;
    const float* kp = kh + rowbase + (size_t)r * 512 + cg;
    const float* qp = qh + rowbase + (size_t)r * 512 + cg;
    f32x4 k0 = *(const f32x4*)kp, k1 = *(const f32x4*)(kp + 4);
    f32x4 q0 = *(const f32x4*)qp, q1 = *(const f32x4*)(qp + 4);
    *(bf16x8*)(KBl + r * 136 + cg) = pack8(k0, k1);
    *(bf16x8*)(QBl + r * 136 + cg) = pack8(q0, q1);
  }
  // decay prefix (wave 0)
  if (w == 0) {
    float la = __logf(al[(size_t)(b * LQ + c * CT + lane) * 4 + h]);
    const float bb = be[(size_t)(b * LQ + c * CT + lane) * 4 + h];
#pragma unroll
    for (int off = 1; off < 64; off <<= 1) {
      const float tv = __shfl_up(la, off, 64);
      if (lane >= off) la += tv;
    }
    const float d63 = __shfl(la, 63, 64);
    dv[lane] = la; bv[lane] = bb; gbv[lane] = bb * __expf(la);
    fvs[lane] = __expf(d63 - la);
    GV[cb * 64 + lane] = __expf(la);
    if (lane == 0) GC[cb] = __expf(d63);
  }
  __syncthreads();

  // G = K K^T, Pq = Q K^T  (each wave owns one 16-row t-band)
  f32x4 aG[4] = {}, aP[4] = {};
#pragma unroll
  for (int ks = 0; ks < 4; ++ks) {
    bf16x8 bk[4];
#pragma unroll
    for (int nt = 0; nt < 4; ++nt)
      bk[nt] = *(const bf16x8*)(KBl + (nt * 16 + lr) * 136 + ks * 32 + lk * 8);
    const bf16x8 ak = *(const bf16x8*)(KBl + (w * 16 + lr) * 136 + ks * 32 + lk * 8);
    const bf16x8 aq = *(const bf16x8*)(QBl + (w * 16 + lr) * 136 + ks * 32 + lk * 8);
#pragma unroll
    for (int nt = 0; nt < 4; ++nt) {
      aG[nt] = MFMA16(ak, bk[nt], aG[nt]);
      aP[nt] = MFMA16(aq, bk[nt], aP[nt]);
    }
  }
#pragma unroll
  for (int nt = 0; nt < 4; ++nt)
#pragma unroll
    for (int jj = 0; jj < 4; ++jj) {
      const int t = w * 16 + lk * 4 + jj;
      const int s = nt * 16 + lr;
      const float eg = __expf(dv[t] - dv[s]);
      Ll[t * 68 + s] = (t > s) ? bv[t] * eg * aG[nt][jj] : 0.f;
      PHB[(size_t)cb * 4096 + t * 64 + s] = (s <= t) ? bf16s(eg * aP[nt][jj]) : (short)0;
    }
  __syncthreads();

  // forward substitution, thread j owns column j of X (64 regs)
  float x[64];
  const int j = tid;
  const float* src = (j < 128) ? kh : vm;
  const float* xp = src + rowbase + (j & 127);
#pragma unroll
  for (int t = 0; t < 64; ++t) x[t] = xp[(size_t)t * 512];
#pragma unroll
  for (int t = 0; t < 64; ++t) x[t] *= (j < 128) ? gbv[t] : bv[t];
#pragma unroll
  for (int t = 1; t < 64; ++t) {
    f32x4 acc = {};
#pragma unroll
    for (int s4 = 0; s4 < 16; ++s4) {
      if (s4 * 4 < t) {   // rows above diagonal are zero in Ll -> safe
        const f32x4 lv = *(const f32x4*)(Ll + t * 68 + s4 * 4);
        acc.x = fmaf(lv.x, x[s4 * 4 + 0], acc.x);
        acc.y = fmaf(lv.y, x[s4 * 4 + 1], acc.y);
        acc.z = fmaf(lv.z, x[s4 * 4 + 2], acc.z);
        acc.w = fmaf(lv.w, x[s4 * 4 + 3], acc.w);
      }
    }
    x[t] -= (acc.x + acc.y) + (acc.z + acc.w);
  }
  // store W~ / Z (bf16, coalesced 2B per lane)
#pragma unroll
  for (int t = 0; t < 64; ++t) {
    const short hv = bf16s(x[t]);
    if (j < 128) WTB[(size_t)cb * 8192 + t * 128 + j] = hv;
    else         ZB [(size_t)cb * 8192 + t * 128 + (j - 128)] = hv;
  }
  // NEW: f-scaled transposed stores (thread j owns one row of WTF / ZF)
  {
    short* dstT = (j < 128) ? (WTFB + (size_t)cb * 8192 + (size_t)j * 64)
                            : (ZFB  + (size_t)cb * 8192 + (size_t)(j - 128) * 64);
#pragma unroll
    for (int s4 = 0; s4 < 16; ++s4) {
      s16x4 p;
#pragma unroll
      for (int e = 0; e < 4; ++e)
        p[e] = bf16s(fvs[s4 * 4 + e] * x[s4 * 4 + e]);
      *(s16x4*)(dstT + s4 * 4) = p;
    }
  }
  // KT = K^T (128 x 64 bf16)
  if (tid < 128) {
    const float* kp2 = kh + rowbase + tid;
#pragma unroll
    for (int s4 = 0; s4 < 16; ++s4) {
      s16x4 pk;
#pragma unroll
      for (int e = 0; e < 4; ++e)
        pk[e] = bf16s(kp2[(size_t)(s4 * 4 + e) * 512]);
      *(s16x4*)(KTB + (size_t)cb * 8192 + tid * 64 + s4 * 4) = pk;
    }
  }
}

// ---------------- scan transition: per-chunk affine factors ----------------
// S_{c+1} = S_c T_c + B_c  (rows of S evolve independently)
//   A(m,j)  = sum_s f_s W~(s,m) K(s,j);   T(m,j) = gc d(m,j) - A(m,j)
//   B(i,j)  = sum_s f_s Z(s,i)  K(s,j)
// Stored: TRB[cb][j][m] = T(m,j) (bf16, transposed for MFMA B-operand),
//         BF[cb][i][j] (f32).
// 256 blocks (one per cb), 4 waves; wave w owns a 32-row output band.
__global__ __launch_bounds__(256)
void scan_transition_kernel(const short* __restrict__ WTFB, const short* __restrict__ ZFB,
                            const short* __restrict__ KTB, const float* __restrict__ GC,
                            short* __restrict__ TRB, float* __restrict__ BF)
{
  const int cb = blockIdx.x;
  const int tid = threadIdx.x, lane = tid & 63, w = tid >> 6;
  const int lr = lane & 15, lk = lane >> 4;
  const float gc = GC[cb];

  // ---- AT(j,m) = sum_s KT(j,s) * WTF(m,s) ; then T^T(j,m) = gc d - AT(j,m)
  {
    f32x4 acc[2][8] = {};
#pragma unroll
    for (int ks = 0; ks < 2; ++ks) {
      bf16x8 a0 = *(const bf16x8*)(KTB + (size_t)cb * 8192 + (w * 32 + lr) * 64 + ks * 32 + lk * 8);
      bf16x8 a1 = *(const bf16x8*)(KTB + (size_t)cb * 8192 + (w * 32 + 16 + lr) * 64 + ks * 32 + lk * 8);
#pragma unroll
      for (int nt = 0; nt < 8; ++nt) {
        const bf16x8 bm = *(const bf16x8*)(WTFB + (size_t)cb * 8192 + (nt * 16 + lr) * 64 + ks * 32 + lk * 8);
        acc[0][nt] = MFMA16(a0, bm, acc[0][nt]);
        acc[1][nt] = MFMA16(a1, bm, acc[1][nt]);
      }
    }
#pragma unroll
    for (int mt = 0; mt < 2; ++mt)
#pragma unroll
      for (int nt = 0; nt < 8; ++nt)
#pragma unroll
        for (int jj = 0; jj < 4; ++jj) {
          const int jr = w * 32 + mt * 16 + lk * 4 + jj;
          const int m  = nt * 16 + lr;
          const float v = ((jr == m) ? gc : 0.f) - acc[mt][nt][jj];
          TRB[(size_t)cb * 16384 + jr * 128 + m] = bf16s(v);
        }
  }
  // ---- B(i,j) = sum_s ZF(i,s) * KT(j,s)
  {
    f32x4 acc[2][8] = {};
#pragma unroll
    for (int ks = 0; ks < 2; ++ks) {
      bf16x8 a0 = *(const bf16x8*)(ZFB + (size_t)cb * 8192 + (w * 32 + lr) * 64 + ks * 32 + lk * 8);
      bf16x8 a1 = *(const bf16x8*)(ZFB + (size_t)cb * 8192 + (w * 32 + 16 + lr) * 64 + ks * 32 + lk * 8);
#pragma unroll
      for (int nt = 0; nt < 8; ++nt) {
        const bf16x8 bj = *(const bf16x8*)(KTB + (size_t)cb * 8192 + (nt * 16 + lr) * 64 + ks * 32 + lk * 8);
        acc[0][nt] = MFMA16(a0, bj, acc[0][nt]);
        acc[1][nt] = MFMA16(a1, bj, acc[1][nt]);
      }
    }
#pragma unroll
    for (int mt = 0; mt < 2; ++mt)
#pragma unroll
      for (int nt = 0; nt < 8; ++nt)
#pragma unroll
        for (int jj = 0; jj < 4; ++jj) {
          const int ir = w * 32 + mt * 16 + lk * 4 + jj;
          const int jc = nt * 16 + lr;
          BF[(size_t)cb * 16384 + ir * 128 + jc] = acc[mt][nt][jj];
        }
  }
}

// ---------------- scan state: serial chunk recurrence, S rows independent ----
// 64 blocks = 8 (b,h) x 8 row-slabs of 16 (bid: bh = bid&7 so all slabs of a
// head share an XCD's L2 for the TT stream). Per chunk: store S_c (bf16) to
// SALL, S <- S*T + B with register-double-buffered prefetch of T_{c+1}/B_{c+1}.
#define L2_PREFETCH(BT, BA, CC) do {                                               \
  const int cbn_ = (CC) * 8 + bh;                                                  \
  _Pragma("unroll") for (int nt = 0; nt < 2; ++nt) {                               \
    _Pragma("unroll") for (int ks = 0; ks < 4; ++ks)                               \
      BT[nt][ks] = *(const bf16x8*)(TRB + (size_t)cbn_ * 16384 +                   \
                                    (w * 32 + nt * 16 + lr) * 128 + ks * 32 + lk * 8); \
    _Pragma("unroll") for (int jj = 0; jj < 4; ++jj)                               \
      BA[nt][jj] = BF[(size_t)cbn_ * 16384 + (r0 + lk * 4 + jj) * 128 +            \
                      w * 32 + nt * 16 + lr];                                      \
  }                                                                                \
} while (0)

#define L2_STEP(BT, BA, CC, PBT, PBA) do {                                         \
  const int cb_ = (CC) * 8 + bh;                                                   \
  { const int idx = tid * 8, r = idx >> 7, jc = idx & 127;                         \
    f32x4 s0 = *(const f32x4*)&Scur[r * 132 + jc];                                 \
    f32x4 s1 = *(const f32x4*)&Scur[r * 132 + jc + 4];                             \
    *(bf16x8*)(SALL + (size_t)cb_ * 16384 + (r0 + r) * 128 + jc) = pack8(s0, s1); }\
  bf16x8 af[4];                                                                    \
  _Pragma("unroll") for (int ks = 0; ks < 4; ++ks)                                 \
    af[ks] = pack8(*(const f32x4*)&Scur[lr * 132 + ks * 32 + lk * 8],              \
                   *(const f32x4*)&Scur[lr * 132 + ks * 32 + lk * 8 + 4]);         \
  if ((CC) < 31) L2_PREFETCH(PBT, PBA, (CC) + 1);                                  \
  f32x4 acc0 = {}, acc1 = {};                                                      \
  _Pragma("unroll") for (int ks = 0; ks < 4; ++ks) {                               \
    acc0 = MFMA16(af[ks], BT[0][ks], acc0);                                        \
    acc1 = MFMA16(af[ks], BT[1][ks], acc1);                                        \
  }                                                                                \
  _Pragma("unroll") for (int jj = 0; jj < 4; ++jj) {                               \
    Snxt[(lk * 4 + jj) * 132 + w * 32 + lr]      = acc0[jj] + BA[0][jj];           \
    Snxt[(lk * 4 + jj) * 132 + w * 32 + 16 + lr] = acc1[jj] + BA[1][jj];           \
  }                                                                                \
  __syncthreads();                                                                 \
  { float* t_ = Scur; Scur = Snxt; Snxt = t_; }                                    \
} while (0)

__global__ __launch_bounds__(256)
void scan_state_kernel(const short* __restrict__ TRB, const float* __restrict__ BF,
                       const float* __restrict__ st0, short* __restrict__ SALL,
                       float* __restrict__ stout)
{
  __shared__ float Sl[2 * 16 * 132];
  const int bid = blockIdx.x;            // 64
  const int bh = bid & 7, slab = bid >> 3;
  const int r0 = slab * 16;
  const int tid = threadIdx.x, lane = tid & 63, w = tid >> 6;
  const int lr = lane & 15, lk = lane >> 4;

  float* Scur = Sl;
  float* Snxt = Sl + 16 * 132;

  // load st0 slab
  {
    const int idx = tid * 8, r = idx >> 7, jc = idx & 127;
    const float* sp = st0 + ((size_t)bh * 128 + r0 + r) * 128 + jc;
    *(f32x4*)&Scur[r * 132 + jc]     = *(const f32x4*)sp;
    *(f32x4*)&Scur[r * 132 + jc + 4] = *(const f32x4*)(sp + 4);
  }
  bf16x8 btA[2][4], btB[2][4];
  float  baA[2][4], baB[2][4];
  L2_PREFETCH(btA, baA, 0);
  __syncthreads();

  for (int c2 = 0; c2 < 16; ++c2) {
    L2_STEP(btA, baA, 2 * c2,     btB, baB);
    L2_STEP(btB, baB, 2 * c2 + 1, btA, baA);
  }

  // final state (Scur holds S_32 after 32 swaps)
  {
    const int idx = tid * 8, r = idx >> 7, jc = idx & 127;
    float* sp = stout + ((size_t)bh * 128 + r0 + r) * 128 + jc;
    *(f32x4*)sp       = *(const f32x4*)&Scur[r * 132 + jc];
    *(f32x4*)(sp + 4) = *(const f32x4*)&Scur[r * 132 + jc + 4];
  }
}

// ---------------- scan output: fully parallel over chunks ----------------
// 256 blocks (cb) x 512 threads (8 waves). waves 0-3: Y_up = Q S_c^T rows,
// waves 4-7: Y_low = W~ S_c^T rows -> U = Z - Y_low -> Ut (LDS); barrier;
// waves 0-3: O = diag(gv) Y_up + Phat U.
__global__ __launch_bounds__(512)
void scan_output_kernel(const float* __restrict__ qh,
                        const short* __restrict__ WTB, const __hip_bfloat16* __restrict__ ZB,
                        const short* __restrict__ PHB, const float* __restrict__ GV,
                        const short* __restrict__ SALL, float* __restrict__ obuf)
{
  __shared__ short Ut[128 * 72];
  const int cb = blockIdx.x;
  const int bh = cb & 7, c = cb >> 3;
  const int b = bh >> 2, h = bh & 3;
  const int tid = threadIdx.x, lane = tid & 63, w = tid >> 6;   // w 0..7
  const int lr = lane & 15, lk = lane >> 4;
  const int r0 = (w & 3) * 16;

  f32x4 Y[8] = {};
#pragma unroll
  for (int ks = 0; ks < 4; ++ks) {
    bf16x8 af;
    if (w < 4) {
      const float* qp = qh + ((size_t)(b * LQ + c * CT) + r0 + lr) * 512 + h * 128 + ks * 32 + lk * 8;
      af = pack8(*(const f32x4*)qp, *(const f32x4*)(qp + 4));
    } else {
      af = *(const bf16x8*)(WTB + (size_t)cb * 8192 + (r0 + lr) * 128 + ks * 32 + lk * 8);
    }
#pragma unroll
    for (int nt = 0; nt < 8; ++nt) {
      const bf16x8 bs = *(const bf16x8*)(SALL + (size_t)cb * 16384 + (nt * 16 + lr) * 128 + ks * 32 + lk * 8);
      Y[nt] = MFMA16(af, bs, Y[nt]);
    }
  }
  if (w >= 4) {   // U = Z - Y_low -> LDS (Ut[i][s])
#pragma unroll
    for (int nt = 0; nt < 8; ++nt) {
      const int i = nt * 16 + lr;
      s16x4 up;
#pragma unroll
      for (int jj = 0; jj < 4; ++jj) {
        const int s = r0 + lk * 4 + jj;
        const float z = __bfloat162float(ZB[(size_t)cb * 8192 + s * 128 + i]);
        up[jj] = bf16s(z - Y[nt][jj]);
      }
      *(s16x4*)&Ut[i * 72 + r0 + lk * 4] = up;
    }
  }
  __syncthreads();
  if (w < 4) {
    f32x4 P2[8] = {};
#pragma unroll
    for (int ks = 0; ks < 2; ++ks) {
      const bf16x8 ap = *(const bf16x8*)(PHB + (size_t)cb * 4096 + (r0 + lr) * 64 + ks * 32 + lk * 8);
#pragma unroll
      for (int nt = 0; nt < 8; ++nt) {
        const bf16x8 bu = *(const bf16x8*)&Ut[(nt * 16 + lr) * 72 + ks * 32 + lk * 8];
        P2[nt] = MFMA16(ap, bu, P2[nt]);
      }
    }
    float gvv[4];
#pragma unroll
    for (int jj = 0; jj < 4; ++jj) gvv[jj] = GV[cb * 64 + r0 + lk * 4 + jj];
#pragma unroll
    for (int nt = 0; nt < 8; ++nt) {
      const int i = nt * 16 + lr;
#pragma unroll
      for (int jj = 0; jj < 4; ++jj) {
        const int t = r0 + lk * 4 + jj;
        obuf[((size_t)(b * LQ + c * CT) + t) * 512 + h * 128 + i] =
            gvv[jj] * Y[nt][jj] + P2[nt][jj];
      }
    }
  }
}

// ---------------- gate * silu(g), LayerNorm(512), cast bf16 ----------------
__global__ __launch_bounds__(256)
void gate_ln_kernel(const float* __restrict__ obuf, const float* __restrict__ vg,
                    const float* __restrict__ C, const float* __restrict__ lnw,
                    const float* __restrict__ lnb, __hip_bfloat16* __restrict__ lno)
{
  const int bl = blockIdx.x, tid = threadIdx.x;
  __shared__ float red[8];
  float y[2]; float s = 0.f, s2 = 0.f;
#pragma unroll
  for (int i = 0; i < 2; ++i) {
    const int c = tid + i * 256;
    const float g = C[(size_t)bl * NPROJ + 2048 + c];
    const float v = obuf[(size_t)bl * 512 + c] * vg[(size_t)bl * 512 + c] * siluf(g);
    y[i] = v; s += v; s2 = fmaf(v, v, s2);
  }
  float2 pr = make_float2(s, s2);
#pragma unroll
  for (int m = 1; m < 64; m <<= 1) { pr.x += __shfl_xor(pr.x, m); pr.y += __shfl_xor(pr.y, m); }
  if ((tid & 63) == 0) { red[(tid >> 6) * 2] = pr.x; red[(tid >> 6) * 2 + 1] = pr.y; }
  __syncthreads();
  const float S  = red[0] + red[2] + red[4] + red[6];
  const float S2 = red[1] + red[3] + red[5] + red[7];
  const float mu  = S * (1.f / 512.f);
  const float var = S2 * (1.f / 512.f) - mu * mu;
  const float rs  = rsqrtf(var + 1e-5f);
#pragma unroll
  for (int i = 0; i < 2; ++i) {
    const int c = tid + i * 256;
    lno[(size_t)bl * 512 + c] = __float2bfloat16(fmaf((y[i] - mu) * rs, lnw[c], lnb[c]));
  }
}

extern "C" void kernel_launch(void* const* d_in, const int* in_sizes, int n_in,
                              void* d_out, int out_size, void* d_ws, size_t ws_size,
                              hipStream_t stream)
{
  (void)in_sizes; (void)n_in; (void)out_size; (void)ws_size;
  const float* x    = (const float*)d_in[0];
  const float* st0  = (const float*)d_in[1];
  const float* Wq   = (const float*)d_in[2];
  const float* Wk   = (const float*)d_in[3];
  const float* Wv   = (const float*)d_in[4];
  const float* Wa   = (const float*)d_in[5];
  const float* Wb   = (const float*)d_in[6];
  const float* Wg   = (const float*)d_in[7];
  const float* Wo   = (const float*)d_in[8];
  const float* qcw  = (const float*)d_in[9];
  const float* qcb  = (const float*)d_in[10];
  const float* kcw  = (const float*)d_in[11];
  const float* kcb  = (const float*)d_in[12];
  const float* vcw  = (const float*)d_in[13];
  const float* vcb  = (const float*)d_in[14];
  const float* lnw  = (const float*)d_in[15];
  const float* lnb  = (const float*)d_in[16];
  float* out = (float*)d_out;

  // workspace layout (bytes); high-water ~124.3 MB
  char* ws = (char*)d_ws;
  __hip_bfloat16* XB   = (__hip_bfloat16*)(ws + 0);            // 4096x1024 bf16 (dead after proj GEMM)
  __hip_bfloat16* LNO  = (__hip_bfloat16*)(ws + 0);            // 4096x512 bf16 (aliases XB 1st half, written at gate_ln)
  short*          WTFB = (short*)(ws + 0);                     // [256][128][64] bf16 (aliases XB 1st half; phaseA->transition window)
  short*          WTB  = (short*)(ws + 4194304);               // [256][64][128] bf16 (aliases XB 2nd half)
  __hip_bfloat16* WCAT = (__hip_bfloat16*)(ws + 8388608);      // 2688x1024 bf16
  __hip_bfloat16* WOB  = (__hip_bfloat16*)(ws + 13893632);     // 1024x512  bf16
  float* CBUF = (float*)(ws + 14942208);                       // 4096x2688 f32
  float* QH   = (float*)(ws + 58982400);                       // 4096x512
  float* KH   = (float*)(ws + 67371008);
  float* BF   = (float*)(ws + 67371008);                       // [256][128][128] f32 (aliases KH+VM; written after phaseA)
  float* VM   = (float*)(ws + 75759616);
  float* VG   = (float*)(ws + 84148224);
  float* AL   = (float*)(ws + 92536832);                       // 4096x4
  float* BE   = (float*)(ws + 92602368);
  float* OBUF = (float*)(ws + 92667904);                       // 4096x512 (written by scan_output)
  short* TRB  = (short*)(ws + 92667904);                       // [256][128][128] bf16 (aliases OBUF; dead before scan_output)
  short* KTB  = (short*)(ws + 101056512);                      // [256][128][64] bf16
  short* PHB  = (short*)(ws + 105250816);                      // [256][64][64] bf16
  short* ZB   = (short*)(ws + 107347968);                      // [256][64][128] bf16
  float* GV   = (float*)(ws + 111542272);                      // [256][64]
  float* GC   = (float*)(ws + 111673344);                      // [256]
  short* ZFB  = (short*)(ws + 111674368);                      // [256][128][64] bf16
  short* SALL = (short*)(ws + 115868672);                      // [256][128][128] bf16 chunk-start states

  cast_f32_bf16_kernel<<<4096, 256, 0, stream>>>(x,  XB,  1048576);
  cast_f32_bf16_kernel<<<512,  256, 0, stream>>>(Wo, WOB, 131072);
  cast_wcat_kernel<<<10752, 256, 0, stream>>>(Wq, Wk, Wv, Wg, Wa, Wb, WCAT);

  gemm_bt_kernel<<<dim3(32, 21), 256, 0, stream>>>(XB, WCAT, CBUF, BLQ, NPROJ, KPROJ);

  conv_act_kernel<<<BLQ, 256, 0, stream>>>(CBUF, qcw, qcb, kcw, kcb, vcw, vcb,
                                           QH, KH, VM, VG, AL, BE);

  scan_phaseA_kernel<<<256, 256, 0, stream>>>(QH, KH, VM, AL, BE,
                                              WTB, ZB, PHB, KTB, GV, GC, WTFB, ZFB);

  scan_transition_kernel<<<256, 256, 0, stream>>>(WTFB, ZFB, KTB, GC, TRB, BF);

  scan_state_kernel<<<64, 256, 0, stream>>>(TRB, BF, st0, SALL, out + 4194304);

  scan_output_kernel<<<256, 512, 0, stream>>>(QH, WTB, (const __hip_bfloat16*)ZB,
                                              PHB, GV, SALL, OBUF);

  gate_ln_kernel<<<BLQ, 256, 0, stream>>>(OBUF, VG, CBUF, lnw, lnb, LNO);

  gemm_bt_kernel<<<dim3(32, 8), 256, 0, stream>>>(LNO, WOB, out, BLQ, DMQ, TOTQ);
}

// Round 4
// 192.580 us; speedup vs baseline: 1.7127x; 1.2165x over previous
//
#include <hip/hip_runtime.h>
#include <hip/hip_bf16.h>

// Problem constants
#define BQ    2
#define LQ    2048
#define DMQ   1024
#define HQ    4
#define DHQ   128
#define TOTQ  512
#define BLQ   4096      // B*L
#define NPROJ 2688      // padded concat: Wq(512) Wk(512) Wv(1024) Wg(512) Wa(4) Wb(4) pad(120)
#define KPROJ 1024
#define CT    64        // scan chunk length
#define NCH   32        // chunks (LQ/CT)

typedef short bf16x8 __attribute__((ext_vector_type(8)));
typedef short s16x4  __attribute__((ext_vector_type(4)));
typedef float f32x4  __attribute__((ext_vector_type(4)));

#define MFMA16(a, b, c) __builtin_amdgcn_mfma_f32_16x16x32_bf16(a, b, c, 0, 0, 0)

__device__ __forceinline__ float siluf(float x) { return x / (1.f + __expf(-x)); }
__device__ __forceinline__ float sigf(float x)  { return 1.f / (1.f + __expf(-x)); }
__device__ __forceinline__ short bf16s(float x) {
  return __builtin_bit_cast(short, __float2bfloat16(x));
}
__device__ __forceinline__ bf16x8 pack8(f32x4 a, f32x4 b) {
  bf16x8 r;
  r[0] = bf16s(a.x); r[1] = bf16s(a.y); r[2] = bf16s(a.z); r[3] = bf16s(a.w);
  r[4] = bf16s(b.x); r[5] = bf16s(b.y); r[6] = bf16s(b.z); r[7] = bf16s(b.w);
  return r;
}

// global -> LDS direct load, 16B per lane. LDS dest must be wave-uniform base;
// HW writes base + lane*16.
__device__ __forceinline__ void gload_lds16(const void* g, void* l) {
  __builtin_amdgcn_global_load_lds(
      (__attribute__((address_space(1))) void*)(unsigned long long)g,
      (__attribute__((address_space(3))) void*)(unsigned int)(unsigned long long)l,
      16, 0, 0);
}

// ---------------- casts ----------------
__global__ __launch_bounds__(256)
void cast_f32_bf16_kernel(const float* __restrict__ src, __hip_bfloat16* __restrict__ dst, int n4)
{
  int i = blockIdx.x * 256 + threadIdx.x;
  if (i < n4) {
    float4 v = ((const float4*)src)[i];
    __hip_bfloat16 o[4] = { __float2bfloat16(v.x), __float2bfloat16(v.y),
                            __float2bfloat16(v.z), __float2bfloat16(v.w) };
    *(ushort4*)((unsigned short*)dst + (size_t)i * 4) = *(ushort4*)o;
  }
}

__global__ __launch_bounds__(256)
void cast_wcat_kernel(const float* __restrict__ Wq, const float* __restrict__ Wk,
                      const float* __restrict__ Wv, const float* __restrict__ Wg,
                      const float* __restrict__ Wa, const float* __restrict__ Wb,
                      __hip_bfloat16* __restrict__ Wcat)
{
  int idx = blockIdx.x * 256 + threadIdx.x;      // 0 .. 2688*1024-1
  int row = idx >> 10, col = idx & 1023;
  float v;
  if      (row < 512)  v = Wq[idx];
  else if (row < 1024) v = Wk[idx - 512 * 1024];
  else if (row < 2048) v = Wv[idx - 1024 * 1024];
  else if (row < 2560) v = Wg[idx - 2048 * 1024];
  else if (row < 2564) v = Wa[(row - 2560) * 1024 + col];
  else if (row < 2568) v = Wb[(row - 2564) * 1024 + col];
  else                 v = 0.f;
  Wcat[idx] = __float2bfloat16(v);
}

// ---------------- bf16 MFMA GEMM: C(f32, MxN) = A(M,K) * B(N,K)^T ----------------
__global__ __launch_bounds__(256)
void gemm_bt_kernel(const __hip_bfloat16* __restrict__ A,
                    const __hip_bfloat16* __restrict__ Bw,
                    float* __restrict__ C, int M, int N, int K)
{
  __shared__ __hip_bfloat16 As[128 * 32];
  __shared__ __hip_bfloat16 Bs[128 * 32];
  const int tid  = threadIdx.x;
  const int lane = tid & 63;
  const int w    = tid >> 6;
  const int wm   = w >> 1, wn = w & 1;
  const int tm   = blockIdx.x, tn = blockIdx.y;
  const int lr   = lane & 15, lk = lane >> 4;

  f32x4 acc[4][4] = {};

  const int e0   = tid * 8;
  const int srow = e0 >> 5;        // 0..63
  const int scol = e0 & 31;
  const __hip_bfloat16* Ap = A  + (size_t)(tm * 128 + srow) * K + scol;
  const __hip_bfloat16* Bp = Bw + (size_t)(tn * 128 + srow) * K + scol;
  char* AsB  = (char*)As;
  char* BsB  = (char*)Bs;
  char* AsD0 = AsB + w * 1024;
  char* BsD0 = BsB + w * 1024;
  const size_t half = (size_t)64 * K;

  for (int kk = 0; kk < K; kk += 32) {
    __syncthreads();
    gload_lds16(Ap + kk,        AsD0);
    gload_lds16(Ap + half + kk, AsD0 + 4096);
    gload_lds16(Bp + kk,        BsD0);
    gload_lds16(Bp + half + kk, BsD0 + 4096);
    __syncthreads();
    bf16x8 af[4], bfv[4];
#pragma unroll
    for (int m = 0; m < 4; ++m)
      af[m]  = *(const bf16x8*)(AsB + ((wm * 64 + m * 16 + lr) * 32 + lk * 8) * 2);
#pragma unroll
    for (int n = 0; n < 4; ++n)
      bfv[n] = *(const bf16x8*)(BsB + ((wn * 64 + n * 16 + lr) * 32 + lk * 8) * 2);
#pragma unroll
    for (int m = 0; m < 4; ++m)
#pragma unroll
      for (int n = 0; n < 4; ++n)
        acc[m][n] = MFMA16(af[m], bfv[n], acc[m][n]);
  }

  const int crow0 = tm * 128 + wm * 64 + (lane >> 4) * 4;
  const int ccol0 = tn * 128 + wn * 64 + lr;
#pragma unroll
  for (int m = 0; m < 4; ++m)
#pragma unroll
    for (int n = 0; n < 4; ++n)
#pragma unroll
      for (int j = 0; j < 4; ++j)
        C[(size_t)(crow0 + m * 16 + j) * N + ccol0 + n * 16] = acc[m][n][j];
}

// ---------------- conv(4-tap causal) + silu + l2norm + sigmoid(a,b) ----------------
__global__ __launch_bounds__(256)
void conv_act_kernel(const float* __restrict__ C,
                     const float* __restrict__ qcw, const float* __restrict__ qcb,
                     const float* __restrict__ kcw, const float* __restrict__ kcb,
                     const float* __restrict__ vcw, const float* __restrict__ vcb,
                     float* __restrict__ qh, float* __restrict__ kh,
                     float* __restrict__ vm, float* __restrict__ vg,
                     float* __restrict__ al, float* __restrict__ be)
{
  const int bl  = blockIdx.x;
  const int t   = bl & (LQ - 1);
  const int tid = threadIdx.x;
  const float* Crow = C + (size_t)bl * NPROJ;
  __shared__ float red[8];

  float qv[2], kv[2];
  float sq = 0.f, sk = 0.f;
#pragma unroll
  for (int i = 0; i < 2; ++i) {
    const int c = tid + i * 256;
    float accq = qcb[c];
    float acck = kcb[c];
    const float4 wq = *(const float4*)(qcw + 4 * c);
    const float4 wk = *(const float4*)(kcw + 4 * c);
#pragma unroll
    for (int j = 0; j < 4; ++j) {
      const int tt = t - 3 + j;
      if (tt >= 0) {
        const float* Cr = Crow + (size_t)(j - 3) * NPROJ;
        accq = fmaf(((const float*)&wq)[j], Cr[c],       accq);
        acck = fmaf(((const float*)&wk)[j], Cr[512 + c], acck);
      }
    }
    qv[i] = siluf(accq); sq = fmaf(qv[i], qv[i], sq);
    kv[i] = siluf(acck); sk = fmaf(kv[i], kv[i], sk);
  }
  float2 pr = make_float2(sq, sk);
#pragma unroll
  for (int m = 1; m < 64; m <<= 1) { pr.x += __shfl_xor(pr.x, m); pr.y += __shfl_xor(pr.y, m); }
  if ((tid & 63) == 0) { red[(tid >> 6) * 2] = pr.x; red[(tid >> 6) * 2 + 1] = pr.y; }
  __syncthreads();
  const float SQ = red[0] + red[2] + red[4] + red[6];
  const float SK = red[1] + red[3] + red[5] + red[7];
  const float rnq = 1.f / fmaxf(sqrtf(SQ), 1e-12f);
  const float rnk = 1.f / fmaxf(sqrtf(SK), 1e-12f);
#pragma unroll
  for (int i = 0; i < 2; ++i) {
    const int c = tid + i * 256;
    qh[(size_t)bl * 512 + c] = qv[i] * rnq;
    kh[(size_t)bl * 512 + c] = kv[i] * rnk;
  }
#pragma unroll
  for (int i = 0; i < 4; ++i) {
    const int c = tid + i * 256;
    float accv = vcb[c];
    const float4 wv = *(const float4*)(vcw + 4 * c);
#pragma unroll
    for (int j = 0; j < 4; ++j) {
      const int tt = t - 3 + j;
      if (tt >= 0)
        accv = fmaf(((const float*)&wv)[j], Crow[(size_t)(j - 3) * NPROJ + 1024 + c], accv);
    }
    const float vvv = siluf(accv);
    if (c < 512) vm[(size_t)bl * 512 + c]         = vvv;
    else         vg[(size_t)bl * 512 + (c - 512)] = vvv;
  }
  if (tid < 4)       al[(size_t)bl * 4 + tid]       = sigf(Crow[2560 + tid]);
  else if (tid < 8)  be[(size_t)bl * 4 + (tid - 4)] = sigf(Crow[2564 + (tid - 4)]);
}

// ---------------- scan phase A: per-chunk WY decomposition ----------------
// 256 blocks = 32 chunks x 8 (b,h). Computes per chunk:
//   d_t = cumsum log a;  G = K K^T, Pq = Q K^T (MFMA bf16)
//   L_{ts} = b_t e^{d_t-d_s} G_{ts} (t>s)
//   solve (I+L)[W~|Z] = [diag(b e^d) K | diag(b) V]  (blocked f32 fwd subst.)
//   store W~ (bf16), Z (bf16), Phat = tril(Pq o e^{d_t-d_s}) (bf16),
//         KT = K^T (bf16), gamma_t = e^{d_t}, gc = e^{d_63}
//   plus f-scaled transposes for the transition kernel:
//         WTF(m,s) = f_s W~(s,m), ZF(i,s) = f_s Z(s,i), f_s = e^{d_63-d_s}
// Substitution is blocked in 4 groups of 16 rows: only u[16] lives in regs;
// solved blocks spill to LDS Xl[64][256] (lane-consecutive -> conflict-free,
// column j private to thread j). Xl aliases the K/Q staging (dead after MFMA).
__global__ __launch_bounds__(256)
void scan_phaseA_kernel(const float* __restrict__ qh, const float* __restrict__ kh,
                        const float* __restrict__ vm, const float* __restrict__ al,
                        const float* __restrict__ be,
                        short* __restrict__ WTB, short* __restrict__ ZB,
                        short* __restrict__ PHB, short* __restrict__ KTB,
                        float* __restrict__ GV, float* __restrict__ GC,
                        short* __restrict__ WTFB, short* __restrict__ ZFB)
{
  __shared__ char sm[83968];
  float* Xl = (float*)(sm);                             // [64][256] f32 (aliases KBl/QBl)
  __hip_bfloat16* KBl = (__hip_bfloat16*)(sm);          // [64][136]
  __hip_bfloat16* QBl = (__hip_bfloat16*)(sm + 17408);  // [64][136]
  float* Ll  = (float*)(sm + 65536);                    // [64][68]
  float* dv  = (float*)(sm + 82944);                    // [64]
  float* bv  = (float*)(sm + 83200);                    // [64]
  float* gbv = (float*)(sm + 83456);                    // [64]
  float* fvs = (float*)(sm + 83712);                    // [64]

  const int cb = blockIdx.x;
  const int bh = cb & 7, c = cb >> 3;
  const int b = bh >> 2, h = bh & 3;
  const int tid = threadIdx.x;
  const int lane = tid & 63;
  const int w = tid >> 6;
  const int lr = lane & 15, lk = lane >> 4;
  const size_t rowbase = (size_t)(b * LQ + c * CT) * 512 + h * 128;

  // stage K,Q -> LDS bf16 (padded rows of 136)
#pragma unroll
  for (int rep = 0; rep < 4; ++rep) {
    const int fid = tid + rep * 256;       // 0..1023
    const int r = fid >> 4;
    const int cg = (fid & 15) * 8;
    const float* kp = kh + rowbase + (size_t)r * 512 + cg;
    const float* qp = qh + rowbase + (size_t)r * 512 + cg;
    f32x4 k0 = *(const f32x4*)kp, k1 = *(const f32x4*)(kp + 4);
    f32x4 q0 = *(const f32x4*)qp, q1 = *(const f32x4*)(qp + 4);
    *(bf16x8*)(KBl + r * 136 + cg) = pack8(k0, k1);
    *(bf16x8*)(QBl + r * 136 + cg) = pack8(q0, q1);
  }
  // decay prefix (wave 0)
  if (w == 0) {
    float la = __logf(al[(size_t)(b * LQ + c * CT + lane) * 4 + h]);
    const float bb = be[(size_t)(b * LQ + c * CT + lane) * 4 + h];
#pragma unroll
    for (int off = 1; off < 64; off <<= 1) {
      const float tv = __shfl_up(la, off, 64);
      if (lane >= off) la += tv;
    }
    const float d63 = __shfl(la, 63, 64);
    dv[lane] = la; bv[lane] = bb; gbv[lane] = bb * __expf(la);
    fvs[lane] = __expf(d63 - la);
    GV[cb * 64 + lane] = __expf(la);
    if (lane == 0) GC[cb] = __expf(d63);
  }
  __syncthreads();

  // G = K K^T, Pq = Q K^T  (each wave owns one 16-row t-band)
  f32x4 aG[4] = {}, aP[4] = {};
#pragma unroll
  for (int ks = 0; ks < 4; ++ks) {
    bf16x8 bk[4];
#pragma unroll
    for (int nt = 0; nt < 4; ++nt)
      bk[nt] = *(const bf16x8*)(KBl + (nt * 16 + lr) * 136 + ks * 32 + lk * 8);
    const bf16x8 ak = *(const bf16x8*)(KBl + (w * 16 + lr) * 136 + ks * 32 + lk * 8);
    const bf16x8 aq = *(const bf16x8*)(QBl + (w * 16 + lr) * 136 + ks * 32 + lk * 8);
#pragma unroll
    for (int nt = 0; nt < 4; ++nt) {
      aG[nt] = MFMA16(ak, bk[nt], aG[nt]);
      aP[nt] = MFMA16(aq, bk[nt], aP[nt]);
    }
  }
#pragma unroll
  for (int nt = 0; nt < 4; ++nt)
#pragma unroll
    for (int jj = 0; jj < 4; ++jj) {
      const int t = w * 16 + lk * 4 + jj;
      const int s = nt * 16 + lr;
      const float eg = __expf(dv[t] - dv[s]);
      Ll[t * 68 + s] = (t > s) ? bv[t] * eg * aG[nt][jj] : 0.f;
      PHB[(size_t)cb * 4096 + t * 64 + s] = (s <= t) ? bf16s(eg * aP[nt][jj]) : (short)0;
    }
  __syncthreads();   // KBl/QBl dead from here -> Xl may overwrite

  // ---- blocked forward substitution: thread j owns column j ----
  const int j = tid;
  const float* src = (j < 128) ? kh : vm;
  const float* xp = src + rowbase + (j & 127);
  float* XlC = Xl + j;                 // private column, stride 256 floats
  short* dstN = (j < 128) ? (WTB + (size_t)cb * 8192 + j)
                          : (ZB  + (size_t)cb * 8192 + (j - 128));
  short* dstT = (j < 128) ? (WTFB + (size_t)cb * 8192 + (size_t)j * 64)
                          : (ZFB  + (size_t)cb * 8192 + (size_t)(j - 128) * 64);

  for (int r = 0; r < 4; ++r) {
    float u[16];
    // RHS block (scaled)
#pragma unroll
    for (int i = 0; i < 16; ++i) {
      const int t = r * 16 + i;
      u[i] = xp[(size_t)t * 512] * ((j < 128) ? gbv[t] : bv[t]);
    }
    // cross-block updates from already-solved 16-blocks (LDS spill)
    for (int sc = 0; sc < r; ++sc) {
      float xs[16];
#pragma unroll
      for (int k = 0; k < 16; ++k) xs[k] = XlC[(sc * 16 + k) * 256];
#pragma unroll
      for (int i = 0; i < 16; ++i) {
        const float* lrow = Ll + (r * 16 + i) * 68 + sc * 16;
        const f32x4 l0 = *(const f32x4*)(lrow);
        const f32x4 l1 = *(const f32x4*)(lrow + 4);
        const f32x4 l2 = *(const f32x4*)(lrow + 8);
        const f32x4 l3 = *(const f32x4*)(lrow + 12);
        f32x4 acc = {};
        acc.x = fmaf(l0.x, xs[0],  acc.x); acc.y = fmaf(l0.y, xs[1],  acc.y);
        acc.z = fmaf(l0.z, xs[2],  acc.z); acc.w = fmaf(l0.w, xs[3],  acc.w);
        acc.x = fmaf(l1.x, xs[4],  acc.x); acc.y = fmaf(l1.y, xs[5],  acc.y);
        acc.z = fmaf(l1.z, xs[6],  acc.z); acc.w = fmaf(l1.w, xs[7],  acc.w);
        acc.x = fmaf(l2.x, xs[8],  acc.x); acc.y = fmaf(l2.y, xs[9],  acc.y);
        acc.z = fmaf(l2.z, xs[10], acc.z); acc.w = fmaf(l2.w, xs[11], acc.w);
        acc.x = fmaf(l3.x, xs[12], acc.x); acc.y = fmaf(l3.y, xs[13], acc.y);
        acc.z = fmaf(l3.z, xs[14], acc.z); acc.w = fmaf(l3.w, xs[15], acc.w);
        u[i] -= (acc.x + acc.y) + (acc.z + acc.w);
      }
    }
    // in-block serial solve (rows above diag of Ll are zero)
#pragma unroll
    for (int i = 1; i < 16; ++i) {
      const float* lrow = Ll + (r * 16 + i) * 68 + r * 16;
      f32x4 acc = {};
#pragma unroll
      for (int k4 = 0; k4 < 4; ++k4) {
        if (k4 * 4 < i) {
          const f32x4 lv = *(const f32x4*)(lrow + k4 * 4);
          acc.x = fmaf(lv.x, u[k4 * 4 + 0], acc.x);
          acc.y = fmaf(lv.y, u[k4 * 4 + 1], acc.y);
          acc.z = fmaf(lv.z, u[k4 * 4 + 2], acc.z);
          acc.w = fmaf(lv.w, u[k4 * 4 + 3], acc.w);
        }
      }
      u[i] -= (acc.x + acc.y) + (acc.z + acc.w);
    }
    // spill for future blocks
    if (r < 3) {
#pragma unroll
      for (int i = 0; i < 16; ++i) XlC[(r * 16 + i) * 256] = u[i];
    }
    // stores: W~/Z (bf16, coalesced) and f-scaled transposed WTF/ZF
#pragma unroll
    for (int i = 0; i < 16; ++i)
      dstN[(r * 16 + i) * 128] = bf16s(u[i]);
#pragma unroll
    for (int s4 = 0; s4 < 4; ++s4) {
      s16x4 p;
#pragma unroll
      for (int e = 0; e < 4; ++e)
        p[e] = bf16s(fvs[r * 16 + s4 * 4 + e] * u[s4 * 4 + e]);
      *(s16x4*)(dstT + r * 16 + s4 * 4) = p;
    }
  }

  // KT = K^T (128 x 64 bf16)
  if (tid < 128) {
    const float* kp2 = kh + rowbase + tid;
#pragma unroll
    for (int s4 = 0; s4 < 16; ++s4) {
      s16x4 pk;
#pragma unroll
      for (int e = 0; e < 4; ++e)
        pk[e] = bf16s(kp2[(size_t)(s4 * 4 + e) * 512]);
      *(s16x4*)(KTB + (size_t)cb * 8192 + tid * 64 + s4 * 4) = pk;
    }
  }
}

// ---------------- scan transition: per-chunk affine factors ----------------
// S_{c+1} = S_c T_c + B_c  (rows of S evolve independently)
//   A(m,j)  = sum_s f_s W~(s,m) K(s,j);   T(m,j) = gc d(m,j) - A(m,j)
//   B(i,j)  = sum_s f_s Z(s,i)  K(s,j)
// Stored: TRB[cb][j][m] = T(m,j) (bf16, transposed for MFMA B-operand),
//         BF[cb][i][j] (f32).
// 256 blocks (one per cb), 4 waves; wave w owns a 32-row output band.
__global__ __launch_bounds__(256)
void scan_transition_kernel(const short* __restrict__ WTFB, const short* __restrict__ ZFB,
                            const short* __restrict__ KTB, const float* __restrict__ GC,
                            short* __restrict__ TRB, float* __restrict__ BF)
{
  const int cb = blockIdx.x;
  const int tid = threadIdx.x, lane = tid & 63, w = tid >> 6;
  const int lr = lane & 15, lk = lane >> 4;
  const float gc = GC[cb];

  // ---- AT(j,m) = sum_s KT(j,s) * WTF(m,s) ; then T^T(j,m) = gc d - AT(j,m)
  {
    f32x4 acc[2][8] = {};
#pragma unroll
    for (int ks = 0; ks < 2; ++ks) {
      bf16x8 a0 = *(const bf16x8*)(KTB + (size_t)cb * 8192 + (w * 32 + lr) * 64 + ks * 32 + lk * 8);
      bf16x8 a1 = *(const bf16x8*)(KTB + (size_t)cb * 8192 + (w * 32 + 16 + lr) * 64 + ks * 32 + lk * 8);
#pragma unroll
      for (int nt = 0; nt < 8; ++nt) {
        const bf16x8 bm = *(const bf16x8*)(WTFB + (size_t)cb * 8192 + (nt * 16 + lr) * 64 + ks * 32 + lk * 8);
        acc[0][nt] = MFMA16(a0, bm, acc[0][nt]);
        acc[1][nt] = MFMA16(a1, bm, acc[1][nt]);
      }
    }
#pragma unroll
    for (int mt = 0; mt < 2; ++mt)
#pragma unroll
      for (int nt = 0; nt < 8; ++nt)
#pragma unroll
        for (int jj = 0; jj < 4; ++jj) {
          const int jr = w * 32 + mt * 16 + lk * 4 + jj;
          const int m  = nt * 16 + lr;
          const float v = ((jr == m) ? gc : 0.f) - acc[mt][nt][jj];
          TRB[(size_t)cb * 16384 + jr * 128 + m] = bf16s(v);
        }
  }
  // ---- B(i,j) = sum_s ZF(i,s) * KT(j,s)
  {
    f32x4 acc[2][8] = {};
#pragma unroll
    for (int ks = 0; ks < 2; ++ks) {
      bf16x8 a0 = *(const bf16x8*)(ZFB + (size_t)cb * 8192 + (w * 32 + lr) * 64 + ks * 32 + lk * 8);
      bf16x8 a1 = *(const bf16x8*)(ZFB + (size_t)cb * 8192 + (w * 32 + 16 + lr) * 64 + ks * 32 + lk * 8);
#pragma unroll
      for (int nt = 0; nt < 8; ++nt) {
        const bf16x8 bj = *(const bf16x8*)(KTB + (size_t)cb * 8192 + (nt * 16 + lr) * 64 + ks * 32 + lk * 8);
        acc[0][nt] = MFMA16(a0, bj, acc[0][nt]);
        acc[1][nt] = MFMA16(a1, bj, acc[1][nt]);
      }
    }
#pragma unroll
    for (int mt = 0; mt < 2; ++mt)
#pragma unroll
      for (int nt = 0; nt < 8; ++nt)
#pragma unroll
        for (int jj = 0; jj < 4; ++jj) {
          const int ir = w * 32 + mt * 16 + lk * 4 + jj;
          const int jc = nt * 16 + lr;
          BF[(size_t)cb * 16384 + ir * 128 + jc] = acc[mt][nt][jj];
        }
  }
}

// ---------------- scan state: serial chunk recurrence, S rows independent ----
// 64 blocks = 8 (b,h) x 8 row-slabs of 16. Per chunk: store S_c (bf16) to
// SALL, S <- S*T + B with register-double-buffered prefetch of T_{c+1}/B_{c+1}.
#define L2_PREFETCH(BT, BA, CC) do {                                               \
  const int cbn_ = (CC) * 8 + bh;                                                  \
  _Pragma("unroll") for (int nt = 0; nt < 2; ++nt) {                               \
    _Pragma("unroll") for (int ks = 0; ks < 4; ++ks)                               \
      BT[nt][ks] = *(const bf16x8*)(TRB + (size_t)cbn_ * 16384 +                   \
                                    (w * 32 + nt * 16 + lr) * 128 + ks * 32 + lk * 8); \
    _Pragma("unroll") for (int jj = 0; jj < 4; ++jj)                               \
      BA[nt][jj] = BF[(size_t)cbn_ * 16384 + (r0 + lk * 4 + jj) * 128 +            \
                      w * 32 + nt * 16 + lr];                                      \
  }                                                                                \
} while (0)

#define L2_STEP(BT, BA, CC, PBT, PBA) do {                                         \
  const int cb_ = (CC) * 8 + bh;                                                   \
  { const int idx = tid * 8, r = idx >> 7, jc = idx & 127;                         \
    f32x4 s0 = *(const f32x4*)&Scur[r * 132 + jc];                                 \
    f32x4 s1 = *(const f32x4*)&Scur[r * 132 + jc + 4];                             \
    *(bf16x8*)(SALL + (size_t)cb_ * 16384 + (r0 + r) * 128 + jc) = pack8(s0, s1); }\
  bf16x8 af[4];                                                                    \
  _Pragma("unroll") for (int ks = 0; ks < 4; ++ks)                                 \
    af[ks] = pack8(*(const f32x4*)&Scur[lr * 132 + ks * 32 + lk * 8],              \
                   *(const f32x4*)&Scur[lr * 132 + ks * 32 + lk * 8 + 4]);         \
  if ((CC) < 31) L2_PREFETCH(PBT, PBA, (CC) + 1);                                  \
  f32x4 acc0 = {}, acc1 = {};                                                      \
  _Pragma("unroll") for (int ks = 0; ks < 4; ++ks) {                               \
    acc0 = MFMA16(af[ks], BT[0][ks], acc0);                                        \
    acc1 = MFMA16(af[ks], BT[1][ks], acc1);                                        \
  }                                                                                \
  _Pragma("unroll") for (int jj = 0; jj < 4; ++jj) {                               \
    Snxt[(lk * 4 + jj) * 132 + w * 32 + lr]      = acc0[jj] + BA[0][jj];           \
    Snxt[(lk * 4 + jj) * 132 + w * 32 + 16 + lr] = acc1[jj] + BA[1][jj];           \
  }                                                                                \
  __syncthreads();                                                                 \
  { float* t_ = Scur; Scur = Snxt; Snxt = t_; }                                    \
} while (0)

__global__ __launch_bounds__(256)
void scan_state_kernel(const short* __restrict__ TRB, const float* __restrict__ BF,
                       const float* __restrict__ st0, short* __restrict__ SALL,
                       float* __restrict__ stout)
{
  __shared__ float Sl[2 * 16 * 132];
  const int bid = blockIdx.x;            // 64
  const int bh = bid & 7, slab = bid >> 3;
  const int r0 = slab * 16;
  const int tid = threadIdx.x, lane = tid & 63, w = tid >> 6;
  const int lr = lane & 15, lk = lane >> 4;

  float* Scur = Sl;
  float* Snxt = Sl + 16 * 132;

  // load st0 slab
  {
    const int idx = tid * 8, r = idx >> 7, jc = idx & 127;
    const float* sp = st0 + ((size_t)bh * 128 + r0 + r) * 128 + jc;
    *(f32x4*)&Scur[r * 132 + jc]     = *(const f32x4*)sp;
    *(f32x4*)&Scur[r * 132 + jc + 4] = *(const f32x4*)(sp + 4);
  }
  bf16x8 btA[2][4], btB[2][4];
  float  baA[2][4], baB[2][4];
  L2_PREFETCH(btA, baA, 0);
  __syncthreads();

  for (int c2 = 0; c2 < 16; ++c2) {
    L2_STEP(btA, baA, 2 * c2,     btB, baB);
    L2_STEP(btB, baB, 2 * c2 + 1, btA, baA);
  }

  // final state (Scur holds S_32 after 32 swaps)
  {
    const int idx = tid * 8, r = idx >> 7, jc = idx & 127;
    float* sp = stout + ((size_t)bh * 128 + r0 + r) * 128 + jc;
    *(f32x4*)sp       = *(const f32x4*)&Scur[r * 132 + jc];
    *(f32x4*)(sp + 4) = *(const f32x4*)&Scur[r * 132 + jc + 4];
  }
}

// ---------------- scan output: fully parallel over chunks ----------------
// 256 blocks (cb) x 512 threads (8 waves). waves 0-3: Y_up = Q S_c^T rows,
// waves 4-7: Y_low = W~ S_c^T rows -> U = Z - Y_low -> Ut (LDS); barrier;
// waves 0-3: O = diag(gv) Y_up + Phat U.
__global__ __launch_bounds__(512)
void scan_output_kernel(const float* __restrict__ qh,
                        const short* __restrict__ WTB, const __hip_bfloat16* __restrict__ ZB,
                        const short* __restrict__ PHB, const float* __restrict__ GV,
                        const short* __restrict__ SALL, float* __restrict__ obuf)
{
  __shared__ short Ut[128 * 72];
  const int cb = blockIdx.x;
  const int bh = cb & 7, c = cb >> 3;
  const int b = bh >> 2, h = bh & 3;
  const int tid = threadIdx.x, lane = tid & 63, w = tid >> 6;   // w 0..7
  const int lr = lane & 15, lk = lane >> 4;
  const int r0 = (w & 3) * 16;

  f32x4 Y[8] = {};
#pragma unroll
  for (int ks = 0; ks < 4; ++ks) {
    bf16x8 af;
    if (w < 4) {
      const float* qp = qh + ((size_t)(b * LQ + c * CT) + r0 + lr) * 512 + h * 128 + ks * 32 + lk * 8;
      af = pack8(*(const f32x4*)qp, *(const f32x4*)(qp + 4));
    } else {
      af = *(const bf16x8*)(WTB + (size_t)cb * 8192 + (r0 + lr) * 128 + ks * 32 + lk * 8);
    }
#pragma unroll
    for (int nt = 0; nt < 8; ++nt) {
      const bf16x8 bs = *(const bf16x8*)(SALL + (size_t)cb * 16384 + (nt * 16 + lr) * 128 + ks * 32 + lk * 8);
      Y[nt] = MFMA16(af, bs, Y[nt]);
    }
  }
  if (w >= 4) {   // U = Z - Y_low -> LDS (Ut[i][s])
#pragma unroll
    for (int nt = 0; nt < 8; ++nt) {
      const int i = nt * 16 + lr;
      s16x4 up;
#pragma unroll
      for (int jj = 0; jj < 4; ++jj) {
        const int s = r0 + lk * 4 + jj;
        const float z = __bfloat162float(ZB[(size_t)cb * 8192 + s * 128 + i]);
        up[jj] = bf16s(z - Y[nt][jj]);
      }
      *(s16x4*)&Ut[i * 72 + r0 + lk * 4] = up;
    }
  }
  __syncthreads();
  if (w < 4) {
    f32x4 P2[8] = {};
#pragma unroll
    for (int ks = 0; ks < 2; ++ks) {
      const bf16x8 ap = *(const bf16x8*)(PHB + (size_t)cb * 4096 + (r0 + lr) * 64 + ks * 32 + lk * 8);
#pragma unroll
      for (int nt = 0; nt < 8; ++nt) {
        const bf16x8 bu = *(const bf16x8*)&Ut[(nt * 16 + lr) * 72 + ks * 32 + lk * 8];
        P2[nt] = MFMA16(ap, bu, P2[nt]);
      }
    }
    float gvv[4];
#pragma unroll
    for (int jj = 0; jj < 4; ++jj) gvv[jj] = GV[cb * 64 + r0 + lk * 4 + jj];
#pragma unroll
    for (int nt = 0; nt < 8; ++nt) {
      const int i = nt * 16 + lr;
#pragma unroll
      for (int jj = 0; jj < 4; ++jj) {
        const int t = r0 + lk * 4 + jj;
        obuf[((size_t)(b * LQ + c * CT) + t) * 512 + h * 128 + i] =
            gvv[jj] * Y[nt][jj] + P2[nt][jj];
      }
    }
  }
}

// ---------------- gate * silu(g), LayerNorm(512), cast bf16 ----------------
__global__ __launch_bounds__(256)
void gate_ln_kernel(const float* __restrict__ obuf, const float* __restrict__ vg,
                    const float* __restrict__ C, const float* __restrict__ lnw,
                    const float* __restrict__ lnb, __hip_bfloat16* __restrict__ lno)
{
  const int bl = blockIdx.x, tid = threadIdx.x;
  __shared__ float red[8];
  float y[2]; float s = 0.f, s2 = 0.f;
#pragma unroll
  for (int i = 0; i < 2; ++i) {
    const int c = tid + i * 256;
    const float g = C[(size_t)bl * NPROJ + 2048 + c];
    const float v = obuf[(size_t)bl * 512 + c] * vg[(size_t)bl * 512 + c] * siluf(g);
    y[i] = v; s += v; s2 = fmaf(v, v, s2);
  }
  float2 pr = make_float2(s, s2);
#pragma unroll
  for (int m = 1; m < 64; m <<= 1) { pr.x += __shfl_xor(pr.x, m); pr.y += __shfl_xor(pr.y, m); }
  if ((tid & 63) == 0) { red[(tid >> 6) * 2] = pr.x; red[(tid >> 6) * 2 + 1] = pr.y; }
  __syncthreads();
  const float S  = red[0] + red[2] + red[4] + red[6];
  const float S2 = red[1] + red[3] + red[5] + red[7];
  const float mu  = S * (1.f / 512.f);
  const float var = S2 * (1.f / 512.f) - mu * mu;
  const float rs  = rsqrtf(var + 1e-5f);
#pragma unroll
  for (int i = 0; i < 2; ++i) {
    const int c = tid + i * 256;
    lno[(size_t)bl * 512 + c] = __float2bfloat16(fmaf((y[i] - mu) * rs, lnw[c], lnb[c]));
  }
}

extern "C" void kernel_launch(void* const* d_in, const int* in_sizes, int n_in,
                              void* d_out, int out_size, void* d_ws, size_t ws_size,
                              hipStream_t stream)
{
  (void)in_sizes; (void)n_in; (void)out_size; (void)ws_size;
  const float* x    = (const float*)d_in[0];
  const float* st0  = (const float*)d_in[1];
  const float* Wq   = (const float*)d_in[2];
  const float* Wk   = (const float*)d_in[3];
  const float* Wv   = (const float*)d_in[4];
  const float* Wa   = (const float*)d_in[5];
  const float* Wb   = (const float*)d_in[6];
  const float* Wg   = (const float*)d_in[7];
  const float* Wo   = (const float*)d_in[8];
  const float* qcw  = (const float*)d_in[9];
  const float* qcb  = (const float*)d_in[10];
  const float* kcw  = (const float*)d_in[11];
  const float* kcb  = (const float*)d_in[12];
  const float* vcw  = (const float*)d_in[13];
  const float* vcb  = (const float*)d_in[14];
  const float* lnw  = (const float*)d_in[15];
  const float* lnb  = (const float*)d_in[16];
  float* out = (float*)d_out;

  // workspace layout (bytes); high-water ~124.3 MB
  char* ws = (char*)d_ws;
  __hip_bfloat16* XB   = (__hip_bfloat16*)(ws + 0);            // 4096x1024 bf16 (dead after proj GEMM)
  __hip_bfloat16* LNO  = (__hip_bfloat16*)(ws + 0);            // 4096x512 bf16 (aliases XB 1st half, written at gate_ln)
  short*          WTFB = (short*)(ws + 0);                     // [256][128][64] bf16 (aliases XB 1st half; phaseA->transition window)
  short*          WTB  = (short*)(ws + 4194304);               // [256][64][128] bf16 (aliases XB 2nd half)
  __hip_bfloat16* WCAT = (__hip_bfloat16*)(ws + 8388608);      // 2688x1024 bf16
  __hip_bfloat16* WOB  = (__hip_bfloat16*)(ws + 13893632);     // 1024x512  bf16
  float* CBUF = (float*)(ws + 14942208);                       // 4096x2688 f32
  float* QH   = (float*)(ws + 58982400);                       // 4096x512
  float* KH   = (float*)(ws + 67371008);
  float* BF   = (float*)(ws + 67371008);                       // [256][128][128] f32 (aliases KH+VM; written after phaseA)
  float* VM   = (float*)(ws + 75759616);
  float* VG   = (float*)(ws + 84148224);
  float* AL   = (float*)(ws + 92536832);                       // 4096x4
  float* BE   = (float*)(ws + 92602368);
  float* OBUF = (float*)(ws + 92667904);                       // 4096x512 (written by scan_output)
  short* TRB  = (short*)(ws + 92667904);                       // [256][128][128] bf16 (aliases OBUF; dead before scan_output)
  short* KTB  = (short*)(ws + 101056512);                      // [256][128][64] bf16
  short* PHB  = (short*)(ws + 105250816);                      // [256][64][64] bf16
  short* ZB   = (short*)(ws + 107347968);                      // [256][64][128] bf16
  float* GV   = (float*)(ws + 111542272);                      // [256][64]
  float* GC   = (float*)(ws + 111673344);                      // [256]
  short* ZFB  = (short*)(ws + 111674368);                      // [256][128][64] bf16
  short* SALL = (short*)(ws + 115868672);                      // [256][128][128] bf16 chunk-start states

  cast_f32_bf16_kernel<<<4096, 256, 0, stream>>>(x,  XB,  1048576);
  cast_f32_bf16_kernel<<<512,  256, 0, stream>>>(Wo, WOB, 131072);
  cast_wcat_kernel<<<10752, 256, 0, stream>>>(Wq, Wk, Wv, Wg, Wa, Wb, WCAT);

  gemm_bt_kernel<<<dim3(32, 21), 256, 0, stream>>>(XB, WCAT, CBUF, BLQ, NPROJ, KPROJ);

  conv_act_kernel<<<BLQ, 256, 0, stream>>>(CBUF, qcw, qcb, kcw, kcb, vcw, vcb,
                                           QH, KH, VM, VG, AL, BE);

  scan_phaseA_kernel<<<256, 256, 0, stream>>>(QH, KH, VM, AL, BE,
                                              WTB, ZB, PHB, KTB, GV, GC, WTFB, ZFB);

  scan_transition_kernel<<<256, 256, 0, stream>>>(WTFB, ZFB, KTB, GC, TRB, BF);

  scan_state_kernel<<<64, 256, 0, stream>>>(TRB, BF, st0, SALL, out + 4194304);

  scan_output_kernel<<<256, 512, 0, stream>>>(QH, WTB, (const __hip_bfloat16*)ZB,
                                              PHB, GV, SALL, OBUF);

  gate_ln_kernel<<<BLQ, 256, 0, stream>>>(OBUF, VG, CBUF, lnw, lnb, LNO);

  gemm_bt_kernel<<<dim3(32, 8), 256, 0, stream>>>(LNO, WOB, out, BLQ, DMQ, TOTQ);
}

// Round 5
// 179.721 us; speedup vs baseline: 1.8353x; 1.0715x over previous
//
#include <hip/hip_runtime.h>
#include <hip/hip_bf16.h>

// Problem constants
#define BQ    2
#define LQ    2048
#define DMQ   1024
#define HQ    4
#define DHQ   128
#define TOTQ  512
#define BLQ   4096      // B*L
#define NPROJ 2688      // padded concat: Wq(512) Wk(512) Wv(1024) Wg(512) Wa(4) Wb(4) pad(120)
#define KPROJ 1024
#define CT    64        // scan chunk length
#define NCH   32        // chunks (LQ/CT)

typedef short bf16x8 __attribute__((ext_vector_type(8)));
typedef short s16x4  __attribute__((ext_vector_type(4)));
typedef float f32x4  __attribute__((ext_vector_type(4)));

#define MFMA16(a, b, c) __builtin_amdgcn_mfma_f32_16x16x32_bf16(a, b, c, 0, 0, 0)

__device__ __forceinline__ float siluf(float x) { return x / (1.f + __expf(-x)); }
__device__ __forceinline__ float sigf(float x)  { return 1.f / (1.f + __expf(-x)); }
__device__ __forceinline__ short bf16s(float x) {
  return __builtin_bit_cast(short, __float2bfloat16(x));
}
__device__ __forceinline__ bf16x8 pack8(f32x4 a, f32x4 b) {
  bf16x8 r;
  r[0] = bf16s(a.x); r[1] = bf16s(a.y); r[2] = bf16s(a.z); r[3] = bf16s(a.w);
  r[4] = bf16s(b.x); r[5] = bf16s(b.y); r[6] = bf16s(b.z); r[7] = bf16s(b.w);
  return r;
}

// global -> LDS direct load, 16B per lane. LDS dest must be wave-uniform base;
// HW writes base + lane*16.
__device__ __forceinline__ void gload_lds16(const void* g, void* l) {
  __builtin_amdgcn_global_load_lds(
      (__attribute__((address_space(1))) void*)(unsigned long long)g,
      (__attribute__((address_space(3))) void*)(unsigned int)(unsigned long long)l,
      16, 0, 0);
}

// ---------------- casts ----------------
__global__ __launch_bounds__(256)
void cast_f32_bf16_kernel(const float* __restrict__ src, __hip_bfloat16* __restrict__ dst, int n4)
{
  int i = blockIdx.x * 256 + threadIdx.x;
  if (i < n4) {
    float4 v = ((const float4*)src)[i];
    __hip_bfloat16 o[4] = { __float2bfloat16(v.x), __float2bfloat16(v.y),
                            __float2bfloat16(v.z), __float2bfloat16(v.w) };
    *(ushort4*)((unsigned short*)dst + (size_t)i * 4) = *(ushort4*)o;
  }
}

__global__ __launch_bounds__(256)
void cast_wcat_kernel(const float* __restrict__ Wq, const float* __restrict__ Wk,
                      const float* __restrict__ Wv, const float* __restrict__ Wg,
                      const float* __restrict__ Wa, const float* __restrict__ Wb,
                      __hip_bfloat16* __restrict__ Wcat)
{
  int idx = blockIdx.x * 256 + threadIdx.x;      // 0 .. 2688*1024-1
  int row = idx >> 10, col = idx & 1023;
  float v;
  if      (row < 512)  v = Wq[idx];
  else if (row < 1024) v = Wk[idx - 512 * 1024];
  else if (row < 2048) v = Wv[idx - 1024 * 1024];
  else if (row < 2560) v = Wg[idx - 2048 * 1024];
  else if (row < 2564) v = Wa[(row - 2560) * 1024 + col];
  else if (row < 2568) v = Wb[(row - 2564) * 1024 + col];
  else                 v = 0.f;
  Wcat[idx] = __float2bfloat16(v);
}

// ---------------- bf16 MFMA GEMM: C(f32, MxN) = A(M,K) * B(N,K)^T ----------------
// 2-phase double-buffered LDS: issue next K-tile's global_load_lds BEFORE the
// current tile's ds_read+MFMA; the barrier's vmcnt drain lands exactly when the
// prefetched tile is needed, overlapping HBM/L2 latency with compute.
__global__ __launch_bounds__(256)
void gemm_bt_kernel(const __hip_bfloat16* __restrict__ A,
                    const __hip_bfloat16* __restrict__ Bw,
                    float* __restrict__ C, int M, int N, int K)
{
  __shared__ __hip_bfloat16 As[2 * 128 * 32];
  __shared__ __hip_bfloat16 Bs[2 * 128 * 32];
  const int tid  = threadIdx.x;
  const int lane = tid & 63;
  const int w    = tid >> 6;
  const int wm   = w >> 1, wn = w & 1;
  const int tm   = blockIdx.x, tn = blockIdx.y;
  const int lr   = lane & 15, lk = lane >> 4;

  f32x4 acc[4][4] = {};

  const int e0   = tid * 8;
  const int srow = e0 >> 5;        // 0..63
  const int scol = e0 & 31;
  const __hip_bfloat16* Ap = A  + (size_t)(tm * 128 + srow) * K + scol;
  const __hip_bfloat16* Bp = Bw + (size_t)(tn * 128 + srow) * K + scol;
  char* AsB  = (char*)As;
  char* BsB  = (char*)Bs;
  const size_t half = (size_t)64 * K;
  const int nk = K >> 5;

  // prologue: stage K-tile 0 into buffer 0
  {
    char* AsD = AsB + w * 1024;
    char* BsD = BsB + w * 1024;
    gload_lds16(Ap,        AsD);
    gload_lds16(Ap + half, AsD + 4096);
    gload_lds16(Bp,        BsD);
    gload_lds16(Bp + half, BsD + 4096);
  }
  __syncthreads();

  for (int it = 0; it < nk; ++it) {
    const int sel = it & 1;
    // prefetch next K-tile into the other buffer (no wait here)
    if (it + 1 < nk) {
      const int kk = (it + 1) * 32;
      char* AsD = AsB + ((sel ^ 1) * 8192) + w * 1024;
      char* BsD = BsB + ((sel ^ 1) * 8192) + w * 1024;
      gload_lds16(Ap + kk,        AsD);
      gload_lds16(Ap + half + kk, AsD + 4096);
      gload_lds16(Bp + kk,        BsD);
      gload_lds16(Bp + half + kk, BsD + 4096);
    }
    // compute on current buffer
    const char* AsR = AsB + sel * 8192;
    const char* BsR = BsB + sel * 8192;
    bf16x8 af[4], bfv[4];
#pragma unroll
    for (int m = 0; m < 4; ++m)
      af[m]  = *(const bf16x8*)(AsR + ((wm * 64 + m * 16 + lr) * 32 + lk * 8) * 2);
#pragma unroll
    for (int n = 0; n < 4; ++n)
      bfv[n] = *(const bf16x8*)(BsR + ((wn * 64 + n * 16 + lr) * 32 + lk * 8) * 2);
#pragma unroll
    for (int m = 0; m < 4; ++m)
#pragma unroll
      for (int n = 0; n < 4; ++n)
        acc[m][n] = MFMA16(af[m], bfv[n], acc[m][n]);
    // barrier (drains vmcnt): next tile resident, current buffer reusable
    __syncthreads();
  }

  const int crow0 = tm * 128 + wm * 64 + (lane >> 4) * 4;
  const int ccol0 = tn * 128 + wn * 64 + lr;
#pragma unroll
  for (int m = 0; m < 4; ++m)
#pragma unroll
    for (int n = 0; n < 4; ++n)
#pragma unroll
      for (int j = 0; j < 4; ++j)
        C[(size_t)(crow0 + m * 16 + j) * N + ccol0 + n * 16] = acc[m][n][j];
}

// ---------------- conv(4-tap causal) + silu + l2norm + sigmoid(a,b) ----------------
__global__ __launch_bounds__(256)
void conv_act_kernel(const float* __restrict__ C,
                     const float* __restrict__ qcw, const float* __restrict__ qcb,
                     const float* __restrict__ kcw, const float* __restrict__ kcb,
                     const float* __restrict__ vcw, const float* __restrict__ vcb,
                     float* __restrict__ qh, float* __restrict__ kh,
                     float* __restrict__ vm, float* __restrict__ vg,
                     float* __restrict__ al, float* __restrict__ be)
{
  const int bl  = blockIdx.x;
  const int t   = bl & (LQ - 1);
  const int tid = threadIdx.x;
  const float* Crow = C + (size_t)bl * NPROJ;
  __shared__ float red[8];

  float qv[2], kv[2];
  float sq = 0.f, sk = 0.f;
#pragma unroll
  for (int i = 0; i < 2; ++i) {
    const int c = tid + i * 256;
    float accq = qcb[c];
    float acck = kcb[c];
    const float4 wq = *(const float4*)(qcw + 4 * c);
    const float4 wk = *(const float4*)(kcw + 4 * c);
#pragma unroll
    for (int j = 0; j < 4; ++j) {
      const int tt = t - 3 + j;
      if (tt >= 0) {
        const float* Cr = Crow + (size_t)(j - 3) * NPROJ;
        accq = fmaf(((const float*)&wq)[j], Cr[c],       accq);
        acck = fmaf(((const float*)&wk)[j], Cr[512 + c], acck);
      }
    }
    qv[i] = siluf(accq); sq = fmaf(qv[i], qv[i], sq);
    kv[i] = siluf(acck); sk = fmaf(kv[i], kv[i], sk);
  }
  float2 pr = make_float2(sq, sk);
#pragma unroll
  for (int m = 1; m < 64; m <<= 1) { pr.x += __shfl_xor(pr.x, m); pr.y += __shfl_xor(pr.y, m); }
  if ((tid & 63) == 0) { red[(tid >> 6) * 2] = pr.x; red[(tid >> 6) * 2 + 1] = pr.y; }
  __syncthreads();
  const float SQ = red[0] + red[2] + red[4] + red[6];
  const float SK = red[1] + red[3] + red[5] + red[7];
  const float rnq = 1.f / fmaxf(sqrtf(SQ), 1e-12f);
  const float rnk = 1.f / fmaxf(sqrtf(SK), 1e-12f);
#pragma unroll
  for (int i = 0; i < 2; ++i) {
    const int c = tid + i * 256;
    qh[(size_t)bl * 512 + c] = qv[i] * rnq;
    kh[(size_t)bl * 512 + c] = kv[i] * rnk;
  }
#pragma unroll
  for (int i = 0; i < 4; ++i) {
    const int c = tid + i * 256;
    float accv = vcb[c];
    const float4 wv = *(const float4*)(vcw + 4 * c);
#pragma unroll
    for (int j = 0; j < 4; ++j) {
      const int tt = t - 3 + j;
      if (tt >= 0)
        accv = fmaf(((const float*)&wv)[j], Crow[(size_t)(j - 3) * NPROJ + 1024 + c], accv);
    }
    const float vvv = siluf(accv);
    if (c < 512) vm[(size_t)bl * 512 + c]         = vvv;
    else         vg[(size_t)bl * 512 + (c - 512)] = vvv;
  }
  if (tid < 4)       al[(size_t)bl * 4 + tid]       = sigf(Crow[2560 + tid]);
  else if (tid < 8)  be[(size_t)bl * 4 + (tid - 4)] = sigf(Crow[2564 + (tid - 4)]);
}

// ---------------- scan phase A: per-chunk WY decomposition ----------------
// 256 blocks = 32 chunks x 8 (b,h). Computes per chunk:
//   d_t = cumsum log a;  G = K K^T, Pq = Q K^T (MFMA bf16)
//   L_{ts} = b_t e^{d_t-d_s} G_{ts} (t>s)
//   solve (I+L)[W~|Z] = [diag(b e^d) K | diag(b) V]  (blocked f32 fwd subst.)
//   store W~ (bf16), Z (bf16), Phat = tril(Pq o e^{d_t-d_s}) (bf16),
//         KT = K^T (bf16), gamma_t = e^{d_t}, gc = e^{d_63}
//   plus f-scaled transposes for the transition kernel:
//         WTF(m,s) = f_s W~(s,m), ZF(i,s) = f_s Z(s,i), f_s = e^{d_63-d_s}
// Substitution is blocked in 4 groups of 16 rows: only u[16] lives in regs;
// solved blocks spill to LDS Xl[64][256] (lane-consecutive -> conflict-free,
// column j private to thread j). Xl aliases the K/Q staging (dead after MFMA).
__global__ __launch_bounds__(256)
void scan_phaseA_kernel(const float* __restrict__ qh, const float* __restrict__ kh,
                        const float* __restrict__ vm, const float* __restrict__ al,
                        const float* __restrict__ be,
                        short* __restrict__ WTB, short* __restrict__ ZB,
                        short* __restrict__ PHB, short* __restrict__ KTB,
                        float* __restrict__ GV, float* __restrict__ GC,
                        short* __restrict__ WTFB, short* __restrict__ ZFB)
{
  __shared__ char sm[83968];
  float* Xl = (float*)(sm);                             // [64][256] f32 (aliases KBl/QBl)
  __hip_bfloat16* KBl = (__hip_bfloat16*)(sm);          // [64][136]
  __hip_bfloat16* QBl = (__hip_bfloat16*)(sm + 17408);  // [64][136]
  float* Ll  = (float*)(sm + 65536);                    // [64][68]
  float* dv  = (float*)(sm + 82944);                    // [64]
  float* bv  = (float*)(sm + 83200);                    // [64]
  float* gbv = (float*)(sm + 83456);                    // [64]
  float* fvs = (float*)(sm + 83712);                    // [64]

  const int cb = blockIdx.x;
  const int bh = cb & 7, c = cb >> 3;
  const int b = bh >> 2, h = bh & 3;
  const int tid = threadIdx.x;
  const int lane = tid & 63;
  const int w = tid >> 6;
  const int lr = lane & 15, lk = lane >> 4;
  const size_t rowbase = (size_t)(b * LQ + c * CT) * 512 + h * 128;

  // stage K,Q -> LDS bf16 (padded rows of 136)
#pragma unroll
  for (int rep = 0; rep < 4; ++rep) {
    const int fid = tid + rep * 256;       // 0..1023
    const int r = fid >> 4;
    const int cg = (fid & 15) * 8;
    const float* kp = kh + rowbase + (size_t)r * 512 + cg;
    const float* qp = qh + rowbase + (size_t)r * 512 + cg;
    f32x4 k0 = *(const f32x4*)kp, k1 = *(const f32x4*)(kp + 4);
    f32x4 q0 = *(const f32x4*)qp, q1 = *(const f32x4*)(qp + 4);
    *(bf16x8*)(KBl + r * 136 + cg) = pack8(k0, k1);
    *(bf16x8*)(QBl + r * 136 + cg) = pack8(q0, q1);
  }
  // decay prefix (wave 0)
  if (w == 0) {
    float la = __logf(al[(size_t)(b * LQ + c * CT + lane) * 4 + h]);
    const float bb = be[(size_t)(b * LQ + c * CT + lane) * 4 + h];
#pragma unroll
    for (int off = 1; off < 64; off <<= 1) {
      const float tv = __shfl_up(la, off, 64);
      if (lane >= off) la += tv;
    }
    const float d63 = __shfl(la, 63, 64);
    dv[lane] = la; bv[lane] = bb; gbv[lane] = bb * __expf(la);
    fvs[lane] = __expf(d63 - la);
    GV[cb * 64 + lane] = __expf(la);
    if (lane == 0) GC[cb] = __expf(d63);
  }
  __syncthreads();

  // G = K K^T, Pq = Q K^T  (each wave owns one 16-row t-band)
  f32x4 aG[4] = {}, aP[4] = {};
#pragma unroll
  for (int ks = 0; ks < 4; ++ks) {
    bf16x8 bk[4];
#pragma unroll
    for (int nt = 0; nt < 4; ++nt)
      bk[nt] = *(const bf16x8*)(KBl + (nt * 16 + lr) * 136 + ks * 32 + lk * 8);
    const bf16x8 ak = *(const bf16x8*)(KBl + (w * 16 + lr) * 136 + ks * 32 + lk * 8);
    const bf16x8 aq = *(const bf16x8*)(QBl + (w * 16 + lr) * 136 + ks * 32 + lk * 8);
#pragma unroll
    for (int nt = 0; nt < 4; ++nt) {
      aG[nt] = MFMA16(ak, bk[nt], aG[nt]);
      aP[nt] = MFMA16(aq, bk[nt], aP[nt]);
    }
  }
#pragma unroll
  for (int nt = 0; nt < 4; ++nt)
#pragma unroll
    for (int jj = 0; jj < 4; ++jj) {
      const int t = w * 16 + lk * 4 + jj;
      const int s = nt * 16 + lr;
      const float eg = __expf(dv[t] - dv[s]);
      Ll[t * 68 + s] = (t > s) ? bv[t] * eg * aG[nt][jj] : 0.f;
      PHB[(size_t)cb * 4096 + t * 64 + s] = (s <= t) ? bf16s(eg * aP[nt][jj]) : (short)0;
    }
  __syncthreads();   // KBl/QBl dead from here -> Xl may overwrite

  // ---- blocked forward substitution: thread j owns column j ----
  const int j = tid;
  const float* src = (j < 128) ? kh : vm;
  const float* xp = src + rowbase + (j & 127);
  float* XlC = Xl + j;                 // private column, stride 256 floats
  short* dstN = (j < 128) ? (WTB + (size_t)cb * 8192 + j)
                          : (ZB  + (size_t)cb * 8192 + (j - 128));
  short* dstT = (j < 128) ? (WTFB + (size_t)cb * 8192 + (size_t)j * 64)
                          : (ZFB  + (size_t)cb * 8192 + (size_t)(j - 128) * 64);

  for (int r = 0; r < 4; ++r) {
    float u[16];
    // RHS block (scaled)
#pragma unroll
    for (int i = 0; i < 16; ++i) {
      const int t = r * 16 + i;
      u[i] = xp[(size_t)t * 512] * ((j < 128) ? gbv[t] : bv[t]);
    }
    // cross-block updates from already-solved 16-blocks (LDS spill)
    for (int sc = 0; sc < r; ++sc) {
      float xs[16];
#pragma unroll
      for (int k = 0; k < 16; ++k) xs[k] = XlC[(sc * 16 + k) * 256];
#pragma unroll
      for (int i = 0; i < 16; ++i) {
        const float* lrow = Ll + (r * 16 + i) * 68 + sc * 16;
        const f32x4 l0 = *(const f32x4*)(lrow);
        const f32x4 l1 = *(const f32x4*)(lrow + 4);
        const f32x4 l2 = *(const f32x4*)(lrow + 8);
        const f32x4 l3 = *(const f32x4*)(lrow + 12);
        f32x4 acc = {};
        acc.x = fmaf(l0.x, xs[0],  acc.x); acc.y = fmaf(l0.y, xs[1],  acc.y);
        acc.z = fmaf(l0.z, xs[2],  acc.z); acc.w = fmaf(l0.w, xs[3],  acc.w);
        acc.x = fmaf(l1.x, xs[4],  acc.x); acc.y = fmaf(l1.y, xs[5],  acc.y);
        acc.z = fmaf(l1.z, xs[6],  acc.z); acc.w = fmaf(l1.w, xs[7],  acc.w);
        acc.x = fmaf(l2.x, xs[8],  acc.x); acc.y = fmaf(l2.y, xs[9],  acc.y);
        acc.z = fmaf(l2.z, xs[10], acc.z); acc.w = fmaf(l2.w, xs[11], acc.w);
        acc.x = fmaf(l3.x, xs[12], acc.x); acc.y = fmaf(l3.y, xs[13], acc.y);
        acc.z = fmaf(l3.z, xs[14], acc.z); acc.w = fmaf(l3.w, xs[15], acc.w);
        u[i] -= (acc.x + acc.y) + (acc.z + acc.w);
      }
    }
    // in-block serial solve (rows above diag of Ll are zero)
#pragma unroll
    for (int i = 1; i < 16; ++i) {
      const float* lrow = Ll + (r * 16 + i) * 68 + r * 16;
      f32x4 acc = {};
#pragma unroll
      for (int k4 = 0; k4 < 4; ++k4) {
        if (k4 * 4 < i) {
          const f32x4 lv = *(const f32x4*)(lrow + k4 * 4);
          acc.x = fmaf(lv.x, u[k4 * 4 + 0], acc.x);
          acc.y = fmaf(lv.y, u[k4 * 4 + 1], acc.y);
          acc.z = fmaf(lv.z, u[k4 * 4 + 2], acc.z);
          acc.w = fmaf(lv.w, u[k4 * 4 + 3], acc.w);
        }
      }
      u[i] -= (acc.x + acc.y) + (acc.z + acc.w);
    }
    // spill for future blocks
    if (r < 3) {
#pragma unroll
      for (int i = 0; i < 16; ++i) XlC[(r * 16 + i) * 256] = u[i];
    }
    // stores: W~/Z (bf16, coalesced) and f-scaled transposed WTF/ZF
#pragma unroll
    for (int i = 0; i < 16; ++i)
      dstN[(r * 16 + i) * 128] = bf16s(u[i]);
#pragma unroll
    for (int s4 = 0; s4 < 4; ++s4) {
      s16x4 p;
#pragma unroll
      for (int e = 0; e < 4; ++e)
        p[e] = bf16s(fvs[r * 16 + s4 * 4 + e] * u[s4 * 4 + e]);
      *(s16x4*)(dstT + r * 16 + s4 * 4) = p;
    }
  }

  // KT = K^T (128 x 64 bf16)
  if (tid < 128) {
    const float* kp2 = kh + rowbase + tid;
#pragma unroll
    for (int s4 = 0; s4 < 16; ++s4) {
      s16x4 pk;
#pragma unroll
      for (int e = 0; e < 4; ++e)
        pk[e] = bf16s(kp2[(size_t)(s4 * 4 + e) * 512]);
      *(s16x4*)(KTB + (size_t)cb * 8192 + tid * 64 + s4 * 4) = pk;
    }
  }
}

// ---------------- scan transition: per-chunk affine factors ----------------
// S_{c+1} = S_c T_c + B_c  (rows of S evolve independently)
//   A(m,j)  = sum_s f_s W~(s,m) K(s,j);   T(m,j) = gc d(m,j) - A(m,j)
//   B(i,j)  = sum_s f_s Z(s,i)  K(s,j)
// Stored: TRB[cb][j][m] = T(m,j) (bf16, transposed for MFMA B-operand),
//         BF[cb][i][j] (f32).
// 256 blocks (one per cb), 4 waves; wave w owns a 32-row output band.
__global__ __launch_bounds__(256)
void scan_transition_kernel(const short* __restrict__ WTFB, const short* __restrict__ ZFB,
                            const short* __restrict__ KTB, const float* __restrict__ GC,
                            short* __restrict__ TRB, float* __restrict__ BF)
{
  const int cb = blockIdx.x;
  const int tid = threadIdx.x, lane = tid & 63, w = tid >> 6;
  const int lr = lane & 15, lk = lane >> 4;
  const float gc = GC[cb];

  // ---- AT(j,m) = sum_s KT(j,s) * WTF(m,s) ; then T^T(j,m) = gc d - AT(j,m)
  {
    f32x4 acc[2][8] = {};
#pragma unroll
    for (int ks = 0; ks < 2; ++ks) {
      bf16x8 a0 = *(const bf16x8*)(KTB + (size_t)cb * 8192 + (w * 32 + lr) * 64 + ks * 32 + lk * 8);
      bf16x8 a1 = *(const bf16x8*)(KTB + (size_t)cb * 8192 + (w * 32 + 16 + lr) * 64 + ks * 32 + lk * 8);
#pragma unroll
      for (int nt = 0; nt < 8; ++nt) {
        const bf16x8 bm = *(const bf16x8*)(WTFB + (size_t)cb * 8192 + (nt * 16 + lr) * 64 + ks * 32 + lk * 8);
        acc[0][nt] = MFMA16(a0, bm, acc[0][nt]);
        acc[1][nt] = MFMA16(a1, bm, acc[1][nt]);
      }
    }
#pragma unroll
    for (int mt = 0; mt < 2; ++mt)
#pragma unroll
      for (int nt = 0; nt < 8; ++nt)
#pragma unroll
        for (int jj = 0; jj < 4; ++jj) {
          const int jr = w * 32 + mt * 16 + lk * 4 + jj;
          const int m  = nt * 16 + lr;
          const float v = ((jr == m) ? gc : 0.f) - acc[mt][nt][jj];
          TRB[(size_t)cb * 16384 + jr * 128 + m] = bf16s(v);
        }
  }
  // ---- B(i,j) = sum_s ZF(i,s) * KT(j,s)
  {
    f32x4 acc[2][8] = {};
#pragma unroll
    for (int ks = 0; ks < 2; ++ks) {
      bf16x8 a0 = *(const bf16x8*)(ZFB + (size_t)cb * 8192 + (w * 32 + lr) * 64 + ks * 32 + lk * 8);
      bf16x8 a1 = *(const bf16x8*)(ZFB + (size_t)cb * 8192 + (w * 32 + 16 + lr) * 64 + ks * 32 + lk * 8);
#pragma unroll
      for (int nt = 0; nt < 8; ++nt) {
        const bf16x8 bj = *(const bf16x8*)(KTB + (size_t)cb * 8192 + (nt * 16 + lr) * 64 + ks * 32 + lk * 8);
        acc[0][nt] = MFMA16(a0, bj, acc[0][nt]);
        acc[1][nt] = MFMA16(a1, bj, acc[1][nt]);
      }
    }
#pragma unroll
    for (int mt = 0; mt < 2; ++mt)
#pragma unroll
      for (int nt = 0; nt < 8; ++nt)
#pragma unroll
        for (int jj = 0; jj < 4; ++jj) {
          const int ir = w * 32 + mt * 16 + lk * 4 + jj;
          const int jc = nt * 16 + lr;
          BF[(size_t)cb * 16384 + ir * 128 + jc] = acc[mt][nt][jj];
        }
  }
}

// ---------------- scan state: serial chunk recurrence, S rows independent ----
// 64 blocks = 8 (b,h) x 8 row-slabs of 16. Per chunk: store S_c (bf16) to
// SALL, S <- S*T + B with register-double-buffered prefetch of T_{c+1}/B_{c+1}.
#define L2_PREFETCH(BT, BA, CC) do {                                               \
  const int cbn_ = (CC) * 8 + bh;                                                  \
  _Pragma("unroll") for (int nt = 0; nt < 2; ++nt) {                               \
    _Pragma("unroll") for (int ks = 0; ks < 4; ++ks)                               \
      BT[nt][ks] = *(const bf16x8*)(TRB + (size_t)cbn_ * 16384 +                   \
                                    (w * 32 + nt * 16 + lr) * 128 + ks * 32 + lk * 8); \
    _Pragma("unroll") for (int jj = 0; jj < 4; ++jj)                               \
      BA[nt][jj] = BF[(size_t)cbn_ * 16384 + (r0 + lk * 4 + jj) * 128 +            \
                      w * 32 + nt * 16 + lr];                                      \
  }                                                                                \
} while (0)

#define L2_STEP(BT, BA, CC, PBT, PBA) do {                                         \
  const int cb_ = (CC) * 8 + bh;                                                   \
  { const int idx = tid * 8, r = idx >> 7, jc = idx & 127;                         \
    f32x4 s0 = *(const f32x4*)&Scur[r * 132 + jc];                                 \
    f32x4 s1 = *(const f32x4*)&Scur[r * 132 + jc + 4];                             \
    *(bf16x8*)(SALL + (size_t)cb_ * 16384 + (r0 + r) * 128 + jc) = pack8(s0, s1); }\
  bf16x8 af[4];                                                                    \
  _Pragma("unroll") for (int ks = 0; ks < 4; ++ks)                                 \
    af[ks] = pack8(*(const f32x4*)&Scur[lr * 132 + ks * 32 + lk * 8],              \
                   *(const f32x4*)&Scur[lr * 132 + ks * 32 + lk * 8 + 4]);         \
  if ((CC) < 31) L2_PREFETCH(PBT, PBA, (CC) + 1);                                  \
  f32x4 acc0 = {}, acc1 = {};                                                      \
  _Pragma("unroll") for (int ks = 0; ks < 4; ++ks) {                               \
    acc0 = MFMA16(af[ks], BT[0][ks], acc0);                                        \
    acc1 = MFMA16(af[ks], BT[1][ks], acc1);                                        \
  }                                                                                \
  _Pragma("unroll") for (int jj = 0; jj < 4; ++jj) {                               \
    Snxt[(lk * 4 + jj) * 132 + w * 32 + lr]      = acc0[jj] + BA[0][jj];           \
    Snxt[(lk * 4 + jj) * 132 + w * 32 + 16 + lr] = acc1[jj] + BA[1][jj];           \
  }                                                                                \
  __syncthreads();                                                                 \
  { float* t_ = Scur; Scur = Snxt; Snxt = t_; }                                    \
} while (0)

__global__ __launch_bounds__(256)
void scan_state_kernel(const short* __restrict__ TRB, const float* __restrict__ BF,
                       const float* __restrict__ st0, short* __restrict__ SALL,
                       float* __restrict__ stout)
{
  __shared__ float Sl[2 * 16 * 132];
  const int bid = blockIdx.x;            // 64
  const int bh = bid & 7, slab = bid >> 3;
  const int r0 = slab * 16;
  const int tid = threadIdx.x, lane = tid & 63, w = tid >> 6;
  const int lr = lane & 15, lk = lane >> 4;

  float* Scur = Sl;
  float* Snxt = Sl + 16 * 132;

  // load st0 slab
  {
    const int idx = tid * 8, r = idx >> 7, jc = idx & 127;
    const float* sp = st0 + ((size_t)bh * 128 + r0 + r) * 128 + jc;
    *(f32x4*)&Scur[r * 132 + jc]     = *(const f32x4*)sp;
    *(f32x4*)&Scur[r * 132 + jc + 4] = *(const f32x4*)(sp + 4);
  }
  bf16x8 btA[2][4], btB[2][4];
  float  baA[2][4], baB[2][4];
  L2_PREFETCH(btA, baA, 0);
  __syncthreads();

  for (int c2 = 0; c2 < 16; ++c2) {
    L2_STEP(btA, baA, 2 * c2,     btB, baB);
    L2_STEP(btB, baB, 2 * c2 + 1, btA, baA);
  }

  // final state (Scur holds S_32 after 32 swaps)
  {
    const int idx = tid * 8, r = idx >> 7, jc = idx & 127;
    float* sp = stout + ((size_t)bh * 128 + r0 + r) * 128 + jc;
    *(f32x4*)sp       = *(const f32x4*)&Scur[r * 132 + jc];
    *(f32x4*)(sp + 4) = *(const f32x4*)&Scur[r * 132 + jc + 4];
  }
}

// ---------------- scan output: fully parallel over chunks ----------------
// 256 blocks (cb) x 512 threads (8 waves). waves 0-3: Y_up = Q S_c^T rows,
// waves 4-7: Y_low = W~ S_c^T rows -> U = Z - Y_low -> Ut (LDS); barrier;
// waves 0-3: O = diag(gv) Y_up + Phat U.
__global__ __launch_bounds__(512)
void scan_output_kernel(const float* __restrict__ qh,
                        const short* __restrict__ WTB, const __hip_bfloat16* __restrict__ ZB,
                        const short* __restrict__ PHB, const float* __restrict__ GV,
                        const short* __restrict__ SALL, float* __restrict__ obuf)
{
  __shared__ short Ut[128 * 72];
  const int cb = blockIdx.x;
  const int bh = cb & 7, c = cb >> 3;
  const int b = bh >> 2, h = bh & 3;
  const int tid = threadIdx.x, lane = tid & 63, w = tid >> 6;   // w 0..7
  const int lr = lane & 15, lk = lane >> 4;
  const int r0 = (w & 3) * 16;

  f32x4 Y[8] = {};
#pragma unroll
  for (int ks = 0; ks < 4; ++ks) {
    bf16x8 af;
    if (w < 4) {
      const float* qp = qh + ((size_t)(b * LQ + c * CT) + r0 + lr) * 512 + h * 128 + ks * 32 + lk * 8;
      af = pack8(*(const f32x4*)qp, *(const f32x4*)(qp + 4));
    } else {
      af = *(const bf16x8*)(WTB + (size_t)cb * 8192 + (r0 + lr) * 128 + ks * 32 + lk * 8);
    }
#pragma unroll
    for (int nt = 0; nt < 8; ++nt) {
      const bf16x8 bs = *(const bf16x8*)(SALL + (size_t)cb * 16384 + (nt * 16 + lr) * 128 + ks * 32 + lk * 8);
      Y[nt] = MFMA16(af, bs, Y[nt]);
    }
  }
  if (w >= 4) {   // U = Z - Y_low -> LDS (Ut[i][s])
#pragma unroll
    for (int nt = 0; nt < 8; ++nt) {
      const int i = nt * 16 + lr;
      s16x4 up;
#pragma unroll
      for (int jj = 0; jj < 4; ++jj) {
        const int s = r0 + lk * 4 + jj;
        const float z = __bfloat162float(ZB[(size_t)cb * 8192 + s * 128 + i]);
        up[jj] = bf16s(z - Y[nt][jj]);
      }
      *(s16x4*)&Ut[i * 72 + r0 + lk * 4] = up;
    }
  }
  __syncthreads();
  if (w < 4) {
    f32x4 P2[8] = {};
#pragma unroll
    for (int ks = 0; ks < 2; ++ks) {
      const bf16x8 ap = *(const bf16x8*)(PHB + (size_t)cb * 4096 + (r0 + lr) * 64 + ks * 32 + lk * 8);
#pragma unroll
      for (int nt = 0; nt < 8; ++nt) {
        const bf16x8 bu = *(const bf16x8*)&Ut[(nt * 16 + lr) * 72 + ks * 32 + lk * 8];
        P2[nt] = MFMA16(ap, bu, P2[nt]);
      }
    }
    float gvv[4];
#pragma unroll
    for (int jj = 0; jj < 4; ++jj) gvv[jj] = GV[cb * 64 + r0 + lk * 4 + jj];
#pragma unroll
    for (int nt = 0; nt < 8; ++nt) {
      const int i = nt * 16 + lr;
#pragma unroll
      for (int jj = 0; jj < 4; ++jj) {
        const int t = r0 + lk * 4 + jj;
        obuf[((size_t)(b * LQ + c * CT) + t) * 512 + h * 128 + i] =
            gvv[jj] * Y[nt][jj] + P2[nt][jj];
      }
    }
  }
}

// ---------------- gate * silu(g), LayerNorm(512), cast bf16 ----------------
__global__ __launch_bounds__(256)
void gate_ln_kernel(const float* __restrict__ obuf, const float* __restrict__ vg,
                    const float* __restrict__ C, const float* __restrict__ lnw,
                    const float* __restrict__ lnb, __hip_bfloat16* __restrict__ lno)
{
  const int bl = blockIdx.x, tid = threadIdx.x;
  __shared__ float red[8];
  float y[2]; float s = 0.f, s2 = 0.f;
#pragma unroll
  for (int i = 0; i < 2; ++i) {
    const int c = tid + i * 256;
    const float g = C[(size_t)bl * NPROJ + 2048 + c];
    const float v = obuf[(size_t)bl * 512 + c] * vg[(size_t)bl * 512 + c] * siluf(g);
    y[i] = v; s += v; s2 = fmaf(v, v, s2);
  }
  float2 pr = make_float2(s, s2);
#pragma unroll
  for (int m = 1; m < 64; m <<= 1) { pr.x += __shfl_xor(pr.x, m); pr.y += __shfl_xor(pr.y, m); }
  if ((tid & 63) == 0) { red[(tid >> 6) * 2] = pr.x; red[(tid >> 6) * 2 + 1] = pr.y; }
  __syncthreads();
  const float S  = red[0] + red[2] + red[4] + red[6];
  const float S2 = red[1] + red[3] + red[5] + red[7];
  const float mu  = S * (1.f / 512.f);
  const float var = S2 * (1.f / 512.f) - mu * mu;
  const float rs  = rsqrtf(var + 1e-5f);
#pragma unroll
  for (int i = 0; i < 2; ++i) {
    const int c = tid + i * 256;
    lno[(size_t)bl * 512 + c] = __float2bfloat16(fmaf((y[i] - mu) * rs, lnw[c], lnb[c]));
  }
}

extern "C" void kernel_launch(void* const* d_in, const int* in_sizes, int n_in,
                              void* d_out, int out_size, void* d_ws, size_t ws_size,
                              hipStream_t stream)
{
  (void)in_sizes; (void)n_in; (void)out_size; (void)ws_size;
  const float* x    = (const float*)d_in[0];
  const float* st0  = (const float*)d_in[1];
  const float* Wq   = (const float*)d_in[2];
  const float* Wk   = (const float*)d_in[3];
  const float* Wv   = (const float*)d_in[4];
  const float* Wa   = (const float*)d_in[5];
  const float* Wb   = (const float*)d_in[6];
  const float* Wg   = (const float*)d_in[7];
  const float* Wo   = (const float*)d_in[8];
  const float* qcw  = (const float*)d_in[9];
  const float* qcb  = (const float*)d_in[10];
  const float* kcw  = (const float*)d_in[11];
  const float* kcb  = (const float*)d_in[12];
  const float* vcw  = (const float*)d_in[13];
  const float* vcb  = (const float*)d_in[14];
  const float* lnw  = (const float*)d_in[15];
  const float* lnb  = (const float*)d_in[16];
  float* out = (float*)d_out;

  // workspace layout (bytes); high-water ~124.3 MB
  char* ws = (char*)d_ws;
  __hip_bfloat16* XB   = (__hip_bfloat16*)(ws + 0);            // 4096x1024 bf16 (dead after proj GEMM)
  __hip_bfloat16* LNO  = (__hip_bfloat16*)(ws + 0);            // 4096x512 bf16 (aliases XB 1st half, written at gate_ln)
  short*          WTFB = (short*)(ws + 0);                     // [256][128][64] bf16 (aliases XB 1st half; phaseA->transition window)
  short*          WTB  = (short*)(ws + 4194304);               // [256][64][128] bf16 (aliases XB 2nd half)
  __hip_bfloat16* WCAT = (__hip_bfloat16*)(ws + 8388608);      // 2688x1024 bf16
  __hip_bfloat16* WOB  = (__hip_bfloat16*)(ws + 13893632);     // 1024x512  bf16
  float* CBUF = (float*)(ws + 14942208);                       // 4096x2688 f32
  float* QH   = (float*)(ws + 58982400);                       // 4096x512
  float* KH   = (float*)(ws + 67371008);
  float* BF   = (float*)(ws + 67371008);                       // [256][128][128] f32 (aliases KH+VM; written after phaseA)
  float* VM   = (float*)(ws + 75759616);
  float* VG   = (float*)(ws + 84148224);
  float* AL   = (float*)(ws + 92536832);                       // 4096x4
  float* BE   = (float*)(ws + 92602368);
  float* OBUF = (float*)(ws + 92667904);                       // 4096x512 (written by scan_output)
  short* TRB  = (short*)(ws + 92667904);                       // [256][128][128] bf16 (aliases OBUF; dead before scan_output)
  short* KTB  = (short*)(ws + 101056512);                      // [256][128][64] bf16
  short* PHB  = (short*)(ws + 105250816);                      // [256][64][64] bf16
  short* ZB   = (short*)(ws + 107347968);                      // [256][64][128] bf16
  float* GV   = (float*)(ws + 111542272);                      // [256][64]
  float* GC   = (float*)(ws + 111673344);                      // [256]
  short* ZFB  = (short*)(ws + 111674368);                      // [256][128][64] bf16
  short* SALL = (short*)(ws + 115868672);                      // [256][128][128] bf16 chunk-start states

  cast_f32_bf16_kernel<<<4096, 256, 0, stream>>>(x,  XB,  1048576);
  cast_f32_bf16_kernel<<<512,  256, 0, stream>>>(Wo, WOB, 131072);
  cast_wcat_kernel<<<10752, 256, 0, stream>>>(Wq, Wk, Wv, Wg, Wa, Wb, WCAT);

  gemm_bt_kernel<<<dim3(32, 21), 256, 0, stream>>>(XB, WCAT, CBUF, BLQ, NPROJ, KPROJ);

  conv_act_kernel<<<BLQ, 256, 0, stream>>>(CBUF, qcw, qcb, kcw, kcb, vcw, vcb,
                                           QH, KH, VM, VG, AL, BE);

  scan_phaseA_kernel<<<256, 256, 0, stream>>>(QH, KH, VM, AL, BE,
                                              WTB, ZB, PHB, KTB, GV, GC, WTFB, ZFB);

  scan_transition_kernel<<<256, 256, 0, stream>>>(WTFB, ZFB, KTB, GC, TRB, BF);

  scan_state_kernel<<<64, 256, 0, stream>>>(TRB, BF, st0, SALL, out + 4194304);

  scan_output_kernel<<<256, 512, 0, stream>>>(QH, WTB, (const __hip_bfloat16*)ZB,
                                              PHB, GV, SALL, OBUF);

  gate_ln_kernel<<<BLQ, 256, 0, stream>>>(OBUF, VG, CBUF, lnw, lnb, LNO);

  gemm_bt_kernel<<<dim3(32, 8), 256, 0, stream>>>(LNO, WOB, out, BLQ, DMQ, TOTQ);
}

// Round 6
// 168.606 us; speedup vs baseline: 1.9563x; 1.0659x over previous
//
#include <hip/hip_runtime.h>
#include <hip/hip_bf16.h>

// Problem constants
#define BQ    2
#define LQ    2048
#define DMQ   1024
#define HQ    4
#define DHQ   128
#define TOTQ  512
#define BLQ   4096      // B*L
#define NPROJ 2688      // padded concat: Wq(512) Wk(512) Wv(1024) Wg(512) Wa(4) Wb(4) pad(120)
#define KPROJ 1024
#define CT    64        // scan chunk length
#define NCH   32        // chunks (LQ/CT)

typedef short bf16x8 __attribute__((ext_vector_type(8)));
typedef short s16x4  __attribute__((ext_vector_type(4)));
typedef float f32x4  __attribute__((ext_vector_type(4)));

#define MFMA16(a, b, c) __builtin_amdgcn_mfma_f32_16x16x32_bf16(a, b, c, 0, 0, 0)

__device__ __forceinline__ float siluf(float x) { return x / (1.f + __expf(-x)); }
__device__ __forceinline__ float sigf(float x)  { return 1.f / (1.f + __expf(-x)); }
__device__ __forceinline__ short bf16s(float x) {
  return __builtin_bit_cast(short, __float2bfloat16(x));
}
__device__ __forceinline__ bf16x8 pack8(f32x4 a, f32x4 b) {
  bf16x8 r;
  r[0] = bf16s(a.x); r[1] = bf16s(a.y); r[2] = bf16s(a.z); r[3] = bf16s(a.w);
  r[4] = bf16s(b.x); r[5] = bf16s(b.y); r[6] = bf16s(b.z); r[7] = bf16s(b.w);
  return r;
}

// global -> LDS direct load, 16B per lane. LDS dest must be wave-uniform base;
// HW writes base + lane*16.
__device__ __forceinline__ void gload_lds16(const void* g, void* l) {
  __builtin_amdgcn_global_load_lds(
      (__attribute__((address_space(1))) void*)(unsigned long long)g,
      (__attribute__((address_space(3))) void*)(unsigned int)(unsigned long long)l,
      16, 0, 0);
}

// ---------------- casts ----------------
__global__ __launch_bounds__(256)
void cast_f32_bf16_kernel(const float* __restrict__ src, __hip_bfloat16* __restrict__ dst, int n4)
{
  int i = blockIdx.x * 256 + threadIdx.x;
  if (i < n4) {
    float4 v = ((const float4*)src)[i];
    __hip_bfloat16 o[4] = { __float2bfloat16(v.x), __float2bfloat16(v.y),
                            __float2bfloat16(v.z), __float2bfloat16(v.w) };
    *(ushort4*)((unsigned short*)dst + (size_t)i * 4) = *(ushort4*)o;
  }
}

__global__ __launch_bounds__(256)
void cast_wcat_kernel(const float* __restrict__ Wq, const float* __restrict__ Wk,
                      const float* __restrict__ Wv, const float* __restrict__ Wg,
                      const float* __restrict__ Wa, const float* __restrict__ Wb,
                      __hip_bfloat16* __restrict__ Wcat)
{
  int idx = blockIdx.x * 256 + threadIdx.x;      // 0 .. 2688*1024-1
  int row = idx >> 10, col = idx & 1023;
  float v;
  if      (row < 512)  v = Wq[idx];
  else if (row < 1024) v = Wk[idx - 512 * 1024];
  else if (row < 2048) v = Wv[idx - 1024 * 1024];
  else if (row < 2560) v = Wg[idx - 2048 * 1024];
  else if (row < 2564) v = Wa[(row - 2560) * 1024 + col];
  else if (row < 2568) v = Wb[(row - 2564) * 1024 + col];
  else                 v = 0.f;
  Wcat[idx] = __float2bfloat16(v);
}

// ---------------- bf16 MFMA GEMM: C(f32, MxN) = A(M,K) * B(N,K)^T ----------------
// 2-phase double-buffered LDS: issue next K-tile's global_load_lds BEFORE the
// current tile's ds_read+MFMA; the barrier's vmcnt drain lands exactly when the
// prefetched tile is needed, overlapping HBM/L2 latency with compute.
__global__ __launch_bounds__(256)
void gemm_bt_kernel(const __hip_bfloat16* __restrict__ A,
                    const __hip_bfloat16* __restrict__ Bw,
                    float* __restrict__ C, int M, int N, int K)
{
  __shared__ __hip_bfloat16 As[2 * 128 * 32];
  __shared__ __hip_bfloat16 Bs[2 * 128 * 32];
  const int tid  = threadIdx.x;
  const int lane = tid & 63;
  const int w    = tid >> 6;
  const int wm   = w >> 1, wn = w & 1;
  const int tm   = blockIdx.x, tn = blockIdx.y;
  const int lr   = lane & 15, lk = lane >> 4;

  f32x4 acc[4][4] = {};

  const int e0   = tid * 8;
  const int srow = e0 >> 5;        // 0..63
  const int scol = e0 & 31;
  const __hip_bfloat16* Ap = A  + (size_t)(tm * 128 + srow) * K + scol;
  const __hip_bfloat16* Bp = Bw + (size_t)(tn * 128 + srow) * K + scol;
  char* AsB  = (char*)As;
  char* BsB  = (char*)Bs;
  const size_t half = (size_t)64 * K;
  const int nk = K >> 5;

  // prologue: stage K-tile 0 into buffer 0
  {
    char* AsD = AsB + w * 1024;
    char* BsD = BsB + w * 1024;
    gload_lds16(Ap,        AsD);
    gload_lds16(Ap + half, AsD + 4096);
    gload_lds16(Bp,        BsD);
    gload_lds16(Bp + half, BsD + 4096);
  }
  __syncthreads();

  for (int it = 0; it < nk; ++it) {
    const int sel = it & 1;
    // prefetch next K-tile into the other buffer (no wait here)
    if (it + 1 < nk) {
      const int kk = (it + 1) * 32;
      char* AsD = AsB + ((sel ^ 1) * 8192) + w * 1024;
      char* BsD = BsB + ((sel ^ 1) * 8192) + w * 1024;
      gload_lds16(Ap + kk,        AsD);
      gload_lds16(Ap + half + kk, AsD + 4096);
      gload_lds16(Bp + kk,        BsD);
      gload_lds16(Bp + half + kk, BsD + 4096);
    }
    // compute on current buffer
    const char* AsR = AsB + sel * 8192;
    const char* BsR = BsB + sel * 8192;
    bf16x8 af[4], bfv[4];
#pragma unroll
    for (int m = 0; m < 4; ++m)
      af[m]  = *(const bf16x8*)(AsR + ((wm * 64 + m * 16 + lr) * 32 + lk * 8) * 2);
#pragma unroll
    for (int n = 0; n < 4; ++n)
      bfv[n] = *(const bf16x8*)(BsR + ((wn * 64 + n * 16 + lr) * 32 + lk * 8) * 2);
#pragma unroll
    for (int m = 0; m < 4; ++m)
#pragma unroll
      for (int n = 0; n < 4; ++n)
        acc[m][n] = MFMA16(af[m], bfv[n], acc[m][n]);
    // barrier (drains vmcnt): next tile resident, current buffer reusable
    __syncthreads();
  }

  const int crow0 = tm * 128 + wm * 64 + (lane >> 4) * 4;
  const int ccol0 = tn * 128 + wn * 64 + lr;
#pragma unroll
  for (int m = 0; m < 4; ++m)
#pragma unroll
    for (int n = 0; n < 4; ++n)
#pragma unroll
      for (int j = 0; j < 4; ++j)
        C[(size_t)(crow0 + m * 16 + j) * N + ccol0 + n * 16] = acc[m][n][j];
}

// ---------------- conv(4-tap causal) + silu + l2norm + sigmoid(a,b) ----------------
// Sliding-window over 8 consecutive timesteps per block (512 blocks): each
// thread holds an 11-row register window per owned channel -> 11 loads per
// 8 outputs instead of 32 (4x fewer CBUF re-reads; old layout re-fetched taps
// cross-XCD). Reduction order matches the old kernel bit-for-bit.
__global__ __launch_bounds__(256)
void conv_act_kernel(const float* __restrict__ C,
                     const float* __restrict__ qcw, const float* __restrict__ qcb,
                     const float* __restrict__ kcw, const float* __restrict__ kcb,
                     const float* __restrict__ vcw, const float* __restrict__ vcb,
                     float* __restrict__ qh, float* __restrict__ kh,
                     float* __restrict__ vm, float* __restrict__ vg,
                     float* __restrict__ al, float* __restrict__ be)
{
  const int blk = blockIdx.x;           // 512
  const int bl0 = blk * 8;              // global row start (never crosses b: 2048%8==0)
  const int t0  = bl0 & (LQ - 1);       // local t start
  const int tid = threadIdx.x;
  __shared__ float red[4][16];

  float qv[2][8], kv[2][8];
  float sq[8], sk[8];
#pragma unroll
  for (int t = 0; t < 8; ++t) { sq[t] = 0.f; sk[t] = 0.f; }

#pragma unroll
  for (int i = 0; i < 2; ++i) {
    const int c = tid + (i << 8);
    const float4 wq = *(const float4*)(qcw + 4 * c);
    const float4 wk = *(const float4*)(kcw + 4 * c);
    const float bq = qcb[c], bk = kcb[c];
    float wrq[11], wrk[11];
#pragma unroll
    for (int r = 0; r < 11; ++r) {
      const int tt = t0 - 3 + r;
      if (tt >= 0) {
        const float* Cr = C + (size_t)(bl0 - 3 + r) * NPROJ;
        wrq[r] = Cr[c];
        wrk[r] = Cr[512 + c];
      } else { wrq[r] = 0.f; wrk[r] = 0.f; }
    }
#pragma unroll
    for (int t = 0; t < 8; ++t) {
      float aq = bq, ak = bk;
#pragma unroll
      for (int j = 0; j < 4; ++j) {
        aq = fmaf(((const float*)&wq)[j], wrq[t + j], aq);
        ak = fmaf(((const float*)&wk)[j], wrk[t + j], ak);
      }
      const float qs = siluf(aq), ks = siluf(ak);
      qv[i][t] = qs; sq[t] = fmaf(qs, qs, sq[t]);
      kv[i][t] = ks; sk[t] = fmaf(ks, ks, sk[t]);
    }
  }
  // reduce sq,sk across 64 lanes, then across 4 waves (same order as before)
#pragma unroll
  for (int m = 1; m < 64; m <<= 1) {
#pragma unroll
    for (int t = 0; t < 8; ++t) {
      sq[t] += __shfl_xor(sq[t], m);
      sk[t] += __shfl_xor(sk[t], m);
    }
  }
  {
    const int w = tid >> 6, lane = tid & 63;
    if (lane == 0) {
#pragma unroll
      for (int t = 0; t < 8; ++t) { red[w][t] = sq[t]; red[w][8 + t] = sk[t]; }
    }
  }
  __syncthreads();
  float rnq[8], rnk[8];
#pragma unroll
  for (int t = 0; t < 8; ++t) {
    const float SQ = red[0][t] + red[1][t] + red[2][t] + red[3][t];
    const float SK = red[0][8 + t] + red[1][8 + t] + red[2][8 + t] + red[3][8 + t];
    rnq[t] = 1.f / fmaxf(sqrtf(SQ), 1e-12f);
    rnk[t] = 1.f / fmaxf(sqrtf(SK), 1e-12f);
  }
#pragma unroll
  for (int i = 0; i < 2; ++i) {
    const int c = tid + (i << 8);
#pragma unroll
    for (int t = 0; t < 8; ++t) {
      qh[(size_t)(bl0 + t) * 512 + c] = qv[i][t] * rnq[t];
      kh[(size_t)(bl0 + t) * 512 + c] = kv[i][t] * rnk[t];
    }
  }
  // v: 4 channels per thread, streamed one channel at a time
#pragma unroll
  for (int i = 0; i < 4; ++i) {
    const int c = tid + (i << 8);
    const float4 wv = *(const float4*)(vcw + 4 * c);
    const float bvv = vcb[c];
    float wr[11];
#pragma unroll
    for (int r = 0; r < 11; ++r) {
      const int tt = t0 - 3 + r;
      wr[r] = (tt >= 0) ? C[(size_t)(bl0 - 3 + r) * NPROJ + 1024 + c] : 0.f;
    }
#pragma unroll
    for (int t = 0; t < 8; ++t) {
      float acc = bvv;
#pragma unroll
      for (int j = 0; j < 4; ++j)
        acc = fmaf(((const float*)&wv)[j], wr[t + j], acc);
      const float vvv = siluf(acc);
      if (c < 512) vm[(size_t)(bl0 + t) * 512 + c]         = vvv;
      else         vg[(size_t)(bl0 + t) * 512 + (c - 512)] = vvv;
    }
  }
  // alpha/beta: threads 0..63 cover 8 t x (4 al + 4 be)
  if (tid < 64) {
    const int t = tid >> 3;
    const int k = tid & 7;
    const float* Cr = C + (size_t)(bl0 + t) * NPROJ;
    if (k < 4) al[(size_t)(bl0 + t) * 4 + k]       = sigf(Cr[2560 + k]);
    else       be[(size_t)(bl0 + t) * 4 + (k - 4)] = sigf(Cr[2564 + (k - 4)]);
  }
}

// ---------------- scan phase A: per-chunk WY decomposition ----------------
// 256 blocks = 32 chunks x 8 (b,h). Computes per chunk:
//   d_t = cumsum log a;  G = K K^T, Pq = Q K^T (MFMA bf16)
//   L_{ts} = b_t e^{d_t-d_s} G_{ts} (t>s)
//   solve (I+L)[W~|Z] = [diag(b e^d) K | diag(b) V]  (blocked f32 fwd subst.)
//   store W~ (bf16), Z (bf16), Phat = tril(Pq o e^{d_t-d_s}) (bf16),
//         KT = K^T (bf16), gamma_t = e^{d_t}, gc = e^{d_63}
//   plus f-scaled transposes for the transition kernel:
//         WTF(m,s) = f_s W~(s,m), ZF(i,s) = f_s Z(s,i), f_s = e^{d_63-d_s}
// Substitution is blocked in 4 groups of 16 rows: only u[16] lives in regs;
// solved blocks spill to LDS Xl[64][256] (lane-consecutive -> conflict-free,
// column j private to thread j). Xl aliases the K/Q staging (dead after MFMA).
__global__ __launch_bounds__(256)
void scan_phaseA_kernel(const float* __restrict__ qh, const float* __restrict__ kh,
                        const float* __restrict__ vm, const float* __restrict__ al,
                        const float* __restrict__ be,
                        short* __restrict__ WTB, short* __restrict__ ZB,
                        short* __restrict__ PHB, short* __restrict__ KTB,
                        float* __restrict__ GV, float* __restrict__ GC,
                        short* __restrict__ WTFB, short* __restrict__ ZFB)
{
  __shared__ char sm[83968];
  float* Xl = (float*)(sm);                             // [64][256] f32 (aliases KBl/QBl)
  __hip_bfloat16* KBl = (__hip_bfloat16*)(sm);          // [64][136]
  __hip_bfloat16* QBl = (__hip_bfloat16*)(sm + 17408);  // [64][136]
  float* Ll  = (float*)(sm + 65536);                    // [64][68]
  float* dv  = (float*)(sm + 82944);                    // [64]
  float* bv  = (float*)(sm + 83200);                    // [64]
  float* gbv = (float*)(sm + 83456);                    // [64]
  float* fvs = (float*)(sm + 83712);                    // [64]

  const int cb = blockIdx.x;
  const int bh = cb & 7, c = cb >> 3;
  const int b = bh >> 2, h = bh & 3;
  const int tid = threadIdx.x;
  const int lane = tid & 63;
  const int w = tid >> 6;
  const int lr = lane & 15, lk = lane >> 4;
  const size_t rowbase = (size_t)(b * LQ + c * CT) * 512 + h * 128;

  // stage K,Q -> LDS bf16 (padded rows of 136)
#pragma unroll
  for (int rep = 0; rep < 4; ++rep) {
    const int fid = tid + rep * 256;       // 0..1023
    const int r = fid >> 4;
    const int cg = (fid & 15) * 8;
    const float* kp = kh + rowbase + (size_t)r * 512 + cg;
    const float* qp = qh + rowbase + (size_t)r * 512 + cg;
    f32x4 k0 = *(const f32x4*)kp, k1 = *(const f32x4*)(kp + 4);
    f32x4 q0 = *(const f32x4*)qp, q1 = *(const f32x4*)(qp + 4);
    *(bf16x8*)(KBl + r * 136 + cg) = pack8(k0, k1);
    *(bf16x8*)(QBl + r * 136 + cg) = pack8(q0, q1);
  }
  // decay prefix (wave 0)
  if (w == 0) {
    float la = __logf(al[(size_t)(b * LQ + c * CT + lane) * 4 + h]);
    const float bb = be[(size_t)(b * LQ + c * CT + lane) * 4 + h];
#pragma unroll
    for (int off = 1; off < 64; off <<= 1) {
      const float tv = __shfl_up(la, off, 64);
      if (lane >= off) la += tv;
    }
    const float d63 = __shfl(la, 63, 64);
    dv[lane] = la; bv[lane] = bb; gbv[lane] = bb * __expf(la);
    fvs[lane] = __expf(d63 - la);
    GV[cb * 64 + lane] = __expf(la);
    if (lane == 0) GC[cb] = __expf(d63);
  }
  __syncthreads();

  // G = K K^T, Pq = Q K^T  (each wave owns one 16-row t-band)
  f32x4 aG[4] = {}, aP[4] = {};
#pragma unroll
  for (int ks = 0; ks < 4; ++ks) {
    bf16x8 bk[4];
#pragma unroll
    for (int nt = 0; nt < 4; ++nt)
      bk[nt] = *(const bf16x8*)(KBl + (nt * 16 + lr) * 136 + ks * 32 + lk * 8);
    const bf16x8 ak = *(const bf16x8*)(KBl + (w * 16 + lr) * 136 + ks * 32 + lk * 8);
    const bf16x8 aq = *(const bf16x8*)(QBl + (w * 16 + lr) * 136 + ks * 32 + lk * 8);
#pragma unroll
    for (int nt = 0; nt < 4; ++nt) {
      aG[nt] = MFMA16(ak, bk[nt], aG[nt]);
      aP[nt] = MFMA16(aq, bk[nt], aP[nt]);
    }
  }
#pragma unroll
  for (int nt = 0; nt < 4; ++nt)
#pragma unroll
    for (int jj = 0; jj < 4; ++jj) {
      const int t = w * 16 + lk * 4 + jj;
      const int s = nt * 16 + lr;
      const float eg = __expf(dv[t] - dv[s]);
      Ll[t * 68 + s] = (t > s) ? bv[t] * eg * aG[nt][jj] : 0.f;
      PHB[(size_t)cb * 4096 + t * 64 + s] = (s <= t) ? bf16s(eg * aP[nt][jj]) : (short)0;
    }
  __syncthreads();   // KBl/QBl dead from here -> Xl may overwrite

  // ---- blocked forward substitution: thread j owns column j ----
  const int j = tid;
  const float* src = (j < 128) ? kh : vm;
  const float* xp = src + rowbase + (j & 127);
  float* XlC = Xl + j;                 // private column, stride 256 floats
  short* dstN = (j < 128) ? (WTB + (size_t)cb * 8192 + j)
                          : (ZB  + (size_t)cb * 8192 + (j - 128));
  short* dstT = (j < 128) ? (WTFB + (size_t)cb * 8192 + (size_t)j * 64)
                          : (ZFB  + (size_t)cb * 8192 + (size_t)(j - 128) * 64);

  for (int r = 0; r < 4; ++r) {
    float u[16];
    // RHS block (scaled)
#pragma unroll
    for (int i = 0; i < 16; ++i) {
      const int t = r * 16 + i;
      u[i] = xp[(size_t)t * 512] * ((j < 128) ? gbv[t] : bv[t]);
    }
    // cross-block updates from already-solved 16-blocks (LDS spill)
    for (int sc = 0; sc < r; ++sc) {
      float xs[16];
#pragma unroll
      for (int k = 0; k < 16; ++k) xs[k] = XlC[(sc * 16 + k) * 256];
#pragma unroll
      for (int i = 0; i < 16; ++i) {
        const float* lrow = Ll + (r * 16 + i) * 68 + sc * 16;
        const f32x4 l0 = *(const f32x4*)(lrow);
        const f32x4 l1 = *(const f32x4*)(lrow + 4);
        const f32x4 l2 = *(const f32x4*)(lrow + 8);
        const f32x4 l3 = *(const f32x4*)(lrow + 12);
        f32x4 acc = {};
        acc.x = fmaf(l0.x, xs[0],  acc.x); acc.y = fmaf(l0.y, xs[1],  acc.y);
        acc.z = fmaf(l0.z, xs[2],  acc.z); acc.w = fmaf(l0.w, xs[3],  acc.w);
        acc.x = fmaf(l1.x, xs[4],  acc.x); acc.y = fmaf(l1.y, xs[5],  acc.y);
        acc.z = fmaf(l1.z, xs[6],  acc.z); acc.w = fmaf(l1.w, xs[7],  acc.w);
        acc.x = fmaf(l2.x, xs[8],  acc.x); acc.y = fmaf(l2.y, xs[9],  acc.y);
        acc.z = fmaf(l2.z, xs[10], acc.z); acc.w = fmaf(l2.w, xs[11], acc.w);
        acc.x = fmaf(l3.x, xs[12], acc.x); acc.y = fmaf(l3.y, xs[13], acc.y);
        acc.z = fmaf(l3.z, xs[14], acc.z); acc.w = fmaf(l3.w, xs[15], acc.w);
        u[i] -= (acc.x + acc.y) + (acc.z + acc.w);
      }
    }
    // in-block serial solve (rows above diag of Ll are zero)
#pragma unroll
    for (int i = 1; i < 16; ++i) {
      const float* lrow = Ll + (r * 16 + i) * 68 + r * 16;
      f32x4 acc = {};
#pragma unroll
      for (int k4 = 0; k4 < 4; ++k4) {
        if (k4 * 4 < i) {
          const f32x4 lv = *(const f32x4*)(lrow + k4 * 4);
          acc.x = fmaf(lv.x, u[k4 * 4 + 0], acc.x);
          acc.y = fmaf(lv.y, u[k4 * 4 + 1], acc.y);
          acc.z = fmaf(lv.z, u[k4 * 4 + 2], acc.z);
          acc.w = fmaf(lv.w, u[k4 * 4 + 3], acc.w);
        }
      }
      u[i] -= (acc.x + acc.y) + (acc.z + acc.w);
    }
    // spill for future blocks
    if (r < 3) {
#pragma unroll
      for (int i = 0; i < 16; ++i) XlC[(r * 16 + i) * 256] = u[i];
    }
    // stores: W~/Z (bf16, coalesced) and f-scaled transposed WTF/ZF
#pragma unroll
    for (int i = 0; i < 16; ++i)
      dstN[(r * 16 + i) * 128] = bf16s(u[i]);
#pragma unroll
    for (int s4 = 0; s4 < 4; ++s4) {
      s16x4 p;
#pragma unroll
      for (int e = 0; e < 4; ++e)
        p[e] = bf16s(fvs[r * 16 + s4 * 4 + e] * u[s4 * 4 + e]);
      *(s16x4*)(dstT + r * 16 + s4 * 4) = p;
    }
  }

  // KT = K^T (128 x 64 bf16)
  if (tid < 128) {
    const float* kp2 = kh + rowbase + tid;
#pragma unroll
    for (int s4 = 0; s4 < 16; ++s4) {
      s16x4 pk;
#pragma unroll
      for (int e = 0; e < 4; ++e)
        pk[e] = bf16s(kp2[(size_t)(s4 * 4 + e) * 512]);
      *(s16x4*)(KTB + (size_t)cb * 8192 + tid * 64 + s4 * 4) = pk;
    }
  }
}

// ---------------- scan transition: per-chunk affine factors ----------------
// S_{c+1} = S_c T_c + B_c  (rows of S evolve independently)
//   A(m,j)  = sum_s f_s W~(s,m) K(s,j);   T(m,j) = gc d(m,j) - A(m,j)
//   B(i,j)  = sum_s f_s Z(s,i)  K(s,j)
// Stored: TRB[cb][j][m] = T(m,j) (bf16, transposed for MFMA B-operand),
//         BF[cb][i][j] (f32).
// 256 blocks (one per cb), 4 waves; wave w owns a 32-row output band.
__global__ __launch_bounds__(256)
void scan_transition_kernel(const short* __restrict__ WTFB, const short* __restrict__ ZFB,
                            const short* __restrict__ KTB, const float* __restrict__ GC,
                            short* __restrict__ TRB, float* __restrict__ BF)
{
  const int cb = blockIdx.x;
  const int tid = threadIdx.x, lane = tid & 63, w = tid >> 6;
  const int lr = lane & 15, lk = lane >> 4;
  const float gc = GC[cb];

  // ---- AT(j,m) = sum_s KT(j,s) * WTF(m,s) ; then T^T(j,m) = gc d - AT(j,m)
  {
    f32x4 acc[2][8] = {};
#pragma unroll
    for (int ks = 0; ks < 2; ++ks) {
      bf16x8 a0 = *(const bf16x8*)(KTB + (size_t)cb * 8192 + (w * 32 + lr) * 64 + ks * 32 + lk * 8);
      bf16x8 a1 = *(const bf16x8*)(KTB + (size_t)cb * 8192 + (w * 32 + 16 + lr) * 64 + ks * 32 + lk * 8);
#pragma unroll
      for (int nt = 0; nt < 8; ++nt) {
        const bf16x8 bm = *(const bf16x8*)(WTFB + (size_t)cb * 8192 + (nt * 16 + lr) * 64 + ks * 32 + lk * 8);
        acc[0][nt] = MFMA16(a0, bm, acc[0][nt]);
        acc[1][nt] = MFMA16(a1, bm, acc[1][nt]);
      }
    }
#pragma unroll
    for (int mt = 0; mt < 2; ++mt)
#pragma unroll
      for (int nt = 0; nt < 8; ++nt)
#pragma unroll
        for (int jj = 0; jj < 4; ++jj) {
          const int jr = w * 32 + mt * 16 + lk * 4 + jj;
          const int m  = nt * 16 + lr;
          const float v = ((jr == m) ? gc : 0.f) - acc[mt][nt][jj];
          TRB[(size_t)cb * 16384 + jr * 128 + m] = bf16s(v);
        }
  }
  // ---- B(i,j) = sum_s ZF(i,s) * KT(j,s)
  {
    f32x4 acc[2][8] = {};
#pragma unroll
    for (int ks = 0; ks < 2; ++ks) {
      bf16x8 a0 = *(const bf16x8*)(ZFB + (size_t)cb * 8192 + (w * 32 + lr) * 64 + ks * 32 + lk * 8);
      bf16x8 a1 = *(const bf16x8*)(ZFB + (size_t)cb * 8192 + (w * 32 + 16 + lr) * 64 + ks * 32 + lk * 8);
#pragma unroll
      for (int nt = 0; nt < 8; ++nt) {
        const bf16x8 bj = *(const bf16x8*)(KTB + (size_t)cb * 8192 + (nt * 16 + lr) * 64 + ks * 32 + lk * 8);
        acc[0][nt] = MFMA16(a0, bj, acc[0][nt]);
        acc[1][nt] = MFMA16(a1, bj, acc[1][nt]);
      }
    }
#pragma unroll
    for (int mt = 0; mt < 2; ++mt)
#pragma unroll
      for (int nt = 0; nt < 8; ++nt)
#pragma unroll
        for (int jj = 0; jj < 4; ++jj) {
          const int ir = w * 32 + mt * 16 + lk * 4 + jj;
          const int jc = nt * 16 + lr;
          BF[(size_t)cb * 16384 + ir * 128 + jc] = acc[mt][nt][jj];
        }
  }
}

// ---------------- scan state: serial chunk recurrence, S rows independent ----
// 64 blocks = 8 (b,h) x 8 row-slabs of 16. Per chunk: store S_c (bf16) to
// SALL, S <- S*T + B with register-double-buffered prefetch of T_{c+1}/B_{c+1}.
#define L2_PREFETCH(BT, BA, CC) do {                                               \
  const int cbn_ = (CC) * 8 + bh;                                                  \
  _Pragma("unroll") for (int nt = 0; nt < 2; ++nt) {                               \
    _Pragma("unroll") for (int ks = 0; ks < 4; ++ks)                               \
      BT[nt][ks] = *(const bf16x8*)(TRB + (size_t)cbn_ * 16384 +                   \
                                    (w * 32 + nt * 16 + lr) * 128 + ks * 32 + lk * 8); \
    _Pragma("unroll") for (int jj = 0; jj < 4; ++jj)                               \
      BA[nt][jj] = BF[(size_t)cbn_ * 16384 + (r0 + lk * 4 + jj) * 128 +            \
                      w * 32 + nt * 16 + lr];                                      \
  }                                                                                \
} while (0)

#define L2_STEP(BT, BA, CC, PBT, PBA) do {                                         \
  const int cb_ = (CC) * 8 + bh;                                                   \
  { const int idx = tid * 8, r = idx >> 7, jc = idx & 127;                         \
    f32x4 s0 = *(const f32x4*)&Scur[r * 132 + jc];                                 \
    f32x4 s1 = *(const f32x4*)&Scur[r * 132 + jc + 4];                             \
    *(bf16x8*)(SALL + (size_t)cb_ * 16384 + (r0 + r) * 128 + jc) = pack8(s0, s1); }\
  bf16x8 af[4];                                                                    \
  _Pragma("unroll") for (int ks = 0; ks < 4; ++ks)                                 \
    af[ks] = pack8(*(const f32x4*)&Scur[lr * 132 + ks * 32 + lk * 8],              \
                   *(const f32x4*)&Scur[lr * 132 + ks * 32 + lk * 8 + 4]);         \
  if ((CC) < 31) L2_PREFETCH(PBT, PBA, (CC) + 1);                                  \
  f32x4 acc0 = {}, acc1 = {};                                                      \
  _Pragma("unroll") for (int ks = 0; ks < 4; ++ks) {                               \
    acc0 = MFMA16(af[ks], BT[0][ks], acc0);                                        \
    acc1 = MFMA16(af[ks], BT[1][ks], acc1);                                        \
  }                                                                                \
  _Pragma("unroll") for (int jj = 0; jj < 4; ++jj) {                               \
    Snxt[(lk * 4 + jj) * 132 + w * 32 + lr]      = acc0[jj] + BA[0][jj];           \
    Snxt[(lk * 4 + jj) * 132 + w * 32 + 16 + lr] = acc1[jj] + BA[1][jj];           \
  }                                                                                \
  __syncthreads();                                                                 \
  { float* t_ = Scur; Scur = Snxt; Snxt = t_; }                                    \
} while (0)

__global__ __launch_bounds__(256)
void scan_state_kernel(const short* __restrict__ TRB, const float* __restrict__ BF,
                       const float* __restrict__ st0, short* __restrict__ SALL,
                       float* __restrict__ stout)
{
  __shared__ float Sl[2 * 16 * 132];
  const int bid = blockIdx.x;            // 64
  const int bh = bid & 7, slab = bid >> 3;
  const int r0 = slab * 16;
  const int tid = threadIdx.x, lane = tid & 63, w = tid >> 6;
  const int lr = lane & 15, lk = lane >> 4;

  float* Scur = Sl;
  float* Snxt = Sl + 16 * 132;

  // load st0 slab
  {
    const int idx = tid * 8, r = idx >> 7, jc = idx & 127;
    const float* sp = st0 + ((size_t)bh * 128 + r0 + r) * 128 + jc;
    *(f32x4*)&Scur[r * 132 + jc]     = *(const f32x4*)sp;
    *(f32x4*)&Scur[r * 132 + jc + 4] = *(const f32x4*)(sp + 4);
  }
  bf16x8 btA[2][4], btB[2][4];
  float  baA[2][4], baB[2][4];
  L2_PREFETCH(btA, baA, 0);
  __syncthreads();

  for (int c2 = 0; c2 < 16; ++c2) {
    L2_STEP(btA, baA, 2 * c2,     btB, baB);
    L2_STEP(btB, baB, 2 * c2 + 1, btA, baA);
  }

  // final state (Scur holds S_32 after 32 swaps)
  {
    const int idx = tid * 8, r = idx >> 7, jc = idx & 127;
    float* sp = stout + ((size_t)bh * 128 + r0 + r) * 128 + jc;
    *(f32x4*)sp       = *(const f32x4*)&Scur[r * 132 + jc];
    *(f32x4*)(sp + 4) = *(const f32x4*)&Scur[r * 132 + jc + 4];
  }
}

// ---------------- scan output: fully parallel over chunks ----------------
// 256 blocks (cb) x 512 threads (8 waves). waves 0-3: Y_up = Q S_c^T rows,
// waves 4-7: Y_low = W~ S_c^T rows -> U = Z - Y_low -> Ut (LDS); barrier;
// waves 0-3: O = diag(gv) Y_up + Phat U.
__global__ __launch_bounds__(512)
void scan_output_kernel(const float* __restrict__ qh,
                        const short* __restrict__ WTB, const __hip_bfloat16* __restrict__ ZB,
                        const short* __restrict__ PHB, const float* __restrict__ GV,
                        const short* __restrict__ SALL, float* __restrict__ obuf)
{
  __shared__ short Ut[128 * 72];
  const int cb = blockIdx.x;
  const int bh = cb & 7, c = cb >> 3;
  const int b = bh >> 2, h = bh & 3;
  const int tid = threadIdx.x, lane = tid & 63, w = tid >> 6;   // w 0..7
  const int lr = lane & 15, lk = lane >> 4;
  const int r0 = (w & 3) * 16;

  f32x4 Y[8] = {};
#pragma unroll
  for (int ks = 0; ks < 4; ++ks) {
    bf16x8 af;
    if (w < 4) {
      const float* qp = qh + ((size_t)(b * LQ + c * CT) + r0 + lr) * 512 + h * 128 + ks * 32 + lk * 8;
      af = pack8(*(const f32x4*)qp, *(const f32x4*)(qp + 4));
    } else {
      af = *(const bf16x8*)(WTB + (size_t)cb * 8192 + (r0 + lr) * 128 + ks * 32 + lk * 8);
    }
#pragma unroll
    for (int nt = 0; nt < 8; ++nt) {
      const bf16x8 bs = *(const bf16x8*)(SALL + (size_t)cb * 16384 + (nt * 16 + lr) * 128 + ks * 32 + lk * 8);
      Y[nt] = MFMA16(af, bs, Y[nt]);
    }
  }
  if (w >= 4) {   // U = Z - Y_low -> LDS (Ut[i][s])
#pragma unroll
    for (int nt = 0; nt < 8; ++nt) {
      const int i = nt * 16 + lr;
      s16x4 up;
#pragma unroll
      for (int jj = 0; jj < 4; ++jj) {
        const int s = r0 + lk * 4 + jj;
        const float z = __bfloat162float(ZB[(size_t)cb * 8192 + s * 128 + i]);
        up[jj] = bf16s(z - Y[nt][jj]);
      }
      *(s16x4*)&Ut[i * 72 + r0 + lk * 4] = up;
    }
  }
  __syncthreads();
  if (w < 4) {
    f32x4 P2[8] = {};
#pragma unroll
    for (int ks = 0; ks < 2; ++ks) {
      const bf16x8 ap = *(const bf16x8*)(PHB + (size_t)cb * 4096 + (r0 + lr) * 64 + ks * 32 + lk * 8);
#pragma unroll
      for (int nt = 0; nt < 8; ++nt) {
        const bf16x8 bu = *(const bf16x8*)&Ut[(nt * 16 + lr) * 72 + ks * 32 + lk * 8];
        P2[nt] = MFMA16(ap, bu, P2[nt]);
      }
    }
    float gvv[4];
#pragma unroll
    for (int jj = 0; jj < 4; ++jj) gvv[jj] = GV[cb * 64 + r0 + lk * 4 + jj];
#pragma unroll
    for (int nt = 0; nt < 8; ++nt) {
      const int i = nt * 16 + lr;
#pragma unroll
      for (int jj = 0; jj < 4; ++jj) {
        const int t = r0 + lk * 4 + jj;
        obuf[((size_t)(b * LQ + c * CT) + t) * 512 + h * 128 + i] =
            gvv[jj] * Y[nt][jj] + P2[nt][jj];
      }
    }
  }
}

// ---------------- gate * silu(g), LayerNorm(512), cast bf16 ----------------
__global__ __launch_bounds__(256)
void gate_ln_kernel(const float* __restrict__ obuf, const float* __restrict__ vg,
                    const float* __restrict__ C, const float* __restrict__ lnw,
                    const float* __restrict__ lnb, __hip_bfloat16* __restrict__ lno)
{
  const int bl = blockIdx.x, tid = threadIdx.x;
  __shared__ float red[8];
  float y[2]; float s = 0.f, s2 = 0.f;
#pragma unroll
  for (int i = 0; i < 2; ++i) {
    const int c = tid + i * 256;
    const float g = C[(size_t)bl * NPROJ + 2048 + c];
    const float v = obuf[(size_t)bl * 512 + c] * vg[(size_t)bl * 512 + c] * siluf(g);
    y[i] = v; s += v; s2 = fmaf(v, v, s2);
  }
  float2 pr = make_float2(s, s2);
#pragma unroll
  for (int m = 1; m < 64; m <<= 1) { pr.x += __shfl_xor(pr.x, m); pr.y += __shfl_xor(pr.y, m); }
  if ((tid & 63) == 0) { red[(tid >> 6) * 2] = pr.x; red[(tid >> 6) * 2 + 1] = pr.y; }
  __syncthreads();
  const float S  = red[0] + red[2] + red[4] + red[6];
  const float S2 = red[1] + red[3] + red[5] + red[7];
  const float mu  = S * (1.f / 512.f);
  const float var = S2 * (1.f / 512.f) - mu * mu;
  const float rs  = rsqrtf(var + 1e-5f);
#pragma unroll
  for (int i = 0; i < 2; ++i) {
    const int c = tid + i * 256;
    lno[(size_t)bl * 512 + c] = __float2bfloat16(fmaf((y[i] - mu) * rs, lnw[c], lnb[c]));
  }
}

extern "C" void kernel_launch(void* const* d_in, const int* in_sizes, int n_in,
                              void* d_out, int out_size, void* d_ws, size_t ws_size,
                              hipStream_t stream)
{
  (void)in_sizes; (void)n_in; (void)out_size; (void)ws_size;
  const float* x    = (const float*)d_in[0];
  const float* st0  = (const float*)d_in[1];
  const float* Wq   = (const float*)d_in[2];
  const float* Wk   = (const float*)d_in[3];
  const float* Wv   = (const float*)d_in[4];
  const float* Wa   = (const float*)d_in[5];
  const float* Wb   = (const float*)d_in[6];
  const float* Wg   = (const float*)d_in[7];
  const float* Wo   = (const float*)d_in[8];
  const float* qcw  = (const float*)d_in[9];
  const float* qcb  = (const float*)d_in[10];
  const float* kcw  = (const float*)d_in[11];
  const float* kcb  = (const float*)d_in[12];
  const float* vcw  = (const float*)d_in[13];
  const float* vcb  = (const float*)d_in[14];
  const float* lnw  = (const float*)d_in[15];
  const float* lnb  = (const float*)d_in[16];
  float* out = (float*)d_out;

  // workspace layout (bytes); high-water ~124.3 MB
  char* ws = (char*)d_ws;
  __hip_bfloat16* XB   = (__hip_bfloat16*)(ws + 0);            // 4096x1024 bf16 (dead after proj GEMM)
  __hip_bfloat16* LNO  = (__hip_bfloat16*)(ws + 0);            // 4096x512 bf16 (aliases XB 1st half, written at gate_ln)
  short*          WTFB = (short*)(ws + 0);                     // [256][128][64] bf16 (aliases XB 1st half; phaseA->transition window)
  short*          WTB  = (short*)(ws + 4194304);               // [256][64][128] bf16 (aliases XB 2nd half)
  __hip_bfloat16* WCAT = (__hip_bfloat16*)(ws + 8388608);      // 2688x1024 bf16
  __hip_bfloat16* WOB  = (__hip_bfloat16*)(ws + 13893632);     // 1024x512  bf16
  float* CBUF = (float*)(ws + 14942208);                       // 4096x2688 f32
  float* QH   = (float*)(ws + 58982400);                       // 4096x512
  float* KH   = (float*)(ws + 67371008);
  float* BF   = (float*)(ws + 67371008);                       // [256][128][128] f32 (aliases KH+VM; written after phaseA)
  float* VM   = (float*)(ws + 75759616);
  float* VG   = (float*)(ws + 84148224);
  float* AL   = (float*)(ws + 92536832);                       // 4096x4
  float* BE   = (float*)(ws + 92602368);
  float* OBUF = (float*)(ws + 92667904);                       // 4096x512 (written by scan_output)
  short* TRB  = (short*)(ws + 92667904);                       // [256][128][128] bf16 (aliases OBUF; dead before scan_output)
  short* KTB  = (short*)(ws + 101056512);                      // [256][128][64] bf16
  short* PHB  = (short*)(ws + 105250816);                      // [256][64][64] bf16
  short* ZB   = (short*)(ws + 107347968);                      // [256][64][128] bf16
  float* GV   = (float*)(ws + 111542272);                      // [256][64]
  float* GC   = (float*)(ws + 111673344);                      // [256]
  short* ZFB  = (short*)(ws + 111674368);                      // [256][128][64] bf16
  short* SALL = (short*)(ws + 115868672);                      // [256][128][128] bf16 chunk-start states

  cast_f32_bf16_kernel<<<4096, 256, 0, stream>>>(x,  XB,  1048576);
  cast_f32_bf16_kernel<<<512,  256, 0, stream>>>(Wo, WOB, 131072);
  cast_wcat_kernel<<<10752, 256, 0, stream>>>(Wq, Wk, Wv, Wg, Wa, Wb, WCAT);

  gemm_bt_kernel<<<dim3(32, 21), 256, 0, stream>>>(XB, WCAT, CBUF, BLQ, NPROJ, KPROJ);

  conv_act_kernel<<<512, 256, 0, stream>>>(CBUF, qcw, qcb, kcw, kcb, vcw, vcb,
                                           QH, KH, VM, VG, AL, BE);

  scan_phaseA_kernel<<<256, 256, 0, stream>>>(QH, KH, VM, AL, BE,
                                              WTB, ZB, PHB, KTB, GV, GC, WTFB, ZFB);

  scan_transition_kernel<<<256, 256, 0, stream>>>(WTFB, ZFB, KTB, GC, TRB, BF);

  scan_state_kernel<<<64, 256, 0, stream>>>(TRB, BF, st0, SALL, out + 4194304);

  scan_output_kernel<<<256, 512, 0, stream>>>(QH, WTB, (const __hip_bfloat16*)ZB,
                                              PHB, GV, SALL, OBUF);

  gate_ln_kernel<<<BLQ, 256, 0, stream>>>(OBUF, VG, CBUF, lnw, lnb, LNO);

  gemm_bt_kernel<<<dim3(32, 8), 256, 0, stream>>>(LNO, WOB, out, BLQ, DMQ, TOTQ);
}

// Round 7
// 165.968 us; speedup vs baseline: 1.9874x; 1.0159x over previous
//
#include <hip/hip_runtime.h>
#include <hip/hip_bf16.h>

// Problem constants
#define BQ    2
#define LQ    2048
#define DMQ   1024
#define HQ    4
#define DHQ   128
#define TOTQ  512
#define BLQ   4096      // B*L
#define NPROJ 2688      // padded concat: Wq(512) Wk(512) Wv(1024) Wg(512) Wa(4) Wb(4) pad(120)
#define KPROJ 1024
#define CT    64        // scan chunk length
#define NCH   32        // chunks (LQ/CT)

typedef short bf16x8 __attribute__((ext_vector_type(8)));
typedef short s16x4  __attribute__((ext_vector_type(4)));
typedef float f32x4  __attribute__((ext_vector_type(4)));

#define MFMA16(a, b, c) __builtin_amdgcn_mfma_f32_16x16x32_bf16(a, b, c, 0, 0, 0)

__device__ __forceinline__ float siluf(float x) { return x / (1.f + __expf(-x)); }
__device__ __forceinline__ float sigf(float x)  { return 1.f / (1.f + __expf(-x)); }
__device__ __forceinline__ short bf16s(float x) {
  return __builtin_bit_cast(short, __float2bfloat16(x));
}
__device__ __forceinline__ bf16x8 pack8(f32x4 a, f32x4 b) {
  bf16x8 r;
  r[0] = bf16s(a.x); r[1] = bf16s(a.y); r[2] = bf16s(a.z); r[3] = bf16s(a.w);
  r[4] = bf16s(b.x); r[5] = bf16s(b.y); r[6] = bf16s(b.z); r[7] = bf16s(b.w);
  return r;
}

// global -> LDS direct load, 16B per lane. LDS dest must be wave-uniform base;
// HW writes base + lane*16.
__device__ __forceinline__ void gload_lds16(const void* g, void* l) {
  __builtin_amdgcn_global_load_lds(
      (__attribute__((address_space(1))) void*)(unsigned long long)g,
      (__attribute__((address_space(3))) void*)(unsigned int)(unsigned long long)l,
      16, 0, 0);
}

// ---------------- casts ----------------
__global__ __launch_bounds__(256)
void cast_f32_bf16_kernel(const float* __restrict__ src, __hip_bfloat16* __restrict__ dst, int n4)
{
  int i = blockIdx.x * 256 + threadIdx.x;
  if (i < n4) {
    float4 v = ((const float4*)src)[i];
    __hip_bfloat16 o[4] = { __float2bfloat16(v.x), __float2bfloat16(v.y),
                            __float2bfloat16(v.z), __float2bfloat16(v.w) };
    *(ushort4*)((unsigned short*)dst + (size_t)i * 4) = *(ushort4*)o;
  }
}

// float4-vectorized concat cast (4 elems per thread, row-uniform branch)
__global__ __launch_bounds__(256)
void cast_wcat_kernel(const float* __restrict__ Wq, const float* __restrict__ Wk,
                      const float* __restrict__ Wv, const float* __restrict__ Wg,
                      const float* __restrict__ Wa, const float* __restrict__ Wb,
                      __hip_bfloat16* __restrict__ Wcat)
{
  int i4 = blockIdx.x * 256 + threadIdx.x;   // 0 .. 2688*256-1
  int row = i4 >> 8;
  int col = (i4 & 255) * 4;
  int idx = row * 1024 + col;
  float4 v;
  if      (row < 512)  v = *(const float4*)(Wq + idx);
  else if (row < 1024) v = *(const float4*)(Wk + idx - 512 * 1024);
  else if (row < 2048) v = *(const float4*)(Wv + idx - 1024 * 1024);
  else if (row < 2560) v = *(const float4*)(Wg + idx - 2048 * 1024);
  else if (row < 2564) v = *(const float4*)(Wa + (row - 2560) * 1024 + col);
  else if (row < 2568) v = *(const float4*)(Wb + (row - 2564) * 1024 + col);
  else                 v = make_float4(0.f, 0.f, 0.f, 0.f);
  __hip_bfloat16 o[4] = { __float2bfloat16(v.x), __float2bfloat16(v.y),
                          __float2bfloat16(v.z), __float2bfloat16(v.w) };
  *(ushort4*)((unsigned short*)Wcat + idx) = *(ushort4*)o;
}

// ---------------- bf16 MFMA GEMM: C(f32, MxN) = A(M,K) * B(N,K)^T ----------------
// 2-phase double-buffered LDS: issue next K-tile's global_load_lds BEFORE the
// current tile's ds_read+MFMA; the barrier's vmcnt drain lands exactly when the
// prefetched tile is needed, overlapping HBM/L2 latency with compute.
__global__ __launch_bounds__(256)
void gemm_bt_kernel(const __hip_bfloat16* __restrict__ A,
                    const __hip_bfloat16* __restrict__ Bw,
                    float* __restrict__ C, int M, int N, int K)
{
  __shared__ __hip_bfloat16 As[2 * 128 * 32];
  __shared__ __hip_bfloat16 Bs[2 * 128 * 32];
  const int tid  = threadIdx.x;
  const int lane = tid & 63;
  const int w    = tid >> 6;
  const int wm   = w >> 1, wn = w & 1;
  const int tm   = blockIdx.x, tn = blockIdx.y;
  const int lr   = lane & 15, lk = lane >> 4;

  f32x4 acc[4][4] = {};

  const int e0   = tid * 8;
  const int srow = e0 >> 5;        // 0..63
  const int scol = e0 & 31;
  const __hip_bfloat16* Ap = A  + (size_t)(tm * 128 + srow) * K + scol;
  const __hip_bfloat16* Bp = Bw + (size_t)(tn * 128 + srow) * K + scol;
  char* AsB  = (char*)As;
  char* BsB  = (char*)Bs;
  const size_t half = (size_t)64 * K;
  const int nk = K >> 5;

  // prologue: stage K-tile 0 into buffer 0
  {
    char* AsD = AsB + w * 1024;
    char* BsD = BsB + w * 1024;
    gload_lds16(Ap,        AsD);
    gload_lds16(Ap + half, AsD + 4096);
    gload_lds16(Bp,        BsD);
    gload_lds16(Bp + half, BsD + 4096);
  }
  __syncthreads();

  for (int it = 0; it < nk; ++it) {
    const int sel = it & 1;
    // prefetch next K-tile into the other buffer (no wait here)
    if (it + 1 < nk) {
      const int kk = (it + 1) * 32;
      char* AsD = AsB + ((sel ^ 1) * 8192) + w * 1024;
      char* BsD = BsB + ((sel ^ 1) * 8192) + w * 1024;
      gload_lds16(Ap + kk,        AsD);
      gload_lds16(Ap + half + kk, AsD + 4096);
      gload_lds16(Bp + kk,        BsD);
      gload_lds16(Bp + half + kk, BsD + 4096);
    }
    // compute on current buffer
    const char* AsR = AsB + sel * 8192;
    const char* BsR = BsB + sel * 8192;
    bf16x8 af[4], bfv[4];
#pragma unroll
    for (int m = 0; m < 4; ++m)
      af[m]  = *(const bf16x8*)(AsR + ((wm * 64 + m * 16 + lr) * 32 + lk * 8) * 2);
#pragma unroll
    for (int n = 0; n < 4; ++n)
      bfv[n] = *(const bf16x8*)(BsR + ((wn * 64 + n * 16 + lr) * 32 + lk * 8) * 2);
#pragma unroll
    for (int m = 0; m < 4; ++m)
#pragma unroll
      for (int n = 0; n < 4; ++n)
        acc[m][n] = MFMA16(af[m], bfv[n], acc[m][n]);
    // barrier (drains vmcnt): next tile resident, current buffer reusable
    __syncthreads();
  }

  const int crow0 = tm * 128 + wm * 64 + (lane >> 4) * 4;
  const int ccol0 = tn * 128 + wn * 64 + lr;
#pragma unroll
  for (int m = 0; m < 4; ++m)
#pragma unroll
    for (int n = 0; n < 4; ++n)
#pragma unroll
      for (int j = 0; j < 4; ++j)
        C[(size_t)(crow0 + m * 16 + j) * N + ccol0 + n * 16] = acc[m][n][j];
}

// ---------------- conv(4-tap causal) + silu + l2norm + sigmoid(a,b) ----------------
// Sliding-window over 8 timesteps per block (512 blocks), VECTORIZED:
// q/k: thread owns channels 2*tid,2*tid+1 (float2 loads/stores);
// v:   thread owns channels 4*tid..4*tid+3 (float4, wave-uniform vm/vg split).
__global__ __launch_bounds__(256)
void conv_act_kernel(const float* __restrict__ C,
                     const float* __restrict__ qcw, const float* __restrict__ qcb,
                     const float* __restrict__ kcw, const float* __restrict__ kcb,
                     const float* __restrict__ vcw, const float* __restrict__ vcb,
                     float* __restrict__ qh, float* __restrict__ kh,
                     float* __restrict__ vm, float* __restrict__ vg,
                     float* __restrict__ al, float* __restrict__ be)
{
  const int blk = blockIdx.x;           // 512
  const int bl0 = blk * 8;              // global row start (never crosses b: 2048%8==0)
  const int t0  = bl0 & (LQ - 1);       // local t start
  const int tid = threadIdx.x;
  __shared__ float red[4][16];

  float2 qv[8], kv[8];
  float sq[8], sk[8];
#pragma unroll
  for (int t = 0; t < 8; ++t) { sq[t] = 0.f; sk[t] = 0.f; }

  {
    const int c0 = tid * 2;
    const float4 wqA = *(const float4*)(qcw + 4 * c0);
    const float4 wqB = *(const float4*)(qcw + 4 * c0 + 4);
    const float4 wkA = *(const float4*)(kcw + 4 * c0);
    const float4 wkB = *(const float4*)(kcw + 4 * c0 + 4);
    const float2 bq = *(const float2*)(qcb + c0);
    const float2 bk = *(const float2*)(kcb + c0);
    float2 wrq[11], wrk[11];
#pragma unroll
    for (int r = 0; r < 11; ++r) {
      const int tt = t0 - 3 + r;
      if (tt >= 0) {
        const float* Cr = C + (size_t)(bl0 - 3 + r) * NPROJ;
        wrq[r] = *(const float2*)(Cr + c0);
        wrk[r] = *(const float2*)(Cr + 512 + c0);
      } else {
        wrq[r] = make_float2(0.f, 0.f);
        wrk[r] = make_float2(0.f, 0.f);
      }
    }
#pragma unroll
    for (int t = 0; t < 8; ++t) {
      float aq0 = bq.x, aq1 = bq.y, ak0 = bk.x, ak1 = bk.y;
#pragma unroll
      for (int j = 0; j < 4; ++j) {
        aq0 = fmaf(((const float*)&wqA)[j], wrq[t + j].x, aq0);
        aq1 = fmaf(((const float*)&wqB)[j], wrq[t + j].y, aq1);
        ak0 = fmaf(((const float*)&wkA)[j], wrk[t + j].x, ak0);
        ak1 = fmaf(((const float*)&wkB)[j], wrk[t + j].y, ak1);
      }
      const float q0 = siluf(aq0), q1 = siluf(aq1);
      const float k0 = siluf(ak0), k1 = siluf(ak1);
      qv[t] = make_float2(q0, q1);
      kv[t] = make_float2(k0, k1);
      sq[t] = fmaf(q1, q1, fmaf(q0, q0, sq[t]));
      sk[t] = fmaf(k1, k1, fmaf(k0, k0, sk[t]));
    }
  }
  // reduce sq,sk across 64 lanes, then across 4 waves
#pragma unroll
  for (int m = 1; m < 64; m <<= 1) {
#pragma unroll
    for (int t = 0; t < 8; ++t) {
      sq[t] += __shfl_xor(sq[t], m);
      sk[t] += __shfl_xor(sk[t], m);
    }
  }
  {
    const int w = tid >> 6, lane = tid & 63;
    if (lane == 0) {
#pragma unroll
      for (int t = 0; t < 8; ++t) { red[w][t] = sq[t]; red[w][8 + t] = sk[t]; }
    }
  }
  __syncthreads();
  float rnq[8], rnk[8];
#pragma unroll
  for (int t = 0; t < 8; ++t) {
    const float SQ = red[0][t] + red[1][t] + red[2][t] + red[3][t];
    const float SK = red[0][8 + t] + red[1][8 + t] + red[2][8 + t] + red[3][8 + t];
    rnq[t] = 1.f / fmaxf(sqrtf(SQ), 1e-12f);
    rnk[t] = 1.f / fmaxf(sqrtf(SK), 1e-12f);
  }
  {
    const int c0 = tid * 2;
#pragma unroll
    for (int t = 0; t < 8; ++t) {
      *(float2*)(qh + (size_t)(bl0 + t) * 512 + c0) =
          make_float2(qv[t].x * rnq[t], qv[t].y * rnq[t]);
      *(float2*)(kh + (size_t)(bl0 + t) * 512 + c0) =
          make_float2(kv[t].x * rnk[t], kv[t].y * rnk[t]);
    }
  }
  // v: 4 consecutive channels per thread (float4)
  {
    const int cv = tid * 4;   // 0..1023
    const float4 wv0 = *(const float4*)(vcw + 4 * cv);
    const float4 wv1 = *(const float4*)(vcw + 4 * cv + 4);
    const float4 wv2 = *(const float4*)(vcw + 4 * cv + 8);
    const float4 wv3 = *(const float4*)(vcw + 4 * cv + 12);
    const float4 bv4 = *(const float4*)(vcb + cv);
    float4 wr[11];
#pragma unroll
    for (int r = 0; r < 11; ++r) {
      const int tt = t0 - 3 + r;
      wr[r] = (tt >= 0) ? *(const float4*)(C + (size_t)(bl0 - 3 + r) * NPROJ + 1024 + cv)
                        : make_float4(0.f, 0.f, 0.f, 0.f);
    }
#pragma unroll
    for (int t = 0; t < 8; ++t) {
      float a0 = bv4.x, a1 = bv4.y, a2 = bv4.z, a3 = bv4.w;
#pragma unroll
      for (int j = 0; j < 4; ++j) {
        a0 = fmaf(((const float*)&wv0)[j], ((const float*)&wr[t + j])[0], a0);
        a1 = fmaf(((const float*)&wv1)[j], ((const float*)&wr[t + j])[1], a1);
        a2 = fmaf(((const float*)&wv2)[j], ((const float*)&wr[t + j])[2], a2);
        a3 = fmaf(((const float*)&wv3)[j], ((const float*)&wr[t + j])[3], a3);
      }
      const float4 o = make_float4(siluf(a0), siluf(a1), siluf(a2), siluf(a3));
      if (cv < 512) *(float4*)(vm + (size_t)(bl0 + t) * 512 + cv)         = o;
      else          *(float4*)(vg + (size_t)(bl0 + t) * 512 + (cv - 512)) = o;
    }
  }
  // alpha/beta: threads 0..63 cover 8 t x (4 al + 4 be)
  if (tid < 64) {
    const int t = tid >> 3;
    const int k = tid & 7;
    const float* Cr = C + (size_t)(bl0 + t) * NPROJ;
    if (k < 4) al[(size_t)(bl0 + t) * 4 + k]       = sigf(Cr[2560 + k]);
    else       be[(size_t)(bl0 + t) * 4 + (k - 4)] = sigf(Cr[2564 + (k - 4)]);
  }
}

// ---------------- scan phase A: per-chunk WY decomposition ----------------
// 256 blocks = 32 chunks x 8 (b,h). Computes per chunk:
//   d_t = cumsum log a;  G = K K^T, Pq = Q K^T (MFMA bf16)
//   L_{ts} = b_t e^{d_t-d_s} G_{ts} (t>s)
//   solve (I+L)[W~|Z] = [diag(b e^d) K | diag(b) V]  (blocked f32 fwd subst.)
//   store W~ (bf16), Z (bf16), Phat = tril(Pq o e^{d_t-d_s}) (bf16),
//         KT = K^T (bf16), gamma_t = e^{d_t}, gc = e^{d_63}
//   plus f-scaled transposes for the transition kernel:
//         WTF(m,s) = f_s W~(s,m), ZF(i,s) = f_s Z(s,i), f_s = e^{d_63-d_s}
// Substitution is blocked in 4 groups of 16 rows: only u[16] lives in regs;
// solved blocks spill to LDS Xl[64][256] (lane-consecutive -> conflict-free,
// column j private to thread j). Xl aliases the K/Q staging (dead after MFMA).
__global__ __launch_bounds__(256)
void scan_phaseA_kernel(const float* __restrict__ qh, const float* __restrict__ kh,
                        const float* __restrict__ vm, const float* __restrict__ al,
                        const float* __restrict__ be,
                        short* __restrict__ WTB, short* __restrict__ ZB,
                        short* __restrict__ PHB, short* __restrict__ KTB,
                        float* __restrict__ GV, float* __restrict__ GC,
                        short* __restrict__ WTFB, short* __restrict__ ZFB)
{
  __shared__ char sm[83968];
  float* Xl = (float*)(sm);                             // [64][256] f32 (aliases KBl/QBl)
  __hip_bfloat16* KBl = (__hip_bfloat16*)(sm);          // [64][136]
  __hip_bfloat16* QBl = (__hip_bfloat16*)(sm + 17408);  // [64][136]
  float* Ll  = (float*)(sm + 65536);                    // [64][68]
  float* dv  = (float*)(sm + 82944);                    // [64]
  float* bv  = (float*)(sm + 83200);                    // [64]
  float* gbv = (float*)(sm + 83456);                    // [64]
  float* fvs = (float*)(sm + 83712);                    // [64]

  const int cb = blockIdx.x;
  const int bh = cb & 7, c = cb >> 3;
  const int b = bh >> 2, h = bh & 3;
  const int tid = threadIdx.x;
  const int lane = tid & 63;
  const int w = tid >> 6;
  const int lr = lane & 15, lk = lane >> 4;
  const size_t rowbase = (size_t)(b * LQ + c * CT) * 512 + h * 128;

  // stage K,Q -> LDS bf16 (padded rows of 136)
#pragma unroll
  for (int rep = 0; rep < 4; ++rep) {
    const int fid = tid + rep * 256;       // 0..1023
    const int r = fid >> 4;
    const int cg = (fid & 15) * 8;
    const float* kp = kh + rowbase + (size_t)r * 512 + cg;
    const float* qp = qh + rowbase + (size_t)r * 512 + cg;
    f32x4 k0 = *(const f32x4*)kp, k1 = *(const f32x4*)(kp + 4);
    f32x4 q0 = *(const f32x4*)qp, q1 = *(const f32x4*)(qp + 4);
    *(bf16x8*)(KBl + r * 136 + cg) = pack8(k0, k1);
    *(bf16x8*)(QBl + r * 136 + cg) = pack8(q0, q1);
  }
  // decay prefix (wave 0)
  if (w == 0) {
    float la = __logf(al[(size_t)(b * LQ + c * CT + lane) * 4 + h]);
    const float bb = be[(size_t)(b * LQ + c * CT + lane) * 4 + h];
#pragma unroll
    for (int off = 1; off < 64; off <<= 1) {
      const float tv = __shfl_up(la, off, 64);
      if (lane >= off) la += tv;
    }
    const float d63 = __shfl(la, 63, 64);
    dv[lane] = la; bv[lane] = bb; gbv[lane] = bb * __expf(la);
    fvs[lane] = __expf(d63 - la);
    GV[cb * 64 + lane] = __expf(la);
    if (lane == 0) GC[cb] = __expf(d63);
  }
  __syncthreads();

  // G = K K^T, Pq = Q K^T  (each wave owns one 16-row t-band)
  f32x4 aG[4] = {}, aP[4] = {};
#pragma unroll
  for (int ks = 0; ks < 4; ++ks) {
    bf16x8 bk[4];
#pragma unroll
    for (int nt = 0; nt < 4; ++nt)
      bk[nt] = *(const bf16x8*)(KBl + (nt * 16 + lr) * 136 + ks * 32 + lk * 8);
    const bf16x8 ak = *(const bf16x8*)(KBl + (w * 16 + lr) * 136 + ks * 32 + lk * 8);
    const bf16x8 aq = *(const bf16x8*)(QBl + (w * 16 + lr) * 136 + ks * 32 + lk * 8);
#pragma unroll
    for (int nt = 0; nt < 4; ++nt) {
      aG[nt] = MFMA16(ak, bk[nt], aG[nt]);
      aP[nt] = MFMA16(aq, bk[nt], aP[nt]);
    }
  }
#pragma unroll
  for (int nt = 0; nt < 4; ++nt)
#pragma unroll
    for (int jj = 0; jj < 4; ++jj) {
      const int t = w * 16 + lk * 4 + jj;
      const int s = nt * 16 + lr;
      const float eg = __expf(dv[t] - dv[s]);
      Ll[t * 68 + s] = (t > s) ? bv[t] * eg * aG[nt][jj] : 0.f;
      PHB[(size_t)cb * 4096 + t * 64 + s] = (s <= t) ? bf16s(eg * aP[nt][jj]) : (short)0;
    }
  __syncthreads();   // KBl/QBl dead from here -> Xl may overwrite

  // ---- blocked forward substitution: thread j owns column j ----
  const int j = tid;
  const float* src = (j < 128) ? kh : vm;
  const float* xp = src + rowbase + (j & 127);
  float* XlC = Xl + j;                 // private column, stride 256 floats
  short* dstN = (j < 128) ? (WTB + (size_t)cb * 8192 + j)
                          : (ZB  + (size_t)cb * 8192 + (j - 128));
  short* dstT = (j < 128) ? (WTFB + (size_t)cb * 8192 + (size_t)j * 64)
                          : (ZFB  + (size_t)cb * 8192 + (size_t)(j - 128) * 64);

  for (int r = 0; r < 4; ++r) {
    float u[16];
    // RHS block (scaled)
#pragma unroll
    for (int i = 0; i < 16; ++i) {
      const int t = r * 16 + i;
      u[i] = xp[(size_t)t * 512] * ((j < 128) ? gbv[t] : bv[t]);
    }
    // cross-block updates from already-solved 16-blocks (LDS spill)
    for (int sc = 0; sc < r; ++sc) {
      float xs[16];
#pragma unroll
      for (int k = 0; k < 16; ++k) xs[k] = XlC[(sc * 16 + k) * 256];
#pragma unroll
      for (int i = 0; i < 16; ++i) {
        const float* lrow = Ll + (r * 16 + i) * 68 + sc * 16;
        const f32x4 l0 = *(const f32x4*)(lrow);
        const f32x4 l1 = *(const f32x4*)(lrow + 4);
        const f32x4 l2 = *(const f32x4*)(lrow + 8);
        const f32x4 l3 = *(const f32x4*)(lrow + 12);
        f32x4 acc = {};
        acc.x = fmaf(l0.x, xs[0],  acc.x); acc.y = fmaf(l0.y, xs[1],  acc.y);
        acc.z = fmaf(l0.z, xs[2],  acc.z); acc.w = fmaf(l0.w, xs[3],  acc.w);
        acc.x = fmaf(l1.x, xs[4],  acc.x); acc.y = fmaf(l1.y, xs[5],  acc.y);
        acc.z = fmaf(l1.z, xs[6],  acc.z); acc.w = fmaf(l1.w, xs[7],  acc.w);
        acc.x = fmaf(l2.x, xs[8],  acc.x); acc.y = fmaf(l2.y, xs[9],  acc.y);
        acc.z = fmaf(l2.z, xs[10], acc.z); acc.w = fmaf(l2.w, xs[11], acc.w);
        acc.x = fmaf(l3.x, xs[12], acc.x); acc.y = fmaf(l3.y, xs[13], acc.y);
        acc.z = fmaf(l3.z, xs[14], acc.z); acc.w = fmaf(l3.w, xs[15], acc.w);
        u[i] -= (acc.x + acc.y) + (acc.z + acc.w);
      }
    }
    // in-block serial solve (rows above diag of Ll are zero)
#pragma unroll
    for (int i = 1; i < 16; ++i) {
      const float* lrow = Ll + (r * 16 + i) * 68 + r * 16;
      f32x4 acc = {};
#pragma unroll
      for (int k4 = 0; k4 < 4; ++k4) {
        if (k4 * 4 < i) {
          const f32x4 lv = *(const f32x4*)(lrow + k4 * 4);
          acc.x = fmaf(lv.x, u[k4 * 4 + 0], acc.x);
          acc.y = fmaf(lv.y, u[k4 * 4 + 1], acc.y);
          acc.z = fmaf(lv.z, u[k4 * 4 + 2], acc.z);
          acc.w = fmaf(lv.w, u[k4 * 4 + 3], acc.w);
        }
      }
      u[i] -= (acc.x + acc.y) + (acc.z + acc.w);
    }
    // spill for future blocks
    if (r < 3) {
#pragma unroll
      for (int i = 0; i < 16; ++i) XlC[(r * 16 + i) * 256] = u[i];
    }
    // stores: W~/Z (bf16, coalesced) and f-scaled transposed WTF/ZF
#pragma unroll
    for (int i = 0; i < 16; ++i)
      dstN[(r * 16 + i) * 128] = bf16s(u[i]);
#pragma unroll
    for (int s4 = 0; s4 < 4; ++s4) {
      s16x4 p;
#pragma unroll
      for (int e = 0; e < 4; ++e)
        p[e] = bf16s(fvs[r * 16 + s4 * 4 + e] * u[s4 * 4 + e]);
      *(s16x4*)(dstT + r * 16 + s4 * 4) = p;
    }
  }

  // KT = K^T (128 x 64 bf16)
  if (tid < 128) {
    const float* kp2 = kh + rowbase + tid;
#pragma unroll
    for (int s4 = 0; s4 < 16; ++s4) {
      s16x4 pk;
#pragma unroll
      for (int e = 0; e < 4; ++e)
        pk[e] = bf16s(kp2[(size_t)(s4 * 4 + e) * 512]);
      *(s16x4*)(KTB + (size_t)cb * 8192 + tid * 64 + s4 * 4) = pk;
    }
  }
}

// ---------------- scan transition: per-chunk affine factors ----------------
// S_{c+1} = S_c T_c + B_c  (rows of S evolve independently)
//   A(m,j)  = sum_s f_s W~(s,m) K(s,j);   T(m,j) = gc d(m,j) - A(m,j)
//   B(i,j)  = sum_s f_s Z(s,i)  K(s,j)
// Stored: TRB[cb][j][m] = T(m,j) (bf16, transposed for MFMA B-operand),
//         BF[cb][i][j] (f32).
// 256 blocks (one per cb), 4 waves; wave w owns a 32-row output band.
__global__ __launch_bounds__(256)
void scan_transition_kernel(const short* __restrict__ WTFB, const short* __restrict__ ZFB,
                            const short* __restrict__ KTB, const float* __restrict__ GC,
                            short* __restrict__ TRB, float* __restrict__ BF)
{
  const int cb = blockIdx.x;
  const int tid = threadIdx.x, lane = tid & 63, w = tid >> 6;
  const int lr = lane & 15, lk = lane >> 4;
  const float gc = GC[cb];

  // ---- AT(j,m) = sum_s KT(j,s) * WTF(m,s) ; then T^T(j,m) = gc d - AT(j,m)
  {
    f32x4 acc[2][8] = {};
#pragma unroll
    for (int ks = 0; ks < 2; ++ks) {
      bf16x8 a0 = *(const bf16x8*)(KTB + (size_t)cb * 8192 + (w * 32 + lr) * 64 + ks * 32 + lk * 8);
      bf16x8 a1 = *(const bf16x8*)(KTB + (size_t)cb * 8192 + (w * 32 + 16 + lr) * 64 + ks * 32 + lk * 8);
#pragma unroll
      for (int nt = 0; nt < 8; ++nt) {
        const bf16x8 bm = *(const bf16x8*)(WTFB + (size_t)cb * 8192 + (nt * 16 + lr) * 64 + ks * 32 + lk * 8);
        acc[0][nt] = MFMA16(a0, bm, acc[0][nt]);
        acc[1][nt] = MFMA16(a1, bm, acc[1][nt]);
      }
    }
#pragma unroll
    for (int mt = 0; mt < 2; ++mt)
#pragma unroll
      for (int nt = 0; nt < 8; ++nt)
#pragma unroll
        for (int jj = 0; jj < 4; ++jj) {
          const int jr = w * 32 + mt * 16 + lk * 4 + jj;
          const int m  = nt * 16 + lr;
          const float v = ((jr == m) ? gc : 0.f) - acc[mt][nt][jj];
          TRB[(size_t)cb * 16384 + jr * 128 + m] = bf16s(v);
        }
  }
  // ---- B(i,j) = sum_s ZF(i,s) * KT(j,s)
  {
    f32x4 acc[2][8] = {};
#pragma unroll
    for (int ks = 0; ks < 2; ++ks) {
      bf16x8 a0 = *(const bf16x8*)(ZFB + (size_t)cb * 8192 + (w * 32 + lr) * 64 + ks * 32 + lk * 8);
      bf16x8 a1 = *(const bf16x8*)(ZFB + (size_t)cb * 8192 + (w * 32 + 16 + lr) * 64 + ks * 32 + lk * 8);
#pragma unroll
      for (int nt = 0; nt < 8; ++nt) {
        const bf16x8 bj = *(const bf16x8*)(KTB + (size_t)cb * 8192 + (nt * 16 + lr) * 64 + ks * 32 + lk * 8);
        acc[0][nt] = MFMA16(a0, bj, acc[0][nt]);
        acc[1][nt] = MFMA16(a1, bj, acc[1][nt]);
      }
    }
#pragma unroll
    for (int mt = 0; mt < 2; ++mt)
#pragma unroll
      for (int nt = 0; nt < 8; ++nt)
#pragma unroll
        for (int jj = 0; jj < 4; ++jj) {
          const int ir = w * 32 + mt * 16 + lk * 4 + jj;
          const int jc = nt * 16 + lr;
          BF[(size_t)cb * 16384 + ir * 128 + jc] = acc[mt][nt][jj];
        }
  }
}

// ---------------- scan state: serial chunk recurrence, S rows independent ----
// 64 blocks = 8 (b,h) x 8 row-slabs of 16. Per chunk: store S_c (bf16) to
// SALL, S <- S*T + B with register-double-buffered prefetch of T_{c+1}/B_{c+1}.
#define L2_PREFETCH(BT, BA, CC) do {                                               \
  const int cbn_ = (CC) * 8 + bh;                                                  \
  _Pragma("unroll") for (int nt = 0; nt < 2; ++nt) {                               \
    _Pragma("unroll") for (int ks = 0; ks < 4; ++ks)                               \
      BT[nt][ks] = *(const bf16x8*)(TRB + (size_t)cbn_ * 16384 +                   \
                                    (w * 32 + nt * 16 + lr) * 128 + ks * 32 + lk * 8); \
    _Pragma("unroll") for (int jj = 0; jj < 4; ++jj)                               \
      BA[nt][jj] = BF[(size_t)cbn_ * 16384 + (r0 + lk * 4 + jj) * 128 +            \
                      w * 32 + nt * 16 + lr];                                      \
  }                                                                                \
} while (0)

#define L2_STEP(BT, BA, CC, PBT, PBA) do {                                         \
  const int cb_ = (CC) * 8 + bh;                                                   \
  { const int idx = tid * 8, r = idx >> 7, jc = idx & 127;                         \
    f32x4 s0 = *(const f32x4*)&Scur[r * 132 + jc];                                 \
    f32x4 s1 = *(const f32x4*)&Scur[r * 132 + jc + 4];                             \
    *(bf16x8*)(SALL + (size_t)cb_ * 16384 + (r0 + r) * 128 + jc) = pack8(s0, s1); }\
  bf16x8 af[4];                                                                    \
  _Pragma("unroll") for (int ks = 0; ks < 4; ++ks)                                 \
    af[ks] = pack8(*(const f32x4*)&Scur[lr * 132 + ks * 32 + lk * 8],              \
                   *(const f32x4*)&Scur[lr * 132 + ks * 32 + lk * 8 + 4]);         \
  if ((CC) < 31) L2_PREFETCH(PBT, PBA, (CC) + 1);                                  \
  f32x4 acc0 = {}, acc1 = {};                                                      \
  _Pragma("unroll") for (int ks = 0; ks < 4; ++ks) {                               \
    acc0 = MFMA16(af[ks], BT[0][ks], acc0);                                        \
    acc1 = MFMA16(af[ks], BT[1][ks], acc1);                                        \
  }                                                                                \
  _Pragma("unroll") for (int jj = 0; jj < 4; ++jj) {                               \
    Snxt[(lk * 4 + jj) * 132 + w * 32 + lr]      = acc0[jj] + BA[0][jj];           \
    Snxt[(lk * 4 + jj) * 132 + w * 32 + 16 + lr] = acc1[jj] + BA[1][jj];           \
  }                                                                                \
  __syncthreads();                                                                 \
  { float* t_ = Scur; Scur = Snxt; Snxt = t_; }                                    \
} while (0)

__global__ __launch_bounds__(256)
void scan_state_kernel(const short* __restrict__ TRB, const float* __restrict__ BF,
                       const float* __restrict__ st0, short* __restrict__ SALL,
                       float* __restrict__ stout)
{
  __shared__ float Sl[2 * 16 * 132];
  const int bid = blockIdx.x;            // 64
  const int bh = bid & 7, slab = bid >> 3;
  const int r0 = slab * 16;
  const int tid = threadIdx.x, lane = tid & 63, w = tid >> 6;
  const int lr = lane & 15, lk = lane >> 4;

  float* Scur = Sl;
  float* Snxt = Sl + 16 * 132;

  // load st0 slab
  {
    const int idx = tid * 8, r = idx >> 7, jc = idx & 127;
    const float* sp = st0 + ((size_t)bh * 128 + r0 + r) * 128 + jc;
    *(f32x4*)&Scur[r * 132 + jc]     = *(const f32x4*)sp;
    *(f32x4*)&Scur[r * 132 + jc + 4] = *(const f32x4*)(sp + 4);
  }
  bf16x8 btA[2][4], btB[2][4];
  float  baA[2][4], baB[2][4];
  L2_PREFETCH(btA, baA, 0);
  __syncthreads();

  for (int c2 = 0; c2 < 16; ++c2) {
    L2_STEP(btA, baA, 2 * c2,     btB, baB);
    L2_STEP(btB, baB, 2 * c2 + 1, btA, baA);
  }

  // final state (Scur holds S_32 after 32 swaps)
  {
    const int idx = tid * 8, r = idx >> 7, jc = idx & 127;
    float* sp = stout + ((size_t)bh * 128 + r0 + r) * 128 + jc;
    *(f32x4*)sp       = *(const f32x4*)&Scur[r * 132 + jc];
    *(f32x4*)(sp + 4) = *(const f32x4*)&Scur[r * 132 + jc + 4];
  }
}

// ---------------- scan output: fully parallel over chunks ----------------
// 256 blocks (cb) x 512 threads (8 waves). waves 0-3: Y_up = Q S_c^T rows,
// waves 4-7: Y_low = W~ S_c^T rows -> U = Z - Y_low -> Ut (LDS); barrier;
// waves 0-3: O = diag(gv) Y_up + Phat U.
__global__ __launch_bounds__(512)
void scan_output_kernel(const float* __restrict__ qh,
                        const short* __restrict__ WTB, const __hip_bfloat16* __restrict__ ZB,
                        const short* __restrict__ PHB, const float* __restrict__ GV,
                        const short* __restrict__ SALL, float* __restrict__ obuf)
{
  __shared__ short Ut[128 * 72];
  const int cb = blockIdx.x;
  const int bh = cb & 7, c = cb >> 3;
  const int b = bh >> 2, h = bh & 3;
  const int tid = threadIdx.x, lane = tid & 63, w = tid >> 6;   // w 0..7
  const int lr = lane & 15, lk = lane >> 4;
  const int r0 = (w & 3) * 16;

  f32x4 Y[8] = {};
#pragma unroll
  for (int ks = 0; ks < 4; ++ks) {
    bf16x8 af;
    if (w < 4) {
      const float* qp = qh + ((size_t)(b * LQ + c * CT) + r0 + lr) * 512 + h * 128 + ks * 32 + lk * 8;
      af = pack8(*(const f32x4*)qp, *(const f32x4*)(qp + 4));
    } else {
      af = *(const bf16x8*)(WTB + (size_t)cb * 8192 + (r0 + lr) * 128 + ks * 32 + lk * 8);
    }
#pragma unroll
    for (int nt = 0; nt < 8; ++nt) {
      const bf16x8 bs = *(const bf16x8*)(SALL + (size_t)cb * 16384 + (nt * 16 + lr) * 128 + ks * 32 + lk * 8);
      Y[nt] = MFMA16(af, bs, Y[nt]);
    }
  }
  if (w >= 4) {   // U = Z - Y_low -> LDS (Ut[i][s])
#pragma unroll
    for (int nt = 0; nt < 8; ++nt) {
      const int i = nt * 16 + lr;
      s16x4 up;
#pragma unroll
      for (int jj = 0; jj < 4; ++jj) {
        const int s = r0 + lk * 4 + jj;
        const float z = __bfloat162float(ZB[(size_t)cb * 8192 + s * 128 + i]);
        up[jj] = bf16s(z - Y[nt][jj]);
      }
      *(s16x4*)&Ut[i * 72 + r0 + lk * 4] = up;
    }
  }
  __syncthreads();
  if (w < 4) {
    f32x4 P2[8] = {};
#pragma unroll
    for (int ks = 0; ks < 2; ++ks) {
      const bf16x8 ap = *(const bf16x8*)(PHB + (size_t)cb * 4096 + (r0 + lr) * 64 + ks * 32 + lk * 8);
#pragma unroll
      for (int nt = 0; nt < 8; ++nt) {
        const bf16x8 bu = *(const bf16x8*)&Ut[(nt * 16 + lr) * 72 + ks * 32 + lk * 8];
        P2[nt] = MFMA16(ap, bu, P2[nt]);
      }
    }
    float gvv[4];
#pragma unroll
    for (int jj = 0; jj < 4; ++jj) gvv[jj] = GV[cb * 64 + r0 + lk * 4 + jj];
#pragma unroll
    for (int nt = 0; nt < 8; ++nt) {
      const int i = nt * 16 + lr;
#pragma unroll
      for (int jj = 0; jj < 4; ++jj) {
        const int t = r0 + lk * 4 + jj;
        obuf[((size_t)(b * LQ + c * CT) + t) * 512 + h * 128 + i] =
            gvv[jj] * Y[nt][jj] + P2[nt][jj];
      }
    }
  }
}

// ---------------- gate * silu(g), LayerNorm(512), cast bf16 ----------------
// float2-vectorized: thread owns channels 2*tid, 2*tid+1.
__global__ __launch_bounds__(256)
void gate_ln_kernel(const float* __restrict__ obuf, const float* __restrict__ vg,
                    const float* __restrict__ C, const float* __restrict__ lnw,
                    const float* __restrict__ lnb, __hip_bfloat16* __restrict__ lno)
{
  const int bl = blockIdx.x, tid = threadIdx.x;
  const int c0 = tid * 2;
  __shared__ float red[8];
  const float2 ov = *(const float2*)(obuf + (size_t)bl * 512 + c0);
  const float2 gv2 = *(const float2*)(vg + (size_t)bl * 512 + c0);
  const float2 gg = *(const float2*)(C + (size_t)bl * NPROJ + 2048 + c0);
  const float v0 = ov.x * gv2.x * siluf(gg.x);
  const float v1 = ov.y * gv2.y * siluf(gg.y);
  float s = v0 + v1;
  float s2 = fmaf(v1, v1, v0 * v0);
  float2 pr = make_float2(s, s2);
#pragma unroll
  for (int m = 1; m < 64; m <<= 1) { pr.x += __shfl_xor(pr.x, m); pr.y += __shfl_xor(pr.y, m); }
  if ((tid & 63) == 0) { red[(tid >> 6) * 2] = pr.x; red[(tid >> 6) * 2 + 1] = pr.y; }
  __syncthreads();
  const float S  = red[0] + red[2] + red[4] + red[6];
  const float S2 = red[1] + red[3] + red[5] + red[7];
  const float mu  = S * (1.f / 512.f);
  const float var = S2 * (1.f / 512.f) - mu * mu;
  const float rs  = rsqrtf(var + 1e-5f);
  const float2 lw = *(const float2*)(lnw + c0);
  const float2 lb = *(const float2*)(lnb + c0);
  __hip_bfloat16 o[2] = {
    __float2bfloat16(fmaf((v0 - mu) * rs, lw.x, lb.x)),
    __float2bfloat16(fmaf((v1 - mu) * rs, lw.y, lb.y)) };
  *(ushort2*)((unsigned short*)lno + (size_t)bl * 512 + c0) = *(ushort2*)o;
}

extern "C" void kernel_launch(void* const* d_in, const int* in_sizes, int n_in,
                              void* d_out, int out_size, void* d_ws, size_t ws_size,
                              hipStream_t stream)
{
  (void)in_sizes; (void)n_in; (void)out_size; (void)ws_size;
  const float* x    = (const float*)d_in[0];
  const float* st0  = (const float*)d_in[1];
  const float* Wq   = (const float*)d_in[2];
  const float* Wk   = (const float*)d_in[3];
  const float* Wv   = (const float*)d_in[4];
  const float* Wa   = (const float*)d_in[5];
  const float* Wb   = (const float*)d_in[6];
  const float* Wg   = (const float*)d_in[7];
  const float* Wo   = (const float*)d_in[8];
  const float* qcw  = (const float*)d_in[9];
  const float* qcb  = (const float*)d_in[10];
  const float* kcw  = (const float*)d_in[11];
  const float* kcb  = (const float*)d_in[12];
  const float* vcw  = (const float*)d_in[13];
  const float* vcb  = (const float*)d_in[14];
  const float* lnw  = (const float*)d_in[15];
  const float* lnb  = (const float*)d_in[16];
  float* out = (float*)d_out;

  // workspace layout (bytes); high-water ~124.3 MB
  char* ws = (char*)d_ws;
  __hip_bfloat16* XB   = (__hip_bfloat16*)(ws + 0);            // 4096x1024 bf16 (dead after proj GEMM)
  __hip_bfloat16* LNO  = (__hip_bfloat16*)(ws + 0);            // 4096x512 bf16 (aliases XB 1st half, written at gate_ln)
  short*          WTFB = (short*)(ws + 0);                     // [256][128][64] bf16 (aliases XB 1st half; phaseA->transition window)
  short*          WTB  = (short*)(ws + 4194304);               // [256][64][128] bf16 (aliases XB 2nd half)
  __hip_bfloat16* WCAT = (__hip_bfloat16*)(ws + 8388608);      // 2688x1024 bf16
  __hip_bfloat16* WOB  = (__hip_bfloat16*)(ws + 13893632);     // 1024x512  bf16
  float* CBUF = (float*)(ws + 14942208);                       // 4096x2688 f32
  float* QH   = (float*)(ws + 58982400);                       // 4096x512
  float* KH   = (float*)(ws + 67371008);
  float* BF   = (float*)(ws + 67371008);                       // [256][128][128] f32 (aliases KH+VM; written after phaseA)
  float* VM   = (float*)(ws + 75759616);
  float* VG   = (float*)(ws + 84148224);
  float* AL   = (float*)(ws + 92536832);                       // 4096x4
  float* BE   = (float*)(ws + 92602368);
  float* OBUF = (float*)(ws + 92667904);                       // 4096x512 (written by scan_output)
  short* TRB  = (short*)(ws + 92667904);                       // [256][128][128] bf16 (aliases OBUF; dead before scan_output)
  short* KTB  = (short*)(ws + 101056512);                      // [256][128][64] bf16
  short* PHB  = (short*)(ws + 105250816);                      // [256][64][64] bf16
  short* ZB   = (short*)(ws + 107347968);                      // [256][64][128] bf16
  float* GV   = (float*)(ws + 111542272);                      // [256][64]
  float* GC   = (float*)(ws + 111673344);                      // [256]
  short* ZFB  = (short*)(ws + 111674368);                      // [256][128][64] bf16
  short* SALL = (short*)(ws + 115868672);                      // [256][128][128] bf16 chunk-start states

  cast_f32_bf16_kernel<<<4096, 256, 0, stream>>>(x,  XB,  1048576);
  cast_f32_bf16_kernel<<<512,  256, 0, stream>>>(Wo, WOB, 131072);
  cast_wcat_kernel<<<2688, 256, 0, stream>>>(Wq, Wk, Wv, Wg, Wa, Wb, WCAT);

  gemm_bt_kernel<<<dim3(32, 21), 256, 0, stream>>>(XB, WCAT, CBUF, BLQ, NPROJ, KPROJ);

  conv_act_kernel<<<512, 256, 0, stream>>>(CBUF, qcw, qcb, kcw, kcb, vcw, vcb,
                                           QH, KH, VM, VG, AL, BE);

  scan_phaseA_kernel<<<256, 256, 0, stream>>>(QH, KH, VM, AL, BE,
                                              WTB, ZB, PHB, KTB, GV, GC, WTFB, ZFB);

  scan_transition_kernel<<<256, 256, 0, stream>>>(WTFB, ZFB, KTB, GC, TRB, BF);

  scan_state_kernel<<<64, 256, 0, stream>>>(TRB, BF, st0, SALL, out + 4194304);

  scan_output_kernel<<<256, 512, 0, stream>>>(QH, WTB, (const __hip_bfloat16*)ZB,
                                              PHB, GV, SALL, OBUF);

  gate_ln_kernel<<<BLQ, 256, 0, stream>>>(OBUF, VG, CBUF, lnw, lnb, LNO);

  gemm_bt_kernel<<<dim3(32, 8), 256, 0, stream>>>(LNO, WOB, out, BLQ, DMQ, TOTQ);
}

// Round 8
// 159.309 us; speedup vs baseline: 2.0704x; 1.0418x over previous
//
#include <hip/hip_runtime.h>
#include <hip/hip_bf16.h>

// Problem constants
#define BQ    2
#define LQ    2048
#define DMQ   1024
#define HQ    4
#define DHQ   128
#define TOTQ  512
#define BLQ   4096      // B*L
#define NPROJ 2688      // padded concat: Wq(512) Wk(512) Wv(1024) Wg(512) Wa(4) Wb(4) pad(120)
#define KPROJ 1024
#define CT    64        // scan chunk length
#define NCH   32        // chunks (LQ/CT)

typedef short bf16x8 __attribute__((ext_vector_type(8)));
typedef short s16x4  __attribute__((ext_vector_type(4)));
typedef float f32x4  __attribute__((ext_vector_type(4)));

#define MFMA16(a, b, c) __builtin_amdgcn_mfma_f32_16x16x32_bf16(a, b, c, 0, 0, 0)

__device__ __forceinline__ float siluf(float x) { return x / (1.f + __expf(-x)); }
__device__ __forceinline__ float sigf(float x)  { return 1.f / (1.f + __expf(-x)); }
__device__ __forceinline__ short bf16s(float x) {
  return __builtin_bit_cast(short, __float2bfloat16(x));
}
__device__ __forceinline__ float bfu2f(unsigned short u) {
  return __bfloat162float(__builtin_bit_cast(__hip_bfloat16, u));
}
__device__ __forceinline__ bf16x8 pack8(f32x4 a, f32x4 b) {
  bf16x8 r;
  r[0] = bf16s(a.x); r[1] = bf16s(a.y); r[2] = bf16s(a.z); r[3] = bf16s(a.w);
  r[4] = bf16s(b.x); r[5] = bf16s(b.y); r[6] = bf16s(b.z); r[7] = bf16s(b.w);
  return r;
}

// global -> LDS direct load, 16B per lane. LDS dest must be wave-uniform base;
// HW writes base + lane*16.
__device__ __forceinline__ void gload_lds16(const void* g, void* l) {
  __builtin_amdgcn_global_load_lds(
      (__attribute__((address_space(1))) void*)(unsigned long long)g,
      (__attribute__((address_space(3))) void*)(unsigned int)(unsigned long long)l,
      16, 0, 0);
}

// ---------------- casts ----------------
__global__ __launch_bounds__(256)
void cast_f32_bf16_kernel(const float* __restrict__ src, __hip_bfloat16* __restrict__ dst, int n4)
{
  int i = blockIdx.x * 256 + threadIdx.x;
  if (i < n4) {
    float4 v = ((const float4*)src)[i];
    __hip_bfloat16 o[4] = { __float2bfloat16(v.x), __float2bfloat16(v.y),
                            __float2bfloat16(v.z), __float2bfloat16(v.w) };
    *(ushort4*)((unsigned short*)dst + (size_t)i * 4) = *(ushort4*)o;
  }
}

// float4-vectorized concat cast (4 elems per thread, row-uniform branch)
__global__ __launch_bounds__(256)
void cast_wcat_kernel(const float* __restrict__ Wq, const float* __restrict__ Wk,
                      const float* __restrict__ Wv, const float* __restrict__ Wg,
                      const float* __restrict__ Wa, const float* __restrict__ Wb,
                      __hip_bfloat16* __restrict__ Wcat)
{
  int i4 = blockIdx.x * 256 + threadIdx.x;   // 0 .. 2688*256-1
  int row = i4 >> 8;
  int col = (i4 & 255) * 4;
  int idx = row * 1024 + col;
  float4 v;
  if      (row < 512)  v = *(const float4*)(Wq + idx);
  else if (row < 1024) v = *(const float4*)(Wk + idx - 512 * 1024);
  else if (row < 2048) v = *(const float4*)(Wv + idx - 1024 * 1024);
  else if (row < 2560) v = *(const float4*)(Wg + idx - 2048 * 1024);
  else if (row < 2564) v = *(const float4*)(Wa + (row - 2560) * 1024 + col);
  else if (row < 2568) v = *(const float4*)(Wb + (row - 2564) * 1024 + col);
  else                 v = make_float4(0.f, 0.f, 0.f, 0.f);
  __hip_bfloat16 o[4] = { __float2bfloat16(v.x), __float2bfloat16(v.y),
                          __float2bfloat16(v.z), __float2bfloat16(v.w) };
  *(ushort4*)((unsigned short*)Wcat + idx) = *(ushort4*)o;
}

// ---------------- bf16 MFMA GEMM: C(TOUT, MxN) = A(M,K) * B(N,K)^T ----------------
// 2-phase double-buffered LDS. TOUT = __hip_bfloat16 (proj) or float (final).
// If aux != nullptr, output columns [auxc0, auxc0+8) are ALSO stored f32 to
// aux[row*8 + (col-auxc0)] (keeps alpha/beta logits full-precision).
template <typename TOUT>
__global__ __launch_bounds__(256)
void gemm_bt_kernel(const __hip_bfloat16* __restrict__ A,
                    const __hip_bfloat16* __restrict__ Bw,
                    TOUT* __restrict__ C, int M, int N, int K,
                    float* __restrict__ aux, int auxc0)
{
  __shared__ __hip_bfloat16 As[2 * 128 * 32];
  __shared__ __hip_bfloat16 Bs[2 * 128 * 32];
  const int tid  = threadIdx.x;
  const int lane = tid & 63;
  const int w    = tid >> 6;
  const int wm   = w >> 1, wn = w & 1;
  const int tm   = blockIdx.x, tn = blockIdx.y;
  const int lr   = lane & 15, lk = lane >> 4;

  f32x4 acc[4][4] = {};

  const int e0   = tid * 8;
  const int srow = e0 >> 5;        // 0..63
  const int scol = e0 & 31;
  const __hip_bfloat16* Ap = A  + (size_t)(tm * 128 + srow) * K + scol;
  const __hip_bfloat16* Bp = Bw + (size_t)(tn * 128 + srow) * K + scol;
  char* AsB  = (char*)As;
  char* BsB  = (char*)Bs;
  const size_t half = (size_t)64 * K;
  const int nk = K >> 5;

  // prologue: stage K-tile 0 into buffer 0
  {
    char* AsD = AsB + w * 1024;
    char* BsD = BsB + w * 1024;
    gload_lds16(Ap,        AsD);
    gload_lds16(Ap + half, AsD + 4096);
    gload_lds16(Bp,        BsD);
    gload_lds16(Bp + half, BsD + 4096);
  }
  __syncthreads();

  for (int it = 0; it < nk; ++it) {
    const int sel = it & 1;
    // prefetch next K-tile into the other buffer (no wait here)
    if (it + 1 < nk) {
      const int kk = (it + 1) * 32;
      char* AsD = AsB + ((sel ^ 1) * 8192) + w * 1024;
      char* BsD = BsB + ((sel ^ 1) * 8192) + w * 1024;
      gload_lds16(Ap + kk,        AsD);
      gload_lds16(Ap + half + kk, AsD + 4096);
      gload_lds16(Bp + kk,        BsD);
      gload_lds16(Bp + half + kk, BsD + 4096);
    }
    // compute on current buffer
    const char* AsR = AsB + sel * 8192;
    const char* BsR = BsB + sel * 8192;
    bf16x8 af[4], bfv[4];
#pragma unroll
    for (int m = 0; m < 4; ++m)
      af[m]  = *(const bf16x8*)(AsR + ((wm * 64 + m * 16 + lr) * 32 + lk * 8) * 2);
#pragma unroll
    for (int n = 0; n < 4; ++n)
      bfv[n] = *(const bf16x8*)(BsR + ((wn * 64 + n * 16 + lr) * 32 + lk * 8) * 2);
#pragma unroll
    for (int m = 0; m < 4; ++m)
#pragma unroll
      for (int n = 0; n < 4; ++n)
        acc[m][n] = MFMA16(af[m], bfv[n], acc[m][n]);
    // barrier (drains vmcnt): next tile resident, current buffer reusable
    __syncthreads();
  }

  const int crow0 = tm * 128 + wm * 64 + (lane >> 4) * 4;
  const int ccol0 = tn * 128 + wn * 64 + lr;
#pragma unroll
  for (int m = 0; m < 4; ++m)
#pragma unroll
    for (int n = 0; n < 4; ++n) {
      const int cc = ccol0 + n * 16;
#pragma unroll
      for (int j = 0; j < 4; ++j) {
        const float v = acc[m][n][j];
        const size_t row = (size_t)(crow0 + m * 16 + j);
        if constexpr (sizeof(TOUT) == 2)
          ((unsigned short*)C)[row * N + cc] = (unsigned short)bf16s(v);
        else
          C[row * N + cc] = v;
        if (aux && cc >= auxc0 && cc < auxc0 + 8)
          aux[row * 8 + (cc - auxc0)] = v;
      }
    }
}

// ---------------- conv(4-tap causal) + silu + l2norm + sigmoid(a,b) ----------------
// Sliding-window over 8 timesteps per block (512 blocks). CBUF is bf16;
// alpha/beta logits come from the f32 side buffer abf. Outputs bf16.
__global__ __launch_bounds__(256)
void conv_act_kernel(const __hip_bfloat16* __restrict__ C, const float* __restrict__ abf,
                     const float* __restrict__ qcw, const float* __restrict__ qcb,
                     const float* __restrict__ kcw, const float* __restrict__ kcb,
                     const float* __restrict__ vcw, const float* __restrict__ vcb,
                     __hip_bfloat16* __restrict__ qh, __hip_bfloat16* __restrict__ kh,
                     __hip_bfloat16* __restrict__ vm, __hip_bfloat16* __restrict__ vg,
                     float* __restrict__ al, float* __restrict__ be)
{
  const int blk = blockIdx.x;           // 512
  const int bl0 = blk * 8;              // global row start (never crosses b: 2048%8==0)
  const int t0  = bl0 & (LQ - 1);       // local t start
  const int tid = threadIdx.x;
  const unsigned short* Cu = (const unsigned short*)C;
  __shared__ float red[4][16];

  float2 qv[8], kv[8];
  float sq[8], sk[8];
#pragma unroll
  for (int t = 0; t < 8; ++t) { sq[t] = 0.f; sk[t] = 0.f; }

  {
    const int c0 = tid * 2;
    const float4 wqA = *(const float4*)(qcw + 4 * c0);
    const float4 wqB = *(const float4*)(qcw + 4 * c0 + 4);
    const float4 wkA = *(const float4*)(kcw + 4 * c0);
    const float4 wkB = *(const float4*)(kcw + 4 * c0 + 4);
    const float2 bq = *(const float2*)(qcb + c0);
    const float2 bk = *(const float2*)(kcb + c0);
    float2 wrq[11], wrk[11];
#pragma unroll
    for (int r = 0; r < 11; ++r) {
      const int tt = t0 - 3 + r;
      if (tt >= 0) {
        const unsigned short* Cr = Cu + (size_t)(bl0 - 3 + r) * NPROJ;
        const ushort2 aq = *(const ushort2*)(Cr + c0);
        const ushort2 ak = *(const ushort2*)(Cr + 512 + c0);
        wrq[r] = make_float2(bfu2f(aq.x), bfu2f(aq.y));
        wrk[r] = make_float2(bfu2f(ak.x), bfu2f(ak.y));
      } else {
        wrq[r] = make_float2(0.f, 0.f);
        wrk[r] = make_float2(0.f, 0.f);
      }
    }
#pragma unroll
    for (int t = 0; t < 8; ++t) {
      float aq0 = bq.x, aq1 = bq.y, ak0 = bk.x, ak1 = bk.y;
#pragma unroll
      for (int j = 0; j < 4; ++j) {
        aq0 = fmaf(((const float*)&wqA)[j], wrq[t + j].x, aq0);
        aq1 = fmaf(((const float*)&wqB)[j], wrq[t + j].y, aq1);
        ak0 = fmaf(((const float*)&wkA)[j], wrk[t + j].x, ak0);
        ak1 = fmaf(((const float*)&wkB)[j], wrk[t + j].y, ak1);
      }
      const float q0 = siluf(aq0), q1 = siluf(aq1);
      const float k0 = siluf(ak0), k1 = siluf(ak1);
      qv[t] = make_float2(q0, q1);
      kv[t] = make_float2(k0, k1);
      sq[t] = fmaf(q1, q1, fmaf(q0, q0, sq[t]));
      sk[t] = fmaf(k1, k1, fmaf(k0, k0, sk[t]));
    }
  }
  // reduce sq,sk across 64 lanes, then across 4 waves
#pragma unroll
  for (int m = 1; m < 64; m <<= 1) {
#pragma unroll
    for (int t = 0; t < 8; ++t) {
      sq[t] += __shfl_xor(sq[t], m);
      sk[t] += __shfl_xor(sk[t], m);
    }
  }
  {
    const int w = tid >> 6, lane = tid & 63;
    if (lane == 0) {
#pragma unroll
      for (int t = 0; t < 8; ++t) { red[w][t] = sq[t]; red[w][8 + t] = sk[t]; }
    }
  }
  __syncthreads();
  float rnq[8], rnk[8];
#pragma unroll
  for (int t = 0; t < 8; ++t) {
    const float SQ = red[0][t] + red[1][t] + red[2][t] + red[3][t];
    const float SK = red[0][8 + t] + red[1][8 + t] + red[2][8 + t] + red[3][8 + t];
    rnq[t] = 1.f / fmaxf(sqrtf(SQ), 1e-12f);
    rnk[t] = 1.f / fmaxf(sqrtf(SK), 1e-12f);
  }
  {
    const int c0 = tid * 2;
#pragma unroll
    for (int t = 0; t < 8; ++t) {
      ushort2 oq, ok;
      oq.x = (unsigned short)bf16s(qv[t].x * rnq[t]);
      oq.y = (unsigned short)bf16s(qv[t].y * rnq[t]);
      ok.x = (unsigned short)bf16s(kv[t].x * rnk[t]);
      ok.y = (unsigned short)bf16s(kv[t].y * rnk[t]);
      *(ushort2*)((unsigned short*)qh + (size_t)(bl0 + t) * 512 + c0) = oq;
      *(ushort2*)((unsigned short*)kh + (size_t)(bl0 + t) * 512 + c0) = ok;
    }
  }
  // v: 4 consecutive channels per thread
  {
    const int cv = tid * 4;   // 0..1023
    const float4 wv0 = *(const float4*)(vcw + 4 * cv);
    const float4 wv1 = *(const float4*)(vcw + 4 * cv + 4);
    const float4 wv2 = *(const float4*)(vcw + 4 * cv + 8);
    const float4 wv3 = *(const float4*)(vcw + 4 * cv + 12);
    const float4 bv4 = *(const float4*)(vcb + cv);
    float4 wr[11];
#pragma unroll
    for (int r = 0; r < 11; ++r) {
      const int tt = t0 - 3 + r;
      if (tt >= 0) {
        const ushort4 u = *(const ushort4*)(Cu + (size_t)(bl0 - 3 + r) * NPROJ + 1024 + cv);
        wr[r] = make_float4(bfu2f(u.x), bfu2f(u.y), bfu2f(u.z), bfu2f(u.w));
      } else {
        wr[r] = make_float4(0.f, 0.f, 0.f, 0.f);
      }
    }
#pragma unroll
    for (int t = 0; t < 8; ++t) {
      float a0 = bv4.x, a1 = bv4.y, a2 = bv4.z, a3 = bv4.w;
#pragma unroll
      for (int j = 0; j < 4; ++j) {
        a0 = fmaf(((const float*)&wv0)[j], ((const float*)&wr[t + j])[0], a0);
        a1 = fmaf(((const float*)&wv1)[j], ((const float*)&wr[t + j])[1], a1);
        a2 = fmaf(((const float*)&wv2)[j], ((const float*)&wr[t + j])[2], a2);
        a3 = fmaf(((const float*)&wv3)[j], ((const float*)&wr[t + j])[3], a3);
      }
      ushort4 o;
      o.x = (unsigned short)bf16s(siluf(a0));
      o.y = (unsigned short)bf16s(siluf(a1));
      o.z = (unsigned short)bf16s(siluf(a2));
      o.w = (unsigned short)bf16s(siluf(a3));
      if (cv < 512) *(ushort4*)((unsigned short*)vm + (size_t)(bl0 + t) * 512 + cv)         = o;
      else          *(ushort4*)((unsigned short*)vg + (size_t)(bl0 + t) * 512 + (cv - 512)) = o;
    }
  }
  // alpha/beta from f32 side buffer: threads 0..63 cover 8 t x (4 al + 4 be)
  if (tid < 64) {
    const int t = tid >> 3;
    const int k = tid & 7;
    const float v = abf[(size_t)(bl0 + t) * 8 + k];
    if (k < 4) al[(size_t)(bl0 + t) * 4 + k]       = sigf(v);
    else       be[(size_t)(bl0 + t) * 4 + (k - 4)] = sigf(v);
  }
}

// ---------------- scan phase A: per-chunk WY decomposition ----------------
// Inputs qh/kh/vm are now bf16. Substitution RHS converts bf16->f32.
__global__ __launch_bounds__(256)
void scan_phaseA_kernel(const __hip_bfloat16* __restrict__ qh, const __hip_bfloat16* __restrict__ kh,
                        const __hip_bfloat16* __restrict__ vm, const float* __restrict__ al,
                        const float* __restrict__ be,
                        short* __restrict__ WTB, short* __restrict__ ZB,
                        short* __restrict__ PHB, short* __restrict__ KTB,
                        float* __restrict__ GV, float* __restrict__ GC,
                        short* __restrict__ WTFB, short* __restrict__ ZFB)
{
  __shared__ char sm[83968];
  float* Xl = (float*)(sm);                             // [64][256] f32 (aliases KBl/QBl)
  __hip_bfloat16* KBl = (__hip_bfloat16*)(sm);          // [64][136]
  __hip_bfloat16* QBl = (__hip_bfloat16*)(sm + 17408);  // [64][136]
  float* Ll  = (float*)(sm + 65536);                    // [64][68]
  float* dv  = (float*)(sm + 82944);                    // [64]
  float* bv  = (float*)(sm + 83200);                    // [64]
  float* gbv = (float*)(sm + 83456);                    // [64]
  float* fvs = (float*)(sm + 83712);                    // [64]

  const int cb = blockIdx.x;
  const int bh = cb & 7, c = cb >> 3;
  const int b = bh >> 2, h = bh & 3;
  const int tid = threadIdx.x;
  const int lane = tid & 63;
  const int w = tid >> 6;
  const int lr = lane & 15, lk = lane >> 4;
  const size_t rowbase = (size_t)(b * LQ + c * CT) * 512 + h * 128;

  // stage K,Q -> LDS bf16 (padded rows of 136); direct 16B copies
#pragma unroll
  for (int rep = 0; rep < 4; ++rep) {
    const int fid = tid + rep * 256;       // 0..1023
    const int r = fid >> 4;
    const int cg = (fid & 15) * 8;
    *(bf16x8*)(KBl + r * 136 + cg) = *(const bf16x8*)(kh + rowbase + (size_t)r * 512 + cg);
    *(bf16x8*)(QBl + r * 136 + cg) = *(const bf16x8*)(qh + rowbase + (size_t)r * 512 + cg);
  }
  // decay prefix (wave 0)
  if (w == 0) {
    float la = __logf(al[(size_t)(b * LQ + c * CT + lane) * 4 + h]);
    const float bb = be[(size_t)(b * LQ + c * CT + lane) * 4 + h];
#pragma unroll
    for (int off = 1; off < 64; off <<= 1) {
      const float tv = __shfl_up(la, off, 64);
      if (lane >= off) la += tv;
    }
    const float d63 = __shfl(la, 63, 64);
    dv[lane] = la; bv[lane] = bb; gbv[lane] = bb * __expf(la);
    fvs[lane] = __expf(d63 - la);
    GV[cb * 64 + lane] = __expf(la);
    if (lane == 0) GC[cb] = __expf(d63);
  }
  __syncthreads();

  // G = K K^T, Pq = Q K^T  (each wave owns one 16-row t-band)
  f32x4 aG[4] = {}, aP[4] = {};
#pragma unroll
  for (int ks = 0; ks < 4; ++ks) {
    bf16x8 bk[4];
#pragma unroll
    for (int nt = 0; nt < 4; ++nt)
      bk[nt] = *(const bf16x8*)(KBl + (nt * 16 + lr) * 136 + ks * 32 + lk * 8);
    const bf16x8 ak = *(const bf16x8*)(KBl + (w * 16 + lr) * 136 + ks * 32 + lk * 8);
    const bf16x8 aq = *(const bf16x8*)(QBl + (w * 16 + lr) * 136 + ks * 32 + lk * 8);
#pragma unroll
    for (int nt = 0; nt < 4; ++nt) {
      aG[nt] = MFMA16(ak, bk[nt], aG[nt]);
      aP[nt] = MFMA16(aq, bk[nt], aP[nt]);
    }
  }
#pragma unroll
  for (int nt = 0; nt < 4; ++nt)
#pragma unroll
    for (int jj = 0; jj < 4; ++jj) {
      const int t = w * 16 + lk * 4 + jj;
      const int s = nt * 16 + lr;
      const float eg = __expf(dv[t] - dv[s]);
      Ll[t * 68 + s] = (t > s) ? bv[t] * eg * aG[nt][jj] : 0.f;
      PHB[(size_t)cb * 4096 + t * 64 + s] = (s <= t) ? bf16s(eg * aP[nt][jj]) : (short)0;
    }
  __syncthreads();   // KBl/QBl dead from here -> Xl may overwrite

  // ---- blocked forward substitution: thread j owns column j ----
  const int j = tid;
  const __hip_bfloat16* src = (j < 128) ? kh : vm;
  const __hip_bfloat16* xp = src + rowbase + (j & 127);
  float* XlC = Xl + j;                 // private column, stride 256 floats
  short* dstN = (j < 128) ? (WTB + (size_t)cb * 8192 + j)
                          : (ZB  + (size_t)cb * 8192 + (j - 128));
  short* dstT = (j < 128) ? (WTFB + (size_t)cb * 8192 + (size_t)j * 64)
                          : (ZFB  + (size_t)cb * 8192 + (size_t)(j - 128) * 64);

  for (int r = 0; r < 4; ++r) {
    float u[16];
    // RHS block (scaled)
#pragma unroll
    for (int i = 0; i < 16; ++i) {
      const int t = r * 16 + i;
      u[i] = __bfloat162float(xp[(size_t)t * 512]) * ((j < 128) ? gbv[t] : bv[t]);
    }
    // cross-block updates from already-solved 16-blocks (LDS spill)
    for (int sc = 0; sc < r; ++sc) {
      float xs[16];
#pragma unroll
      for (int k = 0; k < 16; ++k) xs[k] = XlC[(sc * 16 + k) * 256];
#pragma unroll
      for (int i = 0; i < 16; ++i) {
        const float* lrow = Ll + (r * 16 + i) * 68 + sc * 16;
        const f32x4 l0 = *(const f32x4*)(lrow);
        const f32x4 l1 = *(const f32x4*)(lrow + 4);
        const f32x4 l2 = *(const f32x4*)(lrow + 8);
        const f32x4 l3 = *(const f32x4*)(lrow + 12);
        f32x4 acc = {};
        acc.x = fmaf(l0.x, xs[0],  acc.x); acc.y = fmaf(l0.y, xs[1],  acc.y);
        acc.z = fmaf(l0.z, xs[2],  acc.z); acc.w = fmaf(l0.w, xs[3],  acc.w);
        acc.x = fmaf(l1.x, xs[4],  acc.x); acc.y = fmaf(l1.y, xs[5],  acc.y);
        acc.z = fmaf(l1.z, xs[6],  acc.z); acc.w = fmaf(l1.w, xs[7],  acc.w);
        acc.x = fmaf(l2.x, xs[8],  acc.x); acc.y = fmaf(l2.y, xs[9],  acc.y);
        acc.z = fmaf(l2.z, xs[10], acc.z); acc.w = fmaf(l2.w, xs[11], acc.w);
        acc.x = fmaf(l3.x, xs[12], acc.x); acc.y = fmaf(l3.y, xs[13], acc.y);
        acc.z = fmaf(l3.z, xs[14], acc.z); acc.w = fmaf(l3.w, xs[15], acc.w);
        u[i] -= (acc.x + acc.y) + (acc.z + acc.w);
      }
    }
    // in-block serial solve (rows above diag of Ll are zero)
#pragma unroll
    for (int i = 1; i < 16; ++i) {
      const float* lrow = Ll + (r * 16 + i) * 68 + r * 16;
      f32x4 acc = {};
#pragma unroll
      for (int k4 = 0; k4 < 4; ++k4) {
        if (k4 * 4 < i) {
          const f32x4 lv = *(const f32x4*)(lrow + k4 * 4);
          acc.x = fmaf(lv.x, u[k4 * 4 + 0], acc.x);
          acc.y = fmaf(lv.y, u[k4 * 4 + 1], acc.y);
          acc.z = fmaf(lv.z, u[k4 * 4 + 2], acc.z);
          acc.w = fmaf(lv.w, u[k4 * 4 + 3], acc.w);
        }
      }
      u[i] -= (acc.x + acc.y) + (acc.z + acc.w);
    }
    // spill for future blocks
    if (r < 3) {
#pragma unroll
      for (int i = 0; i < 16; ++i) XlC[(r * 16 + i) * 256] = u[i];
    }
    // stores: W~/Z (bf16, coalesced) and f-scaled transposed WTF/ZF
#pragma unroll
    for (int i = 0; i < 16; ++i)
      dstN[(r * 16 + i) * 128] = bf16s(u[i]);
#pragma unroll
    for (int s4 = 0; s4 < 4; ++s4) {
      s16x4 p;
#pragma unroll
      for (int e = 0; e < 4; ++e)
        p[e] = bf16s(fvs[r * 16 + s4 * 4 + e] * u[s4 * 4 + e]);
      *(s16x4*)(dstT + r * 16 + s4 * 4) = p;
    }
  }

  // KT = K^T (128 x 64 bf16) — kh already bf16, direct copy
  if (tid < 128) {
    const short* kp2 = (const short*)kh + rowbase + tid;
#pragma unroll
    for (int s4 = 0; s4 < 16; ++s4) {
      s16x4 pk;
#pragma unroll
      for (int e = 0; e < 4; ++e)
        pk[e] = kp2[(size_t)(s4 * 4 + e) * 512];
      *(s16x4*)(KTB + (size_t)cb * 8192 + tid * 64 + s4 * 4) = pk;
    }
  }
}

// ---------------- scan transition: per-chunk affine factors ----------------
__global__ __launch_bounds__(256)
void scan_transition_kernel(const short* __restrict__ WTFB, const short* __restrict__ ZFB,
                            const short* __restrict__ KTB, const float* __restrict__ GC,
                            short* __restrict__ TRB, float* __restrict__ BF)
{
  const int cb = blockIdx.x;
  const int tid = threadIdx.x, lane = tid & 63, w = tid >> 6;
  const int lr = lane & 15, lk = lane >> 4;
  const float gc = GC[cb];

  // ---- AT(j,m) = sum_s KT(j,s) * WTF(m,s) ; then T^T(j,m) = gc d - AT(j,m)
  {
    f32x4 acc[2][8] = {};
#pragma unroll
    for (int ks = 0; ks < 2; ++ks) {
      bf16x8 a0 = *(const bf16x8*)(KTB + (size_t)cb * 8192 + (w * 32 + lr) * 64 + ks * 32 + lk * 8);
      bf16x8 a1 = *(const bf16x8*)(KTB + (size_t)cb * 8192 + (w * 32 + 16 + lr) * 64 + ks * 32 + lk * 8);
#pragma unroll
      for (int nt = 0; nt < 8; ++nt) {
        const bf16x8 bm = *(const bf16x8*)(WTFB + (size_t)cb * 8192 + (nt * 16 + lr) * 64 + ks * 32 + lk * 8);
        acc[0][nt] = MFMA16(a0, bm, acc[0][nt]);
        acc[1][nt] = MFMA16(a1, bm, acc[1][nt]);
      }
    }
#pragma unroll
    for (int mt = 0; mt < 2; ++mt)
#pragma unroll
      for (int nt = 0; nt < 8; ++nt)
#pragma unroll
        for (int jj = 0; jj < 4; ++jj) {
          const int jr = w * 32 + mt * 16 + lk * 4 + jj;
          const int m  = nt * 16 + lr;
          const float v = ((jr == m) ? gc : 0.f) - acc[mt][nt][jj];
          TRB[(size_t)cb * 16384 + jr * 128 + m] = bf16s(v);
        }
  }
  // ---- B(i,j) = sum_s ZF(i,s) * KT(j,s)
  {
    f32x4 acc[2][8] = {};
#pragma unroll
    for (int ks = 0; ks < 2; ++ks) {
      bf16x8 a0 = *(const bf16x8*)(ZFB + (size_t)cb * 8192 + (w * 32 + lr) * 64 + ks * 32 + lk * 8);
      bf16x8 a1 = *(const bf16x8*)(ZFB + (size_t)cb * 8192 + (w * 32 + 16 + lr) * 64 + ks * 32 + lk * 8);
#pragma unroll
      for (int nt = 0; nt < 8; ++nt) {
        const bf16x8 bj = *(const bf16x8*)(KTB + (size_t)cb * 8192 + (nt * 16 + lr) * 64 + ks * 32 + lk * 8);
        acc[0][nt] = MFMA16(a0, bj, acc[0][nt]);
        acc[1][nt] = MFMA16(a1, bj, acc[1][nt]);
      }
    }
#pragma unroll
    for (int mt = 0; mt < 2; ++mt)
#pragma unroll
      for (int nt = 0; nt < 8; ++nt)
#pragma unroll
        for (int jj = 0; jj < 4; ++jj) {
          const int ir = w * 32 + mt * 16 + lk * 4 + jj;
          const int jc = nt * 16 + lr;
          BF[(size_t)cb * 16384 + ir * 128 + jc] = acc[mt][nt][jj];
        }
  }
}

// ---------------- scan state: serial chunk recurrence, S rows independent ----
#define L2_PREFETCH(BT, BA, CC) do {                                               \
  const int cbn_ = (CC) * 8 + bh;                                                  \
  _Pragma("unroll") for (int nt = 0; nt < 2; ++nt) {                               \
    _Pragma("unroll") for (int ks = 0; ks < 4; ++ks)                               \
      BT[nt][ks] = *(const bf16x8*)(TRB + (size_t)cbn_ * 16384 +                   \
                                    (w * 32 + nt * 16 + lr) * 128 + ks * 32 + lk * 8); \
    _Pragma("unroll") for (int jj = 0; jj < 4; ++jj)                               \
      BA[nt][jj] = BF[(size_t)cbn_ * 16384 + (r0 + lk * 4 + jj) * 128 +            \
                      w * 32 + nt * 16 + lr];                                      \
  }                                                                                \
} while (0)

#define L2_STEP(BT, BA, CC, PBT, PBA) do {                                         \
  const int cb_ = (CC) * 8 + bh;                                                   \
  { const int idx = tid * 8, r = idx >> 7, jc = idx & 127;                         \
    f32x4 s0 = *(const f32x4*)&Scur[r * 132 + jc];                                 \
    f32x4 s1 = *(const f32x4*)&Scur[r * 132 + jc + 4];                             \
    *(bf16x8*)(SALL + (size_t)cb_ * 16384 + (r0 + r) * 128 + jc) = pack8(s0, s1); }\
  bf16x8 af[4];                                                                    \
  _Pragma("unroll") for (int ks = 0; ks < 4; ++ks)                                 \
    af[ks] = pack8(*(const f32x4*)&Scur[lr * 132 + ks * 32 + lk * 8],              \
                   *(const f32x4*)&Scur[lr * 132 + ks * 32 + lk * 8 + 4]);         \
  if ((CC) < 31) L2_PREFETCH(PBT, PBA, (CC) + 1);                                  \
  f32x4 acc0 = {}, acc1 = {};                                                      \
  _Pragma("unroll") for (int ks = 0; ks < 4; ++ks) {                               \
    acc0 = MFMA16(af[ks], BT[0][ks], acc0);                                        \
    acc1 = MFMA16(af[ks], BT[1][ks], acc1);                                        \
  }                                                                                \
  _Pragma("unroll") for (int jj = 0; jj < 4; ++jj) {                               \
    Snxt[(lk * 4 + jj) * 132 + w * 32 + lr]      = acc0[jj] + BA[0][jj];           \
    Snxt[(lk * 4 + jj) * 132 + w * 32 + 16 + lr] = acc1[jj] + BA[1][jj];           \
  }                                                                                \
  __syncthreads();                                                                 \
  { float* t_ = Scur; Scur = Snxt; Snxt = t_; }                                    \
} while (0)

__global__ __launch_bounds__(256)
void scan_state_kernel(const short* __restrict__ TRB, const float* __restrict__ BF,
                       const float* __restrict__ st0, short* __restrict__ SALL,
                       float* __restrict__ stout)
{
  __shared__ float Sl[2 * 16 * 132];
  const int bid = blockIdx.x;            // 64
  const int bh = bid & 7, slab = bid >> 3;
  const int r0 = slab * 16;
  const int tid = threadIdx.x, lane = tid & 63, w = tid >> 6;
  const int lr = lane & 15, lk = lane >> 4;

  float* Scur = Sl;
  float* Snxt = Sl + 16 * 132;

  // load st0 slab
  {
    const int idx = tid * 8, r = idx >> 7, jc = idx & 127;
    const float* sp = st0 + ((size_t)bh * 128 + r0 + r) * 128 + jc;
    *(f32x4*)&Scur[r * 132 + jc]     = *(const f32x4*)sp;
    *(f32x4*)&Scur[r * 132 + jc + 4] = *(const f32x4*)(sp + 4);
  }
  bf16x8 btA[2][4], btB[2][4];
  float  baA[2][4], baB[2][4];
  L2_PREFETCH(btA, baA, 0);
  __syncthreads();

  for (int c2 = 0; c2 < 16; ++c2) {
    L2_STEP(btA, baA, 2 * c2,     btB, baB);
    L2_STEP(btB, baB, 2 * c2 + 1, btA, baA);
  }

  // final state (Scur holds S_32 after 32 swaps)
  {
    const int idx = tid * 8, r = idx >> 7, jc = idx & 127;
    float* sp = stout + ((size_t)bh * 128 + r0 + r) * 128 + jc;
    *(f32x4*)sp       = *(const f32x4*)&Scur[r * 132 + jc];
    *(f32x4*)(sp + 4) = *(const f32x4*)&Scur[r * 132 + jc + 4];
  }
}

// ---------------- scan output: fully parallel over chunks ----------------
__global__ __launch_bounds__(512)
void scan_output_kernel(const __hip_bfloat16* __restrict__ qh,
                        const short* __restrict__ WTB, const __hip_bfloat16* __restrict__ ZB,
                        const short* __restrict__ PHB, const float* __restrict__ GV,
                        const short* __restrict__ SALL, float* __restrict__ obuf)
{
  __shared__ short Ut[128 * 72];
  const int cb = blockIdx.x;
  const int bh = cb & 7, c = cb >> 3;
  const int b = bh >> 2, h = bh & 3;
  const int tid = threadIdx.x, lane = tid & 63, w = tid >> 6;   // w 0..7
  const int lr = lane & 15, lk = lane >> 4;
  const int r0 = (w & 3) * 16;

  f32x4 Y[8] = {};
#pragma unroll
  for (int ks = 0; ks < 4; ++ks) {
    bf16x8 af;
    if (w < 4) {
      af = *(const bf16x8*)(qh + ((size_t)(b * LQ + c * CT) + r0 + lr) * 512 + h * 128 + ks * 32 + lk * 8);
    } else {
      af = *(const bf16x8*)(WTB + (size_t)cb * 8192 + (r0 + lr) * 128 + ks * 32 + lk * 8);
    }
#pragma unroll
    for (int nt = 0; nt < 8; ++nt) {
      const bf16x8 bs = *(const bf16x8*)(SALL + (size_t)cb * 16384 + (nt * 16 + lr) * 128 + ks * 32 + lk * 8);
      Y[nt] = MFMA16(af, bs, Y[nt]);
    }
  }
  if (w >= 4) {   // U = Z - Y_low -> LDS (Ut[i][s])
#pragma unroll
    for (int nt = 0; nt < 8; ++nt) {
      const int i = nt * 16 + lr;
      s16x4 up;
#pragma unroll
      for (int jj = 0; jj < 4; ++jj) {
        const int s = r0 + lk * 4 + jj;
        const float z = __bfloat162float(ZB[(size_t)cb * 8192 + s * 128 + i]);
        up[jj] = bf16s(z - Y[nt][jj]);
      }
      *(s16x4*)&Ut[i * 72 + r0 + lk * 4] = up;
    }
  }
  __syncthreads();
  if (w < 4) {
    f32x4 P2[8] = {};
#pragma unroll
    for (int ks = 0; ks < 2; ++ks) {
      const bf16x8 ap = *(const bf16x8*)(PHB + (size_t)cb * 4096 + (r0 + lr) * 64 + ks * 32 + lk * 8);
#pragma unroll
      for (int nt = 0; nt < 8; ++nt) {
        const bf16x8 bu = *(const bf16x8*)&Ut[(nt * 16 + lr) * 72 + ks * 32 + lk * 8];
        P2[nt] = MFMA16(ap, bu, P2[nt]);
      }
    }
    float gvv[4];
#pragma unroll
    for (int jj = 0; jj < 4; ++jj) gvv[jj] = GV[cb * 64 + r0 + lk * 4 + jj];
#pragma unroll
    for (int nt = 0; nt < 8; ++nt) {
      const int i = nt * 16 + lr;
#pragma unroll
      for (int jj = 0; jj < 4; ++jj) {
        const int t = r0 + lk * 4 + jj;
        obuf[((size_t)(b * LQ + c * CT) + t) * 512 + h * 128 + i] =
            gvv[jj] * Y[nt][jj] + P2[nt][jj];
      }
    }
  }
}

// ---------------- gate * silu(g), LayerNorm(512), cast bf16 ----------------
// vg and gate columns are bf16 now.
__global__ __launch_bounds__(256)
void gate_ln_kernel(const float* __restrict__ obuf, const __hip_bfloat16* __restrict__ vg,
                    const __hip_bfloat16* __restrict__ C, const float* __restrict__ lnw,
                    const float* __restrict__ lnb, __hip_bfloat16* __restrict__ lno)
{
  const int bl = blockIdx.x, tid = threadIdx.x;
  const int c0 = tid * 2;
  __shared__ float red[8];
  const float2 ov = *(const float2*)(obuf + (size_t)bl * 512 + c0);
  const ushort2 gvu = *(const ushort2*)((const unsigned short*)vg + (size_t)bl * 512 + c0);
  const ushort2 ggu = *(const ushort2*)((const unsigned short*)C + (size_t)bl * NPROJ + 2048 + c0);
  const float v0 = ov.x * bfu2f(gvu.x) * siluf(bfu2f(ggu.x));
  const float v1 = ov.y * bfu2f(gvu.y) * siluf(bfu2f(ggu.y));
  float s = v0 + v1;
  float s2 = fmaf(v1, v1, v0 * v0);
  float2 pr = make_float2(s, s2);
#pragma unroll
  for (int m = 1; m < 64; m <<= 1) { pr.x += __shfl_xor(pr.x, m); pr.y += __shfl_xor(pr.y, m); }
  if ((tid & 63) == 0) { red[(tid >> 6) * 2] = pr.x; red[(tid >> 6) * 2 + 1] = pr.y; }
  __syncthreads();
  const float S  = red[0] + red[2] + red[4] + red[6];
  const float S2 = red[1] + red[3] + red[5] + red[7];
  const float mu  = S * (1.f / 512.f);
  const float var = S2 * (1.f / 512.f) - mu * mu;
  const float rs  = rsqrtf(var + 1e-5f);
  const float2 lw = *(const float2*)(lnw + c0);
  const float2 lb = *(const float2*)(lnb + c0);
  __hip_bfloat16 o[2] = {
    __float2bfloat16(fmaf((v0 - mu) * rs, lw.x, lb.x)),
    __float2bfloat16(fmaf((v1 - mu) * rs, lw.y, lb.y)) };
  *(ushort2*)((unsigned short*)lno + (size_t)bl * 512 + c0) = *(ushort2*)o;
}

extern "C" void kernel_launch(void* const* d_in, const int* in_sizes, int n_in,
                              void* d_out, int out_size, void* d_ws, size_t ws_size,
                              hipStream_t stream)
{
  (void)in_sizes; (void)n_in; (void)out_size; (void)ws_size;
  const float* x    = (const float*)d_in[0];
  const float* st0  = (const float*)d_in[1];
  const float* Wq   = (const float*)d_in[2];
  const float* Wk   = (const float*)d_in[3];
  const float* Wv   = (const float*)d_in[4];
  const float* Wa   = (const float*)d_in[5];
  const float* Wb   = (const float*)d_in[6];
  const float* Wg   = (const float*)d_in[7];
  const float* Wo   = (const float*)d_in[8];
  const float* qcw  = (const float*)d_in[9];
  const float* qcb  = (const float*)d_in[10];
  const float* kcw  = (const float*)d_in[11];
  const float* kcb  = (const float*)d_in[12];
  const float* vcw  = (const float*)d_in[13];
  const float* vcb  = (const float*)d_in[14];
  const float* lnw  = (const float*)d_in[15];
  const float* lnb  = (const float*)d_in[16];
  float* out = (float*)d_out;

  // workspace layout (bytes); offsets unchanged, several buffers now bf16
  char* ws = (char*)d_ws;
  __hip_bfloat16* XB   = (__hip_bfloat16*)(ws + 0);            // 4096x1024 bf16 (dead after proj GEMM)
  __hip_bfloat16* LNO  = (__hip_bfloat16*)(ws + 0);            // 4096x512 bf16 (aliases XB 1st half, written at gate_ln)
  short*          WTFB = (short*)(ws + 0);                     // [256][128][64] bf16 (aliases XB 1st half; phaseA->transition window)
  short*          WTB  = (short*)(ws + 4194304);               // [256][64][128] bf16 (aliases XB 2nd half)
  __hip_bfloat16* WCAT = (__hip_bfloat16*)(ws + 8388608);      // 2688x1024 bf16
  __hip_bfloat16* WOB  = (__hip_bfloat16*)(ws + 13893632);     // 1024x512  bf16
  __hip_bfloat16* CBUFH = (__hip_bfloat16*)(ws + 14942208);    // 4096x2688 bf16 (22 MB of old 44 MB slot)
  __hip_bfloat16* QH   = (__hip_bfloat16*)(ws + 58982400);     // 4096x512 bf16
  __hip_bfloat16* KH   = (__hip_bfloat16*)(ws + 67371008);     // 4096x512 bf16
  float* BF   = (float*)(ws + 67371008);                       // [256][128][128] f32 (aliases KH+VM slots; written after phaseA)
  __hip_bfloat16* VM   = (__hip_bfloat16*)(ws + 75759616);     // 4096x512 bf16
  __hip_bfloat16* VG   = (__hip_bfloat16*)(ws + 84148224);     // 4096x512 bf16
  float* AL   = (float*)(ws + 92536832);                       // 4096x4
  float* BE   = (float*)(ws + 92602368);
  float* OBUF = (float*)(ws + 92667904);                       // 4096x512 f32 (written by scan_output)
  short* TRB  = (short*)(ws + 92667904);                       // [256][128][128] bf16 (aliases OBUF; dead before scan_output)
  short* KTB  = (short*)(ws + 101056512);                      // [256][128][64] bf16
  short* PHB  = (short*)(ws + 105250816);                      // [256][64][64] bf16
  short* ZB   = (short*)(ws + 107347968);                      // [256][64][128] bf16
  float* GV   = (float*)(ws + 111542272);                      // [256][64]
  float* GC   = (float*)(ws + 111673344);                      // [256]
  short* ZFB  = (short*)(ws + 111674368);                      // [256][128][64] bf16
  short* SALL = (short*)(ws + 115868672);                      // [256][128][128] bf16 chunk-start states
  float* ABF  = (float*)(ws + 124257280);                      // [4096][8] f32 alpha/beta logits

  cast_f32_bf16_kernel<<<4096, 256, 0, stream>>>(x,  XB,  1048576);
  cast_f32_bf16_kernel<<<512,  256, 0, stream>>>(Wo, WOB, 131072);
  cast_wcat_kernel<<<2688, 256, 0, stream>>>(Wq, Wk, Wv, Wg, Wa, Wb, WCAT);

  gemm_bt_kernel<__hip_bfloat16><<<dim3(32, 21), 256, 0, stream>>>(
      XB, WCAT, CBUFH, BLQ, NPROJ, KPROJ, ABF, 2560);

  conv_act_kernel<<<512, 256, 0, stream>>>(CBUFH, ABF, qcw, qcb, kcw, kcb, vcw, vcb,
                                           QH, KH, VM, VG, AL, BE);

  scan_phaseA_kernel<<<256, 256, 0, stream>>>(QH, KH, VM, AL, BE,
                                              WTB, ZB, PHB, KTB, GV, GC, WTFB, ZFB);

  scan_transition_kernel<<<256, 256, 0, stream>>>(WTFB, ZFB, KTB, GC, TRB, BF);

  scan_state_kernel<<<64, 256, 0, stream>>>(TRB, BF, st0, SALL, out + 4194304);

  scan_output_kernel<<<256, 512, 0, stream>>>(QH, WTB, (const __hip_bfloat16*)ZB,
                                              PHB, GV, SALL, OBUF);

  gate_ln_kernel<<<BLQ, 256, 0, stream>>>(OBUF, VG, CBUFH, lnw, lnb, LNO);

  gemm_bt_kernel<float><<<dim3(32, 8), 256, 0, stream>>>(
      LNO, WOB, out, BLQ, DMQ, TOTQ, nullptr, 0);
}

// Round 9
// 151.420 us; speedup vs baseline: 2.1783x; 1.0521x over previous
//
#include <hip/hip_runtime.h>
#include <hip/hip_bf16.h>

// Problem constants
#define BQ    2
#define LQ    2048
#define DMQ   1024
#define HQ    4
#define DHQ   128
#define TOTQ  512
#define BLQ   4096      // B*L
#define NPROJ 2688      // padded concat: Wq(512) Wk(512) Wv(1024) Wg(512) Wa(4) Wb(4) pad(120)
#define KPROJ 1024
#define CT    64        // scan chunk length
#define NCH   32        // chunks (LQ/CT)

typedef short bf16x8 __attribute__((ext_vector_type(8)));
typedef short s16x4  __attribute__((ext_vector_type(4)));
typedef float f32x4  __attribute__((ext_vector_type(4)));

#define MFMA16(a, b, c) __builtin_amdgcn_mfma_f32_16x16x32_bf16(a, b, c, 0, 0, 0)

__device__ __forceinline__ float siluf(float x) { return x / (1.f + __expf(-x)); }
__device__ __forceinline__ float sigf(float x)  { return 1.f / (1.f + __expf(-x)); }
__device__ __forceinline__ short bf16s(float x) {
  return __builtin_bit_cast(short, __float2bfloat16(x));
}
__device__ __forceinline__ float bfu2f(unsigned short u) {
  return __bfloat162float(__builtin_bit_cast(__hip_bfloat16, u));
}
__device__ __forceinline__ bf16x8 pack8(f32x4 a, f32x4 b) {
  bf16x8 r;
  r[0] = bf16s(a.x); r[1] = bf16s(a.y); r[2] = bf16s(a.z); r[3] = bf16s(a.w);
  r[4] = bf16s(b.x); r[5] = bf16s(b.y); r[6] = bf16s(b.z); r[7] = bf16s(b.w);
  return r;
}

// global -> LDS direct load, 16B per lane. LDS dest must be wave-uniform base;
// HW writes base + lane*16.
__device__ __forceinline__ void gload_lds16(const void* g, void* l) {
  __builtin_amdgcn_global_load_lds(
      (__attribute__((address_space(1))) void*)(unsigned long long)g,
      (__attribute__((address_space(3))) void*)(unsigned int)(unsigned long long)l,
      16, 0, 0);
}

// ---------------- casts ----------------
__global__ __launch_bounds__(256)
void cast_f32_bf16_kernel(const float* __restrict__ src, __hip_bfloat16* __restrict__ dst, int n4)
{
  int i = blockIdx.x * 256 + threadIdx.x;
  if (i < n4) {
    float4 v = ((const float4*)src)[i];
    __hip_bfloat16 o[4] = { __float2bfloat16(v.x), __float2bfloat16(v.y),
                            __float2bfloat16(v.z), __float2bfloat16(v.w) };
    *(ushort4*)((unsigned short*)dst + (size_t)i * 4) = *(ushort4*)o;
  }
}

// float4-vectorized concat cast (4 elems per thread, row-uniform branch)
__global__ __launch_bounds__(256)
void cast_wcat_kernel(const float* __restrict__ Wq, const float* __restrict__ Wk,
                      const float* __restrict__ Wv, const float* __restrict__ Wg,
                      const float* __restrict__ Wa, const float* __restrict__ Wb,
                      __hip_bfloat16* __restrict__ Wcat)
{
  int i4 = blockIdx.x * 256 + threadIdx.x;   // 0 .. 2688*256-1
  int row = i4 >> 8;
  int col = (i4 & 255) * 4;
  int idx = row * 1024 + col;
  float4 v;
  if      (row < 512)  v = *(const float4*)(Wq + idx);
  else if (row < 1024) v = *(const float4*)(Wk + idx - 512 * 1024);
  else if (row < 2048) v = *(const float4*)(Wv + idx - 1024 * 1024);
  else if (row < 2560) v = *(const float4*)(Wg + idx - 2048 * 1024);
  else if (row < 2564) v = *(const float4*)(Wa + (row - 2560) * 1024 + col);
  else if (row < 2568) v = *(const float4*)(Wb + (row - 2564) * 1024 + col);
  else                 v = make_float4(0.f, 0.f, 0.f, 0.f);
  __hip_bfloat16 o[4] = { __float2bfloat16(v.x), __float2bfloat16(v.y),
                          __float2bfloat16(v.z), __float2bfloat16(v.w) };
  *(ushort4*)((unsigned short*)Wcat + idx) = *(ushort4*)o;
}

// ---------------- bf16 MFMA GEMM: C(TOUT, MxN) = A(M,K) * B(N,K)^T ----------------
// 2-phase double-buffered LDS. TOUT = __hip_bfloat16 (proj) or float (final).
// If aux != nullptr, output columns [auxc0, auxc0+8) are ALSO stored f32 to
// aux[row*8 + (col-auxc0)] (keeps alpha/beta logits full-precision).
template <typename TOUT>
__global__ __launch_bounds__(256)
void gemm_bt_kernel(const __hip_bfloat16* __restrict__ A,
                    const __hip_bfloat16* __restrict__ Bw,
                    TOUT* __restrict__ C, int M, int N, int K,
                    float* __restrict__ aux, int auxc0)
{
  __shared__ __hip_bfloat16 As[2 * 128 * 32];
  __shared__ __hip_bfloat16 Bs[2 * 128 * 32];
  const int tid  = threadIdx.x;
  const int lane = tid & 63;
  const int w    = tid >> 6;
  const int wm   = w >> 1, wn = w & 1;
  const int tm   = blockIdx.x, tn = blockIdx.y;
  const int lr   = lane & 15, lk = lane >> 4;

  f32x4 acc[4][4] = {};

  const int e0   = tid * 8;
  const int srow = e0 >> 5;        // 0..63
  const int scol = e0 & 31;
  const __hip_bfloat16* Ap = A  + (size_t)(tm * 128 + srow) * K + scol;
  const __hip_bfloat16* Bp = Bw + (size_t)(tn * 128 + srow) * K + scol;
  char* AsB  = (char*)As;
  char* BsB  = (char*)Bs;
  const size_t half = (size_t)64 * K;
  const int nk = K >> 5;

  // prologue: stage K-tile 0 into buffer 0
  {
    char* AsD = AsB + w * 1024;
    char* BsD = BsB + w * 1024;
    gload_lds16(Ap,        AsD);
    gload_lds16(Ap + half, AsD + 4096);
    gload_lds16(Bp,        BsD);
    gload_lds16(Bp + half, BsD + 4096);
  }
  __syncthreads();

  for (int it = 0; it < nk; ++it) {
    const int sel = it & 1;
    // prefetch next K-tile into the other buffer (no wait here)
    if (it + 1 < nk) {
      const int kk = (it + 1) * 32;
      char* AsD = AsB + ((sel ^ 1) * 8192) + w * 1024;
      char* BsD = BsB + ((sel ^ 1) * 8192) + w * 1024;
      gload_lds16(Ap + kk,        AsD);
      gload_lds16(Ap + half + kk, AsD + 4096);
      gload_lds16(Bp + kk,        BsD);
      gload_lds16(Bp + half + kk, BsD + 4096);
    }
    // compute on current buffer
    const char* AsR = AsB + sel * 8192;
    const char* BsR = BsB + sel * 8192;
    bf16x8 af[4], bfv[4];
#pragma unroll
    for (int m = 0; m < 4; ++m)
      af[m]  = *(const bf16x8*)(AsR + ((wm * 64 + m * 16 + lr) * 32 + lk * 8) * 2);
#pragma unroll
    for (int n = 0; n < 4; ++n)
      bfv[n] = *(const bf16x8*)(BsR + ((wn * 64 + n * 16 + lr) * 32 + lk * 8) * 2);
#pragma unroll
    for (int m = 0; m < 4; ++m)
#pragma unroll
      for (int n = 0; n < 4; ++n)
        acc[m][n] = MFMA16(af[m], bfv[n], acc[m][n]);
    // barrier (drains vmcnt): next tile resident, current buffer reusable
    __syncthreads();
  }

  const int crow0 = tm * 128 + wm * 64 + (lane >> 4) * 4;
  const int ccol0 = tn * 128 + wn * 64 + lr;
#pragma unroll
  for (int m = 0; m < 4; ++m)
#pragma unroll
    for (int n = 0; n < 4; ++n) {
      const int cc = ccol0 + n * 16;
#pragma unroll
      for (int j = 0; j < 4; ++j) {
        const float v = acc[m][n][j];
        const size_t row = (size_t)(crow0 + m * 16 + j);
        if constexpr (sizeof(TOUT) == 2)
          ((unsigned short*)C)[row * N + cc] = (unsigned short)bf16s(v);
        else
          C[row * N + cc] = v;
        if (aux && cc >= auxc0 && cc < auxc0 + 8)
          aux[row * 8 + (cc - auxc0)] = v;
      }
    }
}

// ---------------- conv(4-tap causal) + silu + l2norm + sigmoid(a,b) ----------------
// Sliding-window over 8 timesteps per block (512 blocks). CBUF is bf16;
// alpha/beta logits come from the f32 side buffer abf. Outputs bf16.
__global__ __launch_bounds__(256)
void conv_act_kernel(const __hip_bfloat16* __restrict__ C, const float* __restrict__ abf,
                     const float* __restrict__ qcw, const float* __restrict__ qcb,
                     const float* __restrict__ kcw, const float* __restrict__ kcb,
                     const float* __restrict__ vcw, const float* __restrict__ vcb,
                     __hip_bfloat16* __restrict__ qh, __hip_bfloat16* __restrict__ kh,
                     __hip_bfloat16* __restrict__ vm, __hip_bfloat16* __restrict__ vg,
                     float* __restrict__ al, float* __restrict__ be)
{
  const int blk = blockIdx.x;           // 512
  const int bl0 = blk * 8;              // global row start (never crosses b: 2048%8==0)
  const int t0  = bl0 & (LQ - 1);       // local t start
  const int tid = threadIdx.x;
  const unsigned short* Cu = (const unsigned short*)C;
  __shared__ float red[4][16];

  float2 qv[8], kv[8];
  float sq[8], sk[8];
#pragma unroll
  for (int t = 0; t < 8; ++t) { sq[t] = 0.f; sk[t] = 0.f; }

  {
    const int c0 = tid * 2;
    const float4 wqA = *(const float4*)(qcw + 4 * c0);
    const float4 wqB = *(const float4*)(qcw + 4 * c0 + 4);
    const float4 wkA = *(const float4*)(kcw + 4 * c0);
    const float4 wkB = *(const float4*)(kcw + 4 * c0 + 4);
    const float2 bq = *(const float2*)(qcb + c0);
    const float2 bk = *(const float2*)(kcb + c0);
    float2 wrq[11], wrk[11];
#pragma unroll
    for (int r = 0; r < 11; ++r) {
      const int tt = t0 - 3 + r;
      if (tt >= 0) {
        const unsigned short* Cr = Cu + (size_t)(bl0 - 3 + r) * NPROJ;
        const ushort2 aq = *(const ushort2*)(Cr + c0);
        const ushort2 ak = *(const ushort2*)(Cr + 512 + c0);
        wrq[r] = make_float2(bfu2f(aq.x), bfu2f(aq.y));
        wrk[r] = make_float2(bfu2f(ak.x), bfu2f(ak.y));
      } else {
        wrq[r] = make_float2(0.f, 0.f);
        wrk[r] = make_float2(0.f, 0.f);
      }
    }
#pragma unroll
    for (int t = 0; t < 8; ++t) {
      float aq0 = bq.x, aq1 = bq.y, ak0 = bk.x, ak1 = bk.y;
#pragma unroll
      for (int j = 0; j < 4; ++j) {
        aq0 = fmaf(((const float*)&wqA)[j], wrq[t + j].x, aq0);
        aq1 = fmaf(((const float*)&wqB)[j], wrq[t + j].y, aq1);
        ak0 = fmaf(((const float*)&wkA)[j], wrk[t + j].x, ak0);
        ak1 = fmaf(((const float*)&wkB)[j], wrk[t + j].y, ak1);
      }
      const float q0 = siluf(aq0), q1 = siluf(aq1);
      const float k0 = siluf(ak0), k1 = siluf(ak1);
      qv[t] = make_float2(q0, q1);
      kv[t] = make_float2(k0, k1);
      sq[t] = fmaf(q1, q1, fmaf(q0, q0, sq[t]));
      sk[t] = fmaf(k1, k1, fmaf(k0, k0, sk[t]));
    }
  }
  // reduce sq,sk across 64 lanes, then across 4 waves
#pragma unroll
  for (int m = 1; m < 64; m <<= 1) {
#pragma unroll
    for (int t = 0; t < 8; ++t) {
      sq[t] += __shfl_xor(sq[t], m);
      sk[t] += __shfl_xor(sk[t], m);
    }
  }
  {
    const int w = tid >> 6, lane = tid & 63;
    if (lane == 0) {
#pragma unroll
      for (int t = 0; t < 8; ++t) { red[w][t] = sq[t]; red[w][8 + t] = sk[t]; }
    }
  }
  __syncthreads();
  float rnq[8], rnk[8];
#pragma unroll
  for (int t = 0; t < 8; ++t) {
    const float SQ = red[0][t] + red[1][t] + red[2][t] + red[3][t];
    const float SK = red[0][8 + t] + red[1][8 + t] + red[2][8 + t] + red[3][8 + t];
    rnq[t] = 1.f / fmaxf(sqrtf(SQ), 1e-12f);
    rnk[t] = 1.f / fmaxf(sqrtf(SK), 1e-12f);
  }
  {
    const int c0 = tid * 2;
#pragma unroll
    for (int t = 0; t < 8; ++t) {
      ushort2 oq, ok;
      oq.x = (unsigned short)bf16s(qv[t].x * rnq[t]);
      oq.y = (unsigned short)bf16s(qv[t].y * rnq[t]);
      ok.x = (unsigned short)bf16s(kv[t].x * rnk[t]);
      ok.y = (unsigned short)bf16s(kv[t].y * rnk[t]);
      *(ushort2*)((unsigned short*)qh + (size_t)(bl0 + t) * 512 + c0) = oq;
      *(ushort2*)((unsigned short*)kh + (size_t)(bl0 + t) * 512 + c0) = ok;
    }
  }
  // v: 4 consecutive channels per thread
  {
    const int cv = tid * 4;   // 0..1023
    const float4 wv0 = *(const float4*)(vcw + 4 * cv);
    const float4 wv1 = *(const float4*)(vcw + 4 * cv + 4);
    const float4 wv2 = *(const float4*)(vcw + 4 * cv + 8);
    const float4 wv3 = *(const float4*)(vcw + 4 * cv + 12);
    const float4 bv4 = *(const float4*)(vcb + cv);
    float4 wr[11];
#pragma unroll
    for (int r = 0; r < 11; ++r) {
      const int tt = t0 - 3 + r;
      if (tt >= 0) {
        const ushort4 u = *(const ushort4*)(Cu + (size_t)(bl0 - 3 + r) * NPROJ + 1024 + cv);
        wr[r] = make_float4(bfu2f(u.x), bfu2f(u.y), bfu2f(u.z), bfu2f(u.w));
      } else {
        wr[r] = make_float4(0.f, 0.f, 0.f, 0.f);
      }
    }
#pragma unroll
    for (int t = 0; t < 8; ++t) {
      float a0 = bv4.x, a1 = bv4.y, a2 = bv4.z, a3 = bv4.w;
#pragma unroll
      for (int j = 0; j < 4; ++j) {
        a0 = fmaf(((const float*)&wv0)[j], ((const float*)&wr[t + j])[0], a0);
        a1 = fmaf(((const float*)&wv1)[j], ((const float*)&wr[t + j])[1], a1);
        a2 = fmaf(((const float*)&wv2)[j], ((const float*)&wr[t + j])[2], a2);
        a3 = fmaf(((const float*)&wv3)[j], ((const float*)&wr[t + j])[3], a3);
      }
      ushort4 o;
      o.x = (unsigned short)bf16s(siluf(a0));
      o.y = (unsigned short)bf16s(siluf(a1));
      o.z = (unsigned short)bf16s(siluf(a2));
      o.w = (unsigned short)bf16s(siluf(a3));
      if (cv < 512) *(ushort4*)((unsigned short*)vm + (size_t)(bl0 + t) * 512 + cv)         = o;
      else          *(ushort4*)((unsigned short*)vg + (size_t)(bl0 + t) * 512 + (cv - 512)) = o;
    }
  }
  // alpha/beta from f32 side buffer: threads 0..63 cover 8 t x (4 al + 4 be)
  if (tid < 64) {
    const int t = tid >> 3;
    const int k = tid & 7;
    const float v = abf[(size_t)(bl0 + t) * 8 + k];
    if (k < 4) al[(size_t)(bl0 + t) * 4 + k]       = sigf(v);
    else       be[(size_t)(bl0 + t) * 4 + (k - 4)] = sigf(v);
  }
}

// ---------------- scan phase A (FUSED with transition) ----------------
// 256 blocks = 32 chunks x 8 (b,h). Per chunk:
//   d_t = cumsum log a;  G = K K^T, Pq = Q K^T (MFMA bf16)
//   L_{ts} = b_t e^{d_t-d_s} G_{ts} (t>s)
//   KT (LDS) = K^T built from staged KBl (bit-identical bf16)
//   solve (I+L)[W~|Z] = [diag(b e^d) K | diag(b) V]  (blocked f32 fwd subst.)
//   store W~ (bf16), Z (bf16), Phat (bf16); WTF/ZF f-scaled transposes -> LDS
//   THEN (same block, after barrier) the transition factors:
//     T^T(j,m) = gc d(j,m) - sum_s KT(j,s) WTF(m,s)  -> TRB (bf16)
//     B(i,j)   = sum_s ZF(i,s) KT(j,s)               -> BF (f32)
// LDS 133 KB (1 block/CU, same as unfused). Saves 24 MB of global traffic
// (WTFB/ZFB/KTB write+read) and one kernel launch.
__global__ __launch_bounds__(256)
void scan_phaseA_kernel(const __hip_bfloat16* __restrict__ qh, const __hip_bfloat16* __restrict__ kh,
                        const __hip_bfloat16* __restrict__ vm, const float* __restrict__ al,
                        const float* __restrict__ be,
                        short* __restrict__ WTB, short* __restrict__ ZB,
                        short* __restrict__ PHB, float* __restrict__ GV,
                        short* __restrict__ TRB, float* __restrict__ BF)
{
  __shared__ char sm[136192];
  float* Xl = (float*)(sm);                             // [64][256] f32 (aliases KBl/QBl)
  __hip_bfloat16* KBl = (__hip_bfloat16*)(sm);          // [64][136]
  __hip_bfloat16* QBl = (__hip_bfloat16*)(sm + 17408);  // [64][136]
  float* Ll  = (float*)(sm + 65536);                    // [64][68]
  float* dv  = (float*)(sm + 82944);                    // [64]
  float* bv  = (float*)(sm + 83200);                    // [64]
  float* gbv = (float*)(sm + 83456);                    // [64]
  float* fvs = (float*)(sm + 83712);                    // [64]
  short* KTl  = (short*)(sm + 83968);                   // [128][68] bf16
  short* WTFl = (short*)(sm + 101376);                  // [128][68] bf16
  short* ZFl  = (short*)(sm + 118784);                  // [128][68] bf16

  const int cb = blockIdx.x;
  const int bh = cb & 7, c = cb >> 3;
  const int b = bh >> 2, h = bh & 3;
  const int tid = threadIdx.x;
  const int lane = tid & 63;
  const int w = tid >> 6;
  const int lr = lane & 15, lk = lane >> 4;
  const size_t rowbase = (size_t)(b * LQ + c * CT) * 512 + h * 128;

  // stage K,Q -> LDS bf16 (padded rows of 136); direct 16B copies
#pragma unroll
  for (int rep = 0; rep < 4; ++rep) {
    const int fid = tid + rep * 256;       // 0..1023
    const int r = fid >> 4;
    const int cg = (fid & 15) * 8;
    *(bf16x8*)(KBl + r * 136 + cg) = *(const bf16x8*)(kh + rowbase + (size_t)r * 512 + cg);
    *(bf16x8*)(QBl + r * 136 + cg) = *(const bf16x8*)(qh + rowbase + (size_t)r * 512 + cg);
  }
  // decay prefix (wave 0)
  if (w == 0) {
    float la = __logf(al[(size_t)(b * LQ + c * CT + lane) * 4 + h]);
    const float bb = be[(size_t)(b * LQ + c * CT + lane) * 4 + h];
#pragma unroll
    for (int off = 1; off < 64; off <<= 1) {
      const float tv = __shfl_up(la, off, 64);
      if (lane >= off) la += tv;
    }
    dv[lane] = la; bv[lane] = bb; gbv[lane] = bb * __expf(la);
    const float d63 = __shfl(la, 63, 64);
    fvs[lane] = __expf(d63 - la);
    GV[cb * 64 + lane] = __expf(la);
  }
  __syncthreads();

  // G = K K^T, Pq = Q K^T  (each wave owns one 16-row t-band)
  f32x4 aG[4] = {}, aP[4] = {};
#pragma unroll
  for (int ks = 0; ks < 4; ++ks) {
    bf16x8 bk[4];
#pragma unroll
    for (int nt = 0; nt < 4; ++nt)
      bk[nt] = *(const bf16x8*)(KBl + (nt * 16 + lr) * 136 + ks * 32 + lk * 8);
    const bf16x8 ak = *(const bf16x8*)(KBl + (w * 16 + lr) * 136 + ks * 32 + lk * 8);
    const bf16x8 aq = *(const bf16x8*)(QBl + (w * 16 + lr) * 136 + ks * 32 + lk * 8);
#pragma unroll
    for (int nt = 0; nt < 4; ++nt) {
      aG[nt] = MFMA16(ak, bk[nt], aG[nt]);
      aP[nt] = MFMA16(aq, bk[nt], aP[nt]);
    }
  }
#pragma unroll
  for (int nt = 0; nt < 4; ++nt)
#pragma unroll
    for (int jj = 0; jj < 4; ++jj) {
      const int t = w * 16 + lk * 4 + jj;
      const int s = nt * 16 + lr;
      const float eg = __expf(dv[t] - dv[s]);
      Ll[t * 68 + s] = (t > s) ? bv[t] * eg * aG[nt][jj] : 0.f;
      PHB[(size_t)cb * 4096 + t * 64 + s] = (s <= t) ? bf16s(eg * aP[nt][jj]) : (short)0;
    }
  // KT (LDS) = K^T from staged KBl, BEFORE Xl overwrites it
  if (tid < 128) {
    const short* Kbs = (const short*)KBl;
#pragma unroll
    for (int s4 = 0; s4 < 16; ++s4) {
      s16x4 pk;
#pragma unroll
      for (int e = 0; e < 4; ++e)
        pk[e] = Kbs[(s4 * 4 + e) * 136 + tid];
      *(s16x4*)(KTl + tid * 68 + s4 * 4) = pk;
    }
  }
  __syncthreads();   // KBl/QBl dead from here -> Xl may overwrite

  // ---- blocked forward substitution: thread j owns column j ----
  const int j = tid;
  const __hip_bfloat16* src = (j < 128) ? kh : vm;
  const __hip_bfloat16* xp = src + rowbase + (j & 127);
  float* XlC = Xl + j;                 // private column, stride 256 floats
  short* dstN = (j < 128) ? (WTB + (size_t)cb * 8192 + j)
                          : (ZB  + (size_t)cb * 8192 + (j - 128));
  short* dstT = (j < 128) ? (WTFl + j * 68)
                          : (ZFl  + (j - 128) * 68);

  for (int r = 0; r < 4; ++r) {
    float u[16];
    // RHS block (scaled)
#pragma unroll
    for (int i = 0; i < 16; ++i) {
      const int t = r * 16 + i;
      u[i] = __bfloat162float(xp[(size_t)t * 512]) * ((j < 128) ? gbv[t] : bv[t]);
    }
    // cross-block updates from already-solved 16-blocks (LDS spill)
    for (int sc = 0; sc < r; ++sc) {
      float xs[16];
#pragma unroll
      for (int k = 0; k < 16; ++k) xs[k] = XlC[(sc * 16 + k) * 256];
#pragma unroll
      for (int i = 0; i < 16; ++i) {
        const float* lrow = Ll + (r * 16 + i) * 68 + sc * 16;
        const f32x4 l0 = *(const f32x4*)(lrow);
        const f32x4 l1 = *(const f32x4*)(lrow + 4);
        const f32x4 l2 = *(const f32x4*)(lrow + 8);
        const f32x4 l3 = *(const f32x4*)(lrow + 12);
        f32x4 acc = {};
        acc.x = fmaf(l0.x, xs[0],  acc.x); acc.y = fmaf(l0.y, xs[1],  acc.y);
        acc.z = fmaf(l0.z, xs[2],  acc.z); acc.w = fmaf(l0.w, xs[3],  acc.w);
        acc.x = fmaf(l1.x, xs[4],  acc.x); acc.y = fmaf(l1.y, xs[5],  acc.y);
        acc.z = fmaf(l1.z, xs[6],  acc.z); acc.w = fmaf(l1.w, xs[7],  acc.w);
        acc.x = fmaf(l2.x, xs[8],  acc.x); acc.y = fmaf(l2.y, xs[9],  acc.y);
        acc.z = fmaf(l2.z, xs[10], acc.z); acc.w = fmaf(l2.w, xs[11], acc.w);
        acc.x = fmaf(l3.x, xs[12], acc.x); acc.y = fmaf(l3.y, xs[13], acc.y);
        acc.z = fmaf(l3.z, xs[14], acc.z); acc.w = fmaf(l3.w, xs[15], acc.w);
        u[i] -= (acc.x + acc.y) + (acc.z + acc.w);
      }
    }
    // in-block serial solve (rows above diag of Ll are zero)
#pragma unroll
    for (int i = 1; i < 16; ++i) {
      const float* lrow = Ll + (r * 16 + i) * 68 + r * 16;
      f32x4 acc = {};
#pragma unroll
      for (int k4 = 0; k4 < 4; ++k4) {
        if (k4 * 4 < i) {
          const f32x4 lv = *(const f32x4*)(lrow + k4 * 4);
          acc.x = fmaf(lv.x, u[k4 * 4 + 0], acc.x);
          acc.y = fmaf(lv.y, u[k4 * 4 + 1], acc.y);
          acc.z = fmaf(lv.z, u[k4 * 4 + 2], acc.z);
          acc.w = fmaf(lv.w, u[k4 * 4 + 3], acc.w);
        }
      }
      u[i] -= (acc.x + acc.y) + (acc.z + acc.w);
    }
    // spill for future blocks
    if (r < 3) {
#pragma unroll
      for (int i = 0; i < 16; ++i) XlC[(r * 16 + i) * 256] = u[i];
    }
    // stores: W~/Z (bf16, global) and f-scaled transposed WTF/ZF (LDS)
#pragma unroll
    for (int i = 0; i < 16; ++i)
      dstN[(r * 16 + i) * 128] = bf16s(u[i]);
#pragma unroll
    for (int s4 = 0; s4 < 4; ++s4) {
      s16x4 p;
#pragma unroll
      for (int e = 0; e < 4; ++e)
        p[e] = bf16s(fvs[r * 16 + s4 * 4 + e] * u[s4 * 4 + e]);
      *(s16x4*)(dstT + r * 16 + s4 * 4) = p;
    }
  }
  __syncthreads();   // WTFl/ZFl/KTl ready for all waves

  // ---- fused transition: T^T and B from LDS operands ----
  const float gc = __expf(dv[63]);
  {
    f32x4 acc[2][8] = {};
#pragma unroll
    for (int ks = 0; ks < 2; ++ks) {
      const bf16x8 a0 = *(const bf16x8*)(KTl + (w * 32 + lr) * 68 + ks * 32 + lk * 8);
      const bf16x8 a1 = *(const bf16x8*)(KTl + (w * 32 + 16 + lr) * 68 + ks * 32 + lk * 8);
#pragma unroll
      for (int nt = 0; nt < 8; ++nt) {
        const bf16x8 bm = *(const bf16x8*)(WTFl + (nt * 16 + lr) * 68 + ks * 32 + lk * 8);
        acc[0][nt] = MFMA16(a0, bm, acc[0][nt]);
        acc[1][nt] = MFMA16(a1, bm, acc[1][nt]);
      }
    }
#pragma unroll
    for (int mt = 0; mt < 2; ++mt)
#pragma unroll
      for (int nt = 0; nt < 8; ++nt)
#pragma unroll
        for (int jj = 0; jj < 4; ++jj) {
          const int jr = w * 32 + mt * 16 + lk * 4 + jj;
          const int m  = nt * 16 + lr;
          const float v = ((jr == m) ? gc : 0.f) - acc[mt][nt][jj];
          TRB[(size_t)cb * 16384 + jr * 128 + m] = bf16s(v);
        }
  }
  {
    f32x4 acc[2][8] = {};
#pragma unroll
    for (int ks = 0; ks < 2; ++ks) {
      const bf16x8 a0 = *(const bf16x8*)(ZFl + (w * 32 + lr) * 68 + ks * 32 + lk * 8);
      const bf16x8 a1 = *(const bf16x8*)(ZFl + (w * 32 + 16 + lr) * 68 + ks * 32 + lk * 8);
#pragma unroll
      for (int nt = 0; nt < 8; ++nt) {
        const bf16x8 bj = *(const bf16x8*)(KTl + (nt * 16 + lr) * 68 + ks * 32 + lk * 8);
        acc[0][nt] = MFMA16(a0, bj, acc[0][nt]);
        acc[1][nt] = MFMA16(a1, bj, acc[1][nt]);
      }
    }
#pragma unroll
    for (int mt = 0; mt < 2; ++mt)
#pragma unroll
      for (int nt = 0; nt < 8; ++nt)
#pragma unroll
        for (int jj = 0; jj < 4; ++jj) {
          const int ir = w * 32 + mt * 16 + lk * 4 + jj;
          const int jc = nt * 16 + lr;
          BF[(size_t)cb * 16384 + ir * 128 + jc] = acc[mt][nt][jj];
        }
  }
}

// ---------------- scan state: serial chunk recurrence, S rows independent ----
#define L2_PREFETCH(BT, BA, CC) do {                                               \
  const int cbn_ = (CC) * 8 + bh;                                                  \
  _Pragma("unroll") for (int nt = 0; nt < 2; ++nt) {                               \
    _Pragma("unroll") for (int ks = 0; ks < 4; ++ks)                               \
      BT[nt][ks] = *(const bf16x8*)(TRB + (size_t)cbn_ * 16384 +                   \
                                    (w * 32 + nt * 16 + lr) * 128 + ks * 32 + lk * 8); \
    _Pragma("unroll") for (int jj = 0; jj < 4; ++jj)                               \
      BA[nt][jj] = BF[(size_t)cbn_ * 16384 + (r0 + lk * 4 + jj) * 128 +            \
                      w * 32 + nt * 16 + lr];                                      \
  }                                                                                \
} while (0)

#define L2_STEP(BT, BA, CC, PBT, PBA) do {                                         \
  const int cb_ = (CC) * 8 + bh;                                                   \
  { const int idx = tid * 8, r = idx >> 7, jc = idx & 127;                         \
    f32x4 s0 = *(const f32x4*)&Scur[r * 132 + jc];                                 \
    f32x4 s1 = *(const f32x4*)&Scur[r * 132 + jc + 4];                             \
    *(bf16x8*)(SALL + (size_t)cb_ * 16384 + (r0 + r) * 128 + jc) = pack8(s0, s1); }\
  bf16x8 af[4];                                                                    \
  _Pragma("unroll") for (int ks = 0; ks < 4; ++ks)                                 \
    af[ks] = pack8(*(const f32x4*)&Scur[lr * 132 + ks * 32 + lk * 8],              \
                   *(const f32x4*)&Scur[lr * 132 + ks * 32 + lk * 8 + 4]);         \
  if ((CC) < 31) L2_PREFETCH(PBT, PBA, (CC) + 1);                                  \
  f32x4 acc0 = {}, acc1 = {};                                                      \
  _Pragma("unroll") for (int ks = 0; ks < 4; ++ks) {                               \
    acc0 = MFMA16(af[ks], BT[0][ks], acc0);                                        \
    acc1 = MFMA16(af[ks], BT[1][ks], acc1);                                        \
  }                                                                                \
  _Pragma("unroll") for (int jj = 0; jj < 4; ++jj) {                               \
    Snxt[(lk * 4 + jj) * 132 + w * 32 + lr]      = acc0[jj] + BA[0][jj];           \
    Snxt[(lk * 4 + jj) * 132 + w * 32 + 16 + lr] = acc1[jj] + BA[1][jj];           \
  }                                                                                \
  __syncthreads();                                                                 \
  { float* t_ = Scur; Scur = Snxt; Snxt = t_; }                                    \
} while (0)

__global__ __launch_bounds__(256)
void scan_state_kernel(const short* __restrict__ TRB, const float* __restrict__ BF,
                       const float* __restrict__ st0, short* __restrict__ SALL,
                       float* __restrict__ stout)
{
  __shared__ float Sl[2 * 16 * 132];
  const int bid = blockIdx.x;            // 64
  const int bh = bid & 7, slab = bid >> 3;
  const int r0 = slab * 16;
  const int tid = threadIdx.x, lane = tid & 63, w = tid >> 6;
  const int lr = lane & 15, lk = lane >> 4;

  float* Scur = Sl;
  float* Snxt = Sl + 16 * 132;

  // load st0 slab
  {
    const int idx = tid * 8, r = idx >> 7, jc = idx & 127;
    const float* sp = st0 + ((size_t)bh * 128 + r0 + r) * 128 + jc;
    *(f32x4*)&Scur[r * 132 + jc]     = *(const f32x4*)sp;
    *(f32x4*)&Scur[r * 132 + jc + 4] = *(const f32x4*)(sp + 4);
  }
  bf16x8 btA[2][4], btB[2][4];
  float  baA[2][4], baB[2][4];
  L2_PREFETCH(btA, baA, 0);
  __syncthreads();

  for (int c2 = 0; c2 < 16; ++c2) {
    L2_STEP(btA, baA, 2 * c2,     btB, baB);
    L2_STEP(btB, baB, 2 * c2 + 1, btA, baA);
  }

  // final state (Scur holds S_32 after 32 swaps)
  {
    const int idx = tid * 8, r = idx >> 7, jc = idx & 127;
    float* sp = stout + ((size_t)bh * 128 + r0 + r) * 128 + jc;
    *(f32x4*)sp       = *(const f32x4*)&Scur[r * 132 + jc];
    *(f32x4*)(sp + 4) = *(const f32x4*)&Scur[r * 132 + jc + 4];
  }
}

// ---------------- scan output: fully parallel over chunks ----------------
__global__ __launch_bounds__(512)
void scan_output_kernel(const __hip_bfloat16* __restrict__ qh,
                        const short* __restrict__ WTB, const __hip_bfloat16* __restrict__ ZB,
                        const short* __restrict__ PHB, const float* __restrict__ GV,
                        const short* __restrict__ SALL, float* __restrict__ obuf)
{
  __shared__ short Ut[128 * 72];
  const int cb = blockIdx.x;
  const int bh = cb & 7, c = cb >> 3;
  const int b = bh >> 2, h = bh & 3;
  const int tid = threadIdx.x, lane = tid & 63, w = tid >> 6;   // w 0..7
  const int lr = lane & 15, lk = lane >> 4;
  const int r0 = (w & 3) * 16;

  f32x4 Y[8] = {};
#pragma unroll
  for (int ks = 0; ks < 4; ++ks) {
    bf16x8 af;
    if (w < 4) {
      af = *(const bf16x8*)(qh + ((size_t)(b * LQ + c * CT) + r0 + lr) * 512 + h * 128 + ks * 32 + lk * 8);
    } else {
      af = *(const bf16x8*)(WTB + (size_t)cb * 8192 + (r0 + lr) * 128 + ks * 32 + lk * 8);
    }
#pragma unroll
    for (int nt = 0; nt < 8; ++nt) {
      const bf16x8 bs = *(const bf16x8*)(SALL + (size_t)cb * 16384 + (nt * 16 + lr) * 128 + ks * 32 + lk * 8);
      Y[nt] = MFMA16(af, bs, Y[nt]);
    }
  }
  if (w >= 4) {   // U = Z - Y_low -> LDS (Ut[i][s])
#pragma unroll
    for (int nt = 0; nt < 8; ++nt) {
      const int i = nt * 16 + lr;
      s16x4 up;
#pragma unroll
      for (int jj = 0; jj < 4; ++jj) {
        const int s = r0 + lk * 4 + jj;
        const float z = __bfloat162float(ZB[(size_t)cb * 8192 + s * 128 + i]);
        up[jj] = bf16s(z - Y[nt][jj]);
      }
      *(s16x4*)&Ut[i * 72 + r0 + lk * 4] = up;
    }
  }
  __syncthreads();
  if (w < 4) {
    f32x4 P2[8] = {};
#pragma unroll
    for (int ks = 0; ks < 2; ++ks) {
      const bf16x8 ap = *(const bf16x8*)(PHB + (size_t)cb * 4096 + (r0 + lr) * 64 + ks * 32 + lk * 8);
#pragma unroll
      for (int nt = 0; nt < 8; ++nt) {
        const bf16x8 bu = *(const bf16x8*)&Ut[(nt * 16 + lr) * 72 + ks * 32 + lk * 8];
        P2[nt] = MFMA16(ap, bu, P2[nt]);
      }
    }
    float gvv[4];
#pragma unroll
    for (int jj = 0; jj < 4; ++jj) gvv[jj] = GV[cb * 64 + r0 + lk * 4 + jj];
#pragma unroll
    for (int nt = 0; nt < 8; ++nt) {
      const int i = nt * 16 + lr;
#pragma unroll
      for (int jj = 0; jj < 4; ++jj) {
        const int t = r0 + lk * 4 + jj;
        obuf[((size_t)(b * LQ + c * CT) + t) * 512 + h * 128 + i] =
            gvv[jj] * Y[nt][jj] + P2[nt][jj];
      }
    }
  }
}

// ---------------- gate * silu(g), LayerNorm(512), cast bf16 ----------------
__global__ __launch_bounds__(256)
void gate_ln_kernel(const float* __restrict__ obuf, const __hip_bfloat16* __restrict__ vg,
                    const __hip_bfloat16* __restrict__ C, const float* __restrict__ lnw,
                    const float* __restrict__ lnb, __hip_bfloat16* __restrict__ lno)
{
  const int bl = blockIdx.x, tid = threadIdx.x;
  const int c0 = tid * 2;
  __shared__ float red[8];
  const float2 ov = *(const float2*)(obuf + (size_t)bl * 512 + c0);
  const ushort2 gvu = *(const ushort2*)((const unsigned short*)vg + (size_t)bl * 512 + c0);
  const ushort2 ggu = *(const ushort2*)((const unsigned short*)C + (size_t)bl * NPROJ + 2048 + c0);
  const float v0 = ov.x * bfu2f(gvu.x) * siluf(bfu2f(ggu.x));
  const float v1 = ov.y * bfu2f(gvu.y) * siluf(bfu2f(ggu.y));
  float s = v0 + v1;
  float s2 = fmaf(v1, v1, v0 * v0);
  float2 pr = make_float2(s, s2);
#pragma unroll
  for (int m = 1; m < 64; m <<= 1) { pr.x += __shfl_xor(pr.x, m); pr.y += __shfl_xor(pr.y, m); }
  if ((tid & 63) == 0) { red[(tid >> 6) * 2] = pr.x; red[(tid >> 6) * 2 + 1] = pr.y; }
  __syncthreads();
  const float S  = red[0] + red[2] + red[4] + red[6];
  const float S2 = red[1] + red[3] + red[5] + red[7];
  const float mu  = S * (1.f / 512.f);
  const float var = S2 * (1.f / 512.f) - mu * mu;
  const float rs  = rsqrtf(var + 1e-5f);
  const float2 lw = *(const float2*)(lnw + c0);
  const float2 lb = *(const float2*)(lnb + c0);
  __hip_bfloat16 o[2] = {
    __float2bfloat16(fmaf((v0 - mu) * rs, lw.x, lb.x)),
    __float2bfloat16(fmaf((v1 - mu) * rs, lw.y, lb.y)) };
  *(ushort2*)((unsigned short*)lno + (size_t)bl * 512 + c0) = *(ushort2*)o;
}

extern "C" void kernel_launch(void* const* d_in, const int* in_sizes, int n_in,
                              void* d_out, int out_size, void* d_ws, size_t ws_size,
                              hipStream_t stream)
{
  (void)in_sizes; (void)n_in; (void)out_size; (void)ws_size;
  const float* x    = (const float*)d_in[0];
  const float* st0  = (const float*)d_in[1];
  const float* Wq   = (const float*)d_in[2];
  const float* Wk   = (const float*)d_in[3];
  const float* Wv   = (const float*)d_in[4];
  const float* Wa   = (const float*)d_in[5];
  const float* Wb   = (const float*)d_in[6];
  const float* Wg   = (const float*)d_in[7];
  const float* Wo   = (const float*)d_in[8];
  const float* qcw  = (const float*)d_in[9];
  const float* qcb  = (const float*)d_in[10];
  const float* kcw  = (const float*)d_in[11];
  const float* kcb  = (const float*)d_in[12];
  const float* vcw  = (const float*)d_in[13];
  const float* vcb  = (const float*)d_in[14];
  const float* lnw  = (const float*)d_in[15];
  const float* lnb  = (const float*)d_in[16];
  float* out = (float*)d_out;

  // workspace layout (bytes); high-water ~141.2 MB
  char* ws = (char*)d_ws;
  __hip_bfloat16* XB   = (__hip_bfloat16*)(ws + 0);            // 4096x1024 bf16 (dead after proj GEMM)
  __hip_bfloat16* LNO  = (__hip_bfloat16*)(ws + 0);            // 4096x512 bf16 (aliases XB 1st half, written at gate_ln)
  short*          WTB  = (short*)(ws + 4194304);               // [256][64][128] bf16 (aliases XB 2nd half)
  __hip_bfloat16* WCAT = (__hip_bfloat16*)(ws + 8388608);      // 2688x1024 bf16
  __hip_bfloat16* WOB  = (__hip_bfloat16*)(ws + 13893632);     // 1024x512  bf16
  __hip_bfloat16* CBUFH = (__hip_bfloat16*)(ws + 14942208);    // 4096x2688 bf16
  __hip_bfloat16* QH   = (__hip_bfloat16*)(ws + 58982400);     // 4096x512 bf16
  __hip_bfloat16* KH   = (__hip_bfloat16*)(ws + 67371008);     // 4096x512 bf16
  __hip_bfloat16* VM   = (__hip_bfloat16*)(ws + 75759616);     // 4096x512 bf16
  __hip_bfloat16* VG   = (__hip_bfloat16*)(ws + 84148224);     // 4096x512 bf16
  float* AL   = (float*)(ws + 92536832);                       // 4096x4
  float* BE   = (float*)(ws + 92602368);
  float* OBUF = (float*)(ws + 92667904);                       // 4096x512 f32 (written by scan_output)
  short* TRB  = (short*)(ws + 92667904);                       // [256][128][128] bf16 (aliases OBUF; dead before scan_output)
  short* PHB  = (short*)(ws + 105250816);                      // [256][64][64] bf16
  short* ZB   = (short*)(ws + 107347968);                      // [256][64][128] bf16
  float* GV   = (float*)(ws + 111542272);                      // [256][64]
  short* SALL = (short*)(ws + 115868672);                      // [256][128][128] bf16 chunk-start states
  float* ABF  = (float*)(ws + 124257280);                      // [4096][8] f32 alpha/beta logits
  float* BF   = (float*)(ws + 124388352);                      // [256][128][128] f32 (fresh region; no aliasing)

  cast_f32_bf16_kernel<<<4096, 256, 0, stream>>>(x,  XB,  1048576);
  cast_f32_bf16_kernel<<<512,  256, 0, stream>>>(Wo, WOB, 131072);
  cast_wcat_kernel<<<2688, 256, 0, stream>>>(Wq, Wk, Wv, Wg, Wa, Wb, WCAT);

  gemm_bt_kernel<__hip_bfloat16><<<dim3(32, 21), 256, 0, stream>>>(
      XB, WCAT, CBUFH, BLQ, NPROJ, KPROJ, ABF, 2560);

  conv_act_kernel<<<512, 256, 0, stream>>>(CBUFH, ABF, qcw, qcb, kcw, kcb, vcw, vcb,
                                           QH, KH, VM, VG, AL, BE);

  scan_phaseA_kernel<<<256, 256, 0, stream>>>(QH, KH, VM, AL, BE,
                                              WTB, ZB, PHB, GV, TRB, BF);

  scan_state_kernel<<<64, 256, 0, stream>>>(TRB, BF, st0, SALL, out + 4194304);

  scan_output_kernel<<<256, 512, 0, stream>>>(QH, WTB, (const __hip_bfloat16*)ZB,
                                              PHB, GV, SALL, OBUF);

  gate_ln_kernel<<<BLQ, 256, 0, stream>>>(OBUF, VG, CBUFH, lnw, lnb, LNO);

  gemm_bt_kernel<float><<<dim3(32, 8), 256, 0, stream>>>(
      LNO, WOB, out, BLQ, DMQ, TOTQ, nullptr, 0);
}

// Round 10
// 143.526 us; speedup vs baseline: 2.2981x; 1.0550x over previous
//
#include <hip/hip_runtime.h>
#include <hip/hip_bf16.h>

// Problem constants
#define BQ    2
#define LQ    2048
#define DMQ   1024
#define HQ    4
#define DHQ   128
#define TOTQ  512
#define BLQ   4096      // B*L
#define NPROJ 2688      // padded concat: Wq(512) Wk(512) Wv(1024) Wg(512) Wa(4) Wb(4) pad(120)
#define KPROJ 1024
#define CT    64        // scan chunk length
#define NCH   32        // chunks (LQ/CT)

typedef short bf16x8 __attribute__((ext_vector_type(8)));
typedef short s16x4  __attribute__((ext_vector_type(4)));
typedef float f32x4  __attribute__((ext_vector_type(4)));

#define MFMA16(a, b, c) __builtin_amdgcn_mfma_f32_16x16x32_bf16(a, b, c, 0, 0, 0)

__device__ __forceinline__ float siluf(float x) { return x / (1.f + __expf(-x)); }
__device__ __forceinline__ float sigf(float x)  { return 1.f / (1.f + __expf(-x)); }
__device__ __forceinline__ short bf16s(float x) {
  return __builtin_bit_cast(short, __float2bfloat16(x));
}
__device__ __forceinline__ float bfu2f(unsigned short u) {
  return __bfloat162float(__builtin_bit_cast(__hip_bfloat16, u));
}
__device__ __forceinline__ bf16x8 pack8(f32x4 a, f32x4 b) {
  bf16x8 r;
  r[0] = bf16s(a.x); r[1] = bf16s(a.y); r[2] = bf16s(a.z); r[3] = bf16s(a.w);
  r[4] = bf16s(b.x); r[5] = bf16s(b.y); r[6] = bf16s(b.z); r[7] = bf16s(b.w);
  return r;
}

// global -> LDS direct load, 16B per lane. LDS dest must be wave-uniform base;
// HW writes base + lane*16.
__device__ __forceinline__ void gload_lds16(const void* g, void* l) {
  __builtin_amdgcn_global_load_lds(
      (__attribute__((address_space(1))) void*)(unsigned long long)g,
      (__attribute__((address_space(3))) void*)(unsigned int)(unsigned long long)l,
      16, 0, 0);
}

// ---------------- merged casts: x->XB, Wo->WOB, Wcat (one launch) ----------------
__global__ __launch_bounds__(256)
void cast_all_kernel(const float* __restrict__ x, const float* __restrict__ Wo,
                     const float* __restrict__ Wq, const float* __restrict__ Wk,
                     const float* __restrict__ Wv, const float* __restrict__ Wg,
                     const float* __restrict__ Wa, const float* __restrict__ Wb,
                     __hip_bfloat16* __restrict__ XB, __hip_bfloat16* __restrict__ WOB,
                     __hip_bfloat16* __restrict__ Wcat)
{
  const int bid = blockIdx.x;
  const int tid = threadIdx.x;
  if (bid < 4096) {                      // x: 4096x1024 f32, 4/thread
    const int i = bid * 256 + tid;
    float4 v = ((const float4*)x)[i];
    __hip_bfloat16 o[4] = { __float2bfloat16(v.x), __float2bfloat16(v.y),
                            __float2bfloat16(v.z), __float2bfloat16(v.w) };
    *(ushort4*)((unsigned short*)XB + (size_t)i * 4) = *(ushort4*)o;
  } else if (bid < 4608) {               // Wo: 1024x512 f32
    const int i = (bid - 4096) * 256 + tid;
    float4 v = ((const float4*)Wo)[i];
    __hip_bfloat16 o[4] = { __float2bfloat16(v.x), __float2bfloat16(v.y),
                            __float2bfloat16(v.z), __float2bfloat16(v.w) };
    *(ushort4*)((unsigned short*)WOB + (size_t)i * 4) = *(ushort4*)o;
  } else {                               // Wcat: 2688 rows x 1024
    const int i4 = (bid - 4608) * 256 + tid;
    const int row = i4 >> 8;
    const int col = (i4 & 255) * 4;
    const int idx = row * 1024 + col;
    float4 v;
    if      (row < 512)  v = *(const float4*)(Wq + idx);
    else if (row < 1024) v = *(const float4*)(Wk + idx - 512 * 1024);
    else if (row < 2048) v = *(const float4*)(Wv + idx - 1024 * 1024);
    else if (row < 2560) v = *(const float4*)(Wg + idx - 2048 * 1024);
    else if (row < 2564) v = *(const float4*)(Wa + (row - 2560) * 1024 + col);
    else if (row < 2568) v = *(const float4*)(Wb + (row - 2564) * 1024 + col);
    else                 v = make_float4(0.f, 0.f, 0.f, 0.f);
    __hip_bfloat16 o[4] = { __float2bfloat16(v.x), __float2bfloat16(v.y),
                            __float2bfloat16(v.z), __float2bfloat16(v.w) };
    *(ushort4*)((unsigned short*)Wcat + idx) = *(ushort4*)o;
  }
}

// ---------------- bf16 MFMA GEMM: C(TOUT, MxN) = A(M,K) * B(N,K)^T ----------------
// 2-phase double-buffered LDS. TOUT = __hip_bfloat16 (proj) or float (final).
// If aux != nullptr, output columns [auxc0, auxc0+8) are ALSO stored f32 to
// aux[row*8 + (col-auxc0)] (keeps alpha/beta logits full-precision).
template <typename TOUT>
__global__ __launch_bounds__(256)
void gemm_bt_kernel(const __hip_bfloat16* __restrict__ A,
                    const __hip_bfloat16* __restrict__ Bw,
                    TOUT* __restrict__ C, int M, int N, int K,
                    float* __restrict__ aux, int auxc0)
{
  __shared__ __hip_bfloat16 As[2 * 128 * 32];
  __shared__ __hip_bfloat16 Bs[2 * 128 * 32];
  const int tid  = threadIdx.x;
  const int lane = tid & 63;
  const int w    = tid >> 6;
  const int wm   = w >> 1, wn = w & 1;
  const int tm   = blockIdx.x, tn = blockIdx.y;
  const int lr   = lane & 15, lk = lane >> 4;

  f32x4 acc[4][4] = {};

  const int e0   = tid * 8;
  const int srow = e0 >> 5;        // 0..63
  const int scol = e0 & 31;
  const __hip_bfloat16* Ap = A  + (size_t)(tm * 128 + srow) * K + scol;
  const __hip_bfloat16* Bp = Bw + (size_t)(tn * 128 + srow) * K + scol;
  char* AsB  = (char*)As;
  char* BsB  = (char*)Bs;
  const size_t half = (size_t)64 * K;
  const int nk = K >> 5;

  // prologue: stage K-tile 0 into buffer 0
  {
    char* AsD = AsB + w * 1024;
    char* BsD = BsB + w * 1024;
    gload_lds16(Ap,        AsD);
    gload_lds16(Ap + half, AsD + 4096);
    gload_lds16(Bp,        BsD);
    gload_lds16(Bp + half, BsD + 4096);
  }
  __syncthreads();

  for (int it = 0; it < nk; ++it) {
    const int sel = it & 1;
    // prefetch next K-tile into the other buffer (no wait here)
    if (it + 1 < nk) {
      const int kk = (it + 1) * 32;
      char* AsD = AsB + ((sel ^ 1) * 8192) + w * 1024;
      char* BsD = BsB + ((sel ^ 1) * 8192) + w * 1024;
      gload_lds16(Ap + kk,        AsD);
      gload_lds16(Ap + half + kk, AsD + 4096);
      gload_lds16(Bp + kk,        BsD);
      gload_lds16(Bp + half + kk, BsD + 4096);
    }
    // compute on current buffer
    const char* AsR = AsB + sel * 8192;
    const char* BsR = BsB + sel * 8192;
    bf16x8 af[4], bfv[4];
#pragma unroll
    for (int m = 0; m < 4; ++m)
      af[m]  = *(const bf16x8*)(AsR + ((wm * 64 + m * 16 + lr) * 32 + lk * 8) * 2);
#pragma unroll
    for (int n = 0; n < 4; ++n)
      bfv[n] = *(const bf16x8*)(BsR + ((wn * 64 + n * 16 + lr) * 32 + lk * 8) * 2);
#pragma unroll
    for (int m = 0; m < 4; ++m)
#pragma unroll
      for (int n = 0; n < 4; ++n)
        acc[m][n] = MFMA16(af[m], bfv[n], acc[m][n]);
    // barrier (drains vmcnt): next tile resident, current buffer reusable
    __syncthreads();
  }

  const int crow0 = tm * 128 + wm * 64 + (lane >> 4) * 4;
  const int ccol0 = tn * 128 + wn * 64 + lr;
#pragma unroll
  for (int m = 0; m < 4; ++m)
#pragma unroll
    for (int n = 0; n < 4; ++n) {
      const int cc = ccol0 + n * 16;
#pragma unroll
      for (int j = 0; j < 4; ++j) {
        const float v = acc[m][n][j];
        const size_t row = (size_t)(crow0 + m * 16 + j);
        if constexpr (sizeof(TOUT) == 2)
          ((unsigned short*)C)[row * N + cc] = (unsigned short)bf16s(v);
        else
          C[row * N + cc] = v;
        if (aux && cc >= auxc0 && cc < auxc0 + 8)
          aux[row * 8 + (cc - auxc0)] = v;
      }
    }
}

// ---------------- conv(4-tap causal) + silu + l2norm + sigmoid(a,b) ----------------
// Sliding-window over 8 timesteps per block (512 blocks). CBUF is bf16;
// alpha/beta logits come from the f32 side buffer abf. Outputs bf16.
__global__ __launch_bounds__(256)
void conv_act_kernel(const __hip_bfloat16* __restrict__ C, const float* __restrict__ abf,
                     const float* __restrict__ qcw, const float* __restrict__ qcb,
                     const float* __restrict__ kcw, const float* __restrict__ kcb,
                     const float* __restrict__ vcw, const float* __restrict__ vcb,
                     __hip_bfloat16* __restrict__ qh, __hip_bfloat16* __restrict__ kh,
                     __hip_bfloat16* __restrict__ vm, __hip_bfloat16* __restrict__ vg,
                     float* __restrict__ al, float* __restrict__ be)
{
  const int blk = blockIdx.x;           // 512
  const int bl0 = blk * 8;              // global row start (never crosses b: 2048%8==0)
  const int t0  = bl0 & (LQ - 1);       // local t start
  const int tid = threadIdx.x;
  const unsigned short* Cu = (const unsigned short*)C;
  __shared__ float red[4][16];

  float2 qv[8], kv[8];
  float sq[8], sk[8];
#pragma unroll
  for (int t = 0; t < 8; ++t) { sq[t] = 0.f; sk[t] = 0.f; }

  {
    const int c0 = tid * 2;
    const float4 wqA = *(const float4*)(qcw + 4 * c0);
    const float4 wqB = *(const float4*)(qcw + 4 * c0 + 4);
    const float4 wkA = *(const float4*)(kcw + 4 * c0);
    const float4 wkB = *(const float4*)(kcw + 4 * c0 + 4);
    const float2 bq = *(const float2*)(qcb + c0);
    const float2 bk = *(const float2*)(kcb + c0);
    float2 wrq[11], wrk[11];
#pragma unroll
    for (int r = 0; r < 11; ++r) {
      const int tt = t0 - 3 + r;
      if (tt >= 0) {
        const unsigned short* Cr = Cu + (size_t)(bl0 - 3 + r) * NPROJ;
        const ushort2 aq = *(const ushort2*)(Cr + c0);
        const ushort2 ak = *(const ushort2*)(Cr + 512 + c0);
        wrq[r] = make_float2(bfu2f(aq.x), bfu2f(aq.y));
        wrk[r] = make_float2(bfu2f(ak.x), bfu2f(ak.y));
      } else {
        wrq[r] = make_float2(0.f, 0.f);
        wrk[r] = make_float2(0.f, 0.f);
      }
    }
#pragma unroll
    for (int t = 0; t < 8; ++t) {
      float aq0 = bq.x, aq1 = bq.y, ak0 = bk.x, ak1 = bk.y;
#pragma unroll
      for (int j = 0; j < 4; ++j) {
        aq0 = fmaf(((const float*)&wqA)[j], wrq[t + j].x, aq0);
        aq1 = fmaf(((const float*)&wqB)[j], wrq[t + j].y, aq1);
        ak0 = fmaf(((const float*)&wkA)[j], wrk[t + j].x, ak0);
        ak1 = fmaf(((const float*)&wkB)[j], wrk[t + j].y, ak1);
      }
      const float q0 = siluf(aq0), q1 = siluf(aq1);
      const float k0 = siluf(ak0), k1 = siluf(ak1);
      qv[t] = make_float2(q0, q1);
      kv[t] = make_float2(k0, k1);
      sq[t] = fmaf(q1, q1, fmaf(q0, q0, sq[t]));
      sk[t] = fmaf(k1, k1, fmaf(k0, k0, sk[t]));
    }
  }
  // reduce sq,sk across 64 lanes, then across 4 waves
#pragma unroll
  for (int m = 1; m < 64; m <<= 1) {
#pragma unroll
    for (int t = 0; t < 8; ++t) {
      sq[t] += __shfl_xor(sq[t], m);
      sk[t] += __shfl_xor(sk[t], m);
    }
  }
  {
    const int w = tid >> 6, lane = tid & 63;
    if (lane == 0) {
#pragma unroll
      for (int t = 0; t < 8; ++t) { red[w][t] = sq[t]; red[w][8 + t] = sk[t]; }
    }
  }
  __syncthreads();
  float rnq[8], rnk[8];
#pragma unroll
  for (int t = 0; t < 8; ++t) {
    const float SQ = red[0][t] + red[1][t] + red[2][t] + red[3][t];
    const float SK = red[0][8 + t] + red[1][8 + t] + red[2][8 + t] + red[3][8 + t];
    rnq[t] = 1.f / fmaxf(sqrtf(SQ), 1e-12f);
    rnk[t] = 1.f / fmaxf(sqrtf(SK), 1e-12f);
  }
  {
    const int c0 = tid * 2;
#pragma unroll
    for (int t = 0; t < 8; ++t) {
      ushort2 oq, ok;
      oq.x = (unsigned short)bf16s(qv[t].x * rnq[t]);
      oq.y = (unsigned short)bf16s(qv[t].y * rnq[t]);
      ok.x = (unsigned short)bf16s(kv[t].x * rnk[t]);
      ok.y = (unsigned short)bf16s(kv[t].y * rnk[t]);
      *(ushort2*)((unsigned short*)qh + (size_t)(bl0 + t) * 512 + c0) = oq;
      *(ushort2*)((unsigned short*)kh + (size_t)(bl0 + t) * 512 + c0) = ok;
    }
  }
  // v: 4 consecutive channels per thread
  {
    const int cv = tid * 4;   // 0..1023
    const float4 wv0 = *(const float4*)(vcw + 4 * cv);
    const float4 wv1 = *(const float4*)(vcw + 4 * cv + 4);
    const float4 wv2 = *(const float4*)(vcw + 4 * cv + 8);
    const float4 wv3 = *(const float4*)(vcw + 4 * cv + 12);
    const float4 bv4 = *(const float4*)(vcb + cv);
    float4 wr[11];
#pragma unroll
    for (int r = 0; r < 11; ++r) {
      const int tt = t0 - 3 + r;
      if (tt >= 0) {
        const ushort4 u = *(const ushort4*)(Cu + (size_t)(bl0 - 3 + r) * NPROJ + 1024 + cv);
        wr[r] = make_float4(bfu2f(u.x), bfu2f(u.y), bfu2f(u.z), bfu2f(u.w));
      } else {
        wr[r] = make_float4(0.f, 0.f, 0.f, 0.f);
      }
    }
#pragma unroll
    for (int t = 0; t < 8; ++t) {
      float a0 = bv4.x, a1 = bv4.y, a2 = bv4.z, a3 = bv4.w;
#pragma unroll
      for (int j = 0; j < 4; ++j) {
        a0 = fmaf(((const float*)&wv0)[j], ((const float*)&wr[t + j])[0], a0);
        a1 = fmaf(((const float*)&wv1)[j], ((const float*)&wr[t + j])[1], a1);
        a2 = fmaf(((const float*)&wv2)[j], ((const float*)&wr[t + j])[2], a2);
        a3 = fmaf(((const float*)&wv3)[j], ((const float*)&wr[t + j])[3], a3);
      }
      ushort4 o;
      o.x = (unsigned short)bf16s(siluf(a0));
      o.y = (unsigned short)bf16s(siluf(a1));
      o.z = (unsigned short)bf16s(siluf(a2));
      o.w = (unsigned short)bf16s(siluf(a3));
      if (cv < 512) *(ushort4*)((unsigned short*)vm + (size_t)(bl0 + t) * 512 + cv)         = o;
      else          *(ushort4*)((unsigned short*)vg + (size_t)(bl0 + t) * 512 + (cv - 512)) = o;
    }
  }
  // alpha/beta from f32 side buffer: threads 0..63 cover 8 t x (4 al + 4 be)
  if (tid < 64) {
    const int t = tid >> 3;
    const int k = tid & 7;
    const float v = abf[(size_t)(bl0 + t) * 8 + k];
    if (k < 4) al[(size_t)(bl0 + t) * 4 + k]       = sigf(v);
    else       be[(size_t)(bl0 + t) * 4 + (k - 4)] = sigf(v);
  }
}

// ---------------- scan phase A (FUSED with transition), 512 threads ----------------
// 256 blocks = 32 chunks x 8 (b,h); 8 waves (2 waves/SIMD vs old 1).
// Work split: G/Pq MFMA over 8 waves (t-band x s-half); substitution with TWO
// threads per column (A: rows 0-7 of each 16-block, B: rows 8-15, barrier
// handoff through the Xl spill); transition over 8 waves (row-band x col-qtr).
__global__ __launch_bounds__(512)
void scan_phaseA_kernel(const __hip_bfloat16* __restrict__ qh, const __hip_bfloat16* __restrict__ kh,
                        const __hip_bfloat16* __restrict__ vm, const float* __restrict__ al,
                        const float* __restrict__ be,
                        short* __restrict__ WTB, short* __restrict__ ZB,
                        short* __restrict__ PHB, float* __restrict__ GV,
                        short* __restrict__ TRB, float* __restrict__ BF)
{
  __shared__ char sm[136192];
  float* Xl = (float*)(sm);                             // [64][256] f32 (aliases KBl/QBl)
  __hip_bfloat16* KBl = (__hip_bfloat16*)(sm);          // [64][136]
  __hip_bfloat16* QBl = (__hip_bfloat16*)(sm + 17408);  // [64][136]
  float* Ll  = (float*)(sm + 65536);                    // [64][68]
  float* dv  = (float*)(sm + 82944);                    // [64]
  float* bv  = (float*)(sm + 83200);                    // [64]
  float* gbv = (float*)(sm + 83456);                    // [64]
  float* fvs = (float*)(sm + 83712);                    // [64]
  short* KTl  = (short*)(sm + 83968);                   // [128][68] bf16
  short* WTFl = (short*)(sm + 101376);                  // [128][68] bf16
  short* ZFl  = (short*)(sm + 118784);                  // [128][68] bf16

  const int cb = blockIdx.x;
  const int bh = cb & 7, c = cb >> 3;
  const int b = bh >> 2, h = bh & 3;
  const int tid = threadIdx.x;          // 0..511
  const int lane = tid & 63;
  const int w = tid >> 6;               // 0..7
  const int lr = lane & 15, lk = lane >> 4;
  const size_t rowbase = (size_t)(b * LQ + c * CT) * 512 + h * 128;

  // stage K,Q -> LDS bf16 (padded rows of 136); 2 reps of 512 threads
#pragma unroll
  for (int rep = 0; rep < 2; ++rep) {
    const int fid = tid + rep * 512;       // 0..1023
    const int r = fid >> 4;
    const int cg = (fid & 15) * 8;
    *(bf16x8*)(KBl + r * 136 + cg) = *(const bf16x8*)(kh + rowbase + (size_t)r * 512 + cg);
    *(bf16x8*)(QBl + r * 136 + cg) = *(const bf16x8*)(qh + rowbase + (size_t)r * 512 + cg);
  }
  // decay prefix (wave 0)
  if (w == 0) {
    float la = __logf(al[(size_t)(b * LQ + c * CT + lane) * 4 + h]);
    const float bb = be[(size_t)(b * LQ + c * CT + lane) * 4 + h];
#pragma unroll
    for (int off = 1; off < 64; off <<= 1) {
      const float tv = __shfl_up(la, off, 64);
      if (lane >= off) la += tv;
    }
    dv[lane] = la; bv[lane] = bb; gbv[lane] = bb * __expf(la);
    const float d63 = __shfl(la, 63, 64);
    fvs[lane] = __expf(d63 - la);
    GV[cb * 64 + lane] = __expf(la);
  }
  __syncthreads();

  // G = K K^T, Pq = Q K^T : wave w owns t-band (w&3) and s-half (w>>2)
  {
    const int tb = (w & 3) * 16;
    const int sh = (w >> 2) * 2;          // s-tile base (2 tiles per wave)
    f32x4 aG[2] = {}, aP[2] = {};
#pragma unroll
    for (int ks = 0; ks < 4; ++ks) {
      bf16x8 bk[2];
#pragma unroll
      for (int nt = 0; nt < 2; ++nt)
        bk[nt] = *(const bf16x8*)(KBl + ((sh + nt) * 16 + lr) * 136 + ks * 32 + lk * 8);
      const bf16x8 ak = *(const bf16x8*)(KBl + (tb + lr) * 136 + ks * 32 + lk * 8);
      const bf16x8 aq = *(const bf16x8*)(QBl + (tb + lr) * 136 + ks * 32 + lk * 8);
#pragma unroll
      for (int nt = 0; nt < 2; ++nt) {
        aG[nt] = MFMA16(ak, bk[nt], aG[nt]);
        aP[nt] = MFMA16(aq, bk[nt], aP[nt]);
      }
    }
#pragma unroll
    for (int nt = 0; nt < 2; ++nt)
#pragma unroll
      for (int jj = 0; jj < 4; ++jj) {
        const int t = tb + lk * 4 + jj;
        const int s = (sh + nt) * 16 + lr;
        const float eg = __expf(dv[t] - dv[s]);
        Ll[t * 68 + s] = (t > s) ? bv[t] * eg * aG[nt][jj] : 0.f;
        PHB[(size_t)cb * 4096 + t * 64 + s] = (s <= t) ? bf16s(eg * aP[nt][jj]) : (short)0;
      }
  }
  // KT (LDS) = K^T from staged KBl, BEFORE Xl overwrites it
  if (tid < 128) {
    const short* Kbs = (const short*)KBl;
#pragma unroll
    for (int s4 = 0; s4 < 16; ++s4) {
      s16x4 pk;
#pragma unroll
      for (int e = 0; e < 4; ++e)
        pk[e] = Kbs[(s4 * 4 + e) * 136 + tid];
      *(s16x4*)(KTl + tid * 68 + s4 * 4) = pk;
    }
  }
  __syncthreads();   // KBl/QBl dead from here -> Xl may overwrite

  // ---- blocked forward substitution: 2 threads per column ----
  // thread (j, half): half 0 -> rows 0-7 of each 16-block; half 1 -> rows 8-15.
  const int j = tid & 255;
  const int half = tid >> 8;
  const int i0 = half * 8;
  const __hip_bfloat16* src = (j < 128) ? kh : vm;
  const __hip_bfloat16* xp = src + rowbase + (j & 127);
  float* XlC = Xl + j;                 // private column, stride 256 floats
  short* dstN = (j < 128) ? (WTB + (size_t)cb * 8192 + j)
                          : (ZB  + (size_t)cb * 8192 + (j - 128));
  short* dstT = (j < 128) ? (WTFl + j * 68)
                          : (ZFl  + (j - 128) * 68);

  for (int r = 0; r < 4; ++r) {
    float u[8];
    // RHS half-block (scaled)
#pragma unroll
    for (int i = 0; i < 8; ++i) {
      const int t = r * 16 + i0 + i;
      u[i] = __bfloat162float(xp[(size_t)t * 512]) * ((j < 128) ? gbv[t] : bv[t]);
    }
    // cross-block updates from already-solved 16-blocks (both halves concurrently)
    for (int sc = 0; sc < r; ++sc) {
      float xs[16];
#pragma unroll
      for (int k = 0; k < 16; ++k) xs[k] = XlC[(sc * 16 + k) * 256];
#pragma unroll
      for (int i = 0; i < 8; ++i) {
        const float* lrow = Ll + (r * 16 + i0 + i) * 68 + sc * 16;
        const f32x4 l0 = *(const f32x4*)(lrow);
        const f32x4 l1 = *(const f32x4*)(lrow + 4);
        const f32x4 l2 = *(const f32x4*)(lrow + 8);
        const f32x4 l3 = *(const f32x4*)(lrow + 12);
        f32x4 acc = {};
        acc.x = fmaf(l0.x, xs[0],  acc.x); acc.y = fmaf(l0.y, xs[1],  acc.y);
        acc.z = fmaf(l0.z, xs[2],  acc.z); acc.w = fmaf(l0.w, xs[3],  acc.w);
        acc.x = fmaf(l1.x, xs[4],  acc.x); acc.y = fmaf(l1.y, xs[5],  acc.y);
        acc.z = fmaf(l1.z, xs[6],  acc.z); acc.w = fmaf(l1.w, xs[7],  acc.w);
        acc.x = fmaf(l2.x, xs[8],  acc.x); acc.y = fmaf(l2.y, xs[9],  acc.y);
        acc.z = fmaf(l2.z, xs[10], acc.z); acc.w = fmaf(l2.w, xs[11], acc.w);
        acc.x = fmaf(l3.x, xs[12], acc.x); acc.y = fmaf(l3.y, xs[13], acc.y);
        acc.z = fmaf(l3.z, xs[14], acc.z); acc.w = fmaf(l3.w, xs[15], acc.w);
        u[i] -= (acc.x + acc.y) + (acc.z + acc.w);
      }
    }
    if (half == 0) {
      // in-block solve rows 0..7 (zeros above diagonal make group guard safe)
#pragma unroll
      for (int i = 1; i < 8; ++i) {
        const float* lrow = Ll + (r * 16 + i) * 68 + r * 16;
        f32x4 acc = {};
#pragma unroll
        for (int k4 = 0; k4 < 2; ++k4) {
          if (k4 * 4 < i) {
            const f32x4 lv = *(const f32x4*)(lrow + k4 * 4);
            acc.x = fmaf(lv.x, u[k4 * 4 + 0], acc.x);
            acc.y = fmaf(lv.y, u[k4 * 4 + 1], acc.y);
            acc.z = fmaf(lv.z, u[k4 * 4 + 2], acc.z);
            acc.w = fmaf(lv.w, u[k4 * 4 + 3], acc.w);
          }
        }
        u[i] -= (acc.x + acc.y) + (acc.z + acc.w);
      }
      // spill + stores for rows r*16 .. r*16+7
#pragma unroll
      for (int i = 0; i < 8; ++i) XlC[(r * 16 + i) * 256] = u[i];
#pragma unroll
      for (int i = 0; i < 8; ++i) dstN[(r * 16 + i) * 128] = bf16s(u[i]);
#pragma unroll
      for (int s4 = 0; s4 < 2; ++s4) {
        s16x4 p;
#pragma unroll
        for (int e = 0; e < 4; ++e)
          p[e] = bf16s(fvs[r * 16 + s4 * 4 + e] * u[s4 * 4 + e]);
        *(s16x4*)(dstT + r * 16 + s4 * 4) = p;
      }
    }
    __syncthreads();   // A-half spill visible
    if (half == 1) {
      // coupling from A-half (8x8 block, all L entries valid: k < 8 <= row)
      float xa[8];
#pragma unroll
      for (int k = 0; k < 8; ++k) xa[k] = XlC[(r * 16 + k) * 256];
#pragma unroll
      for (int i = 0; i < 8; ++i) {
        const float* lrow = Ll + (r * 16 + 8 + i) * 68 + r * 16;
        const f32x4 l0 = *(const f32x4*)(lrow);
        const f32x4 l1 = *(const f32x4*)(lrow + 4);
        f32x4 acc = {};
        acc.x = fmaf(l0.x, xa[0], acc.x); acc.y = fmaf(l0.y, xa[1], acc.y);
        acc.z = fmaf(l0.z, xa[2], acc.z); acc.w = fmaf(l0.w, xa[3], acc.w);
        acc.x = fmaf(l1.x, xa[4], acc.x); acc.y = fmaf(l1.y, xa[5], acc.y);
        acc.z = fmaf(l1.z, xa[6], acc.z); acc.w = fmaf(l1.w, xa[7], acc.w);
        u[i] -= (acc.x + acc.y) + (acc.z + acc.w);
      }
      // in-block solve rows 8..15 among themselves
#pragma unroll
      for (int i = 1; i < 8; ++i) {
        const float* lrow = Ll + (r * 16 + 8 + i) * 68 + r * 16 + 8;
        f32x4 acc = {};
#pragma unroll
        for (int k4 = 0; k4 < 2; ++k4) {
          if (k4 * 4 < i) {
            const f32x4 lv = *(const f32x4*)(lrow + k4 * 4);
            acc.x = fmaf(lv.x, u[k4 * 4 + 0], acc.x);
            acc.y = fmaf(lv.y, u[k4 * 4 + 1], acc.y);
            acc.z = fmaf(lv.z, u[k4 * 4 + 2], acc.z);
            acc.w = fmaf(lv.w, u[k4 * 4 + 3], acc.w);
          }
        }
        u[i] -= (acc.x + acc.y) + (acc.z + acc.w);
      }
      // spill + stores for rows r*16+8 .. r*16+15
#pragma unroll
      for (int i = 0; i < 8; ++i) XlC[(r * 16 + 8 + i) * 256] = u[i];
#pragma unroll
      for (int i = 0; i < 8; ++i) dstN[(r * 16 + 8 + i) * 128] = bf16s(u[i]);
#pragma unroll
      for (int s4 = 0; s4 < 2; ++s4) {
        s16x4 p;
#pragma unroll
        for (int e = 0; e < 4; ++e)
          p[e] = bf16s(fvs[r * 16 + 8 + s4 * 4 + e] * u[s4 * 4 + e]);
        *(s16x4*)(dstT + r * 16 + 8 + s4 * 4) = p;
      }
    }
    __syncthreads();   // block r fully solved
  }

  // ---- fused transition: 8 waves, wave w owns row-band (w&3) x col-quarter (w>>2)
  const float gc = __expf(dv[63]);
  const int rb = (w & 3) * 32;
  const int cq = (w >> 2) * 4;
  {
    f32x4 acc[2][4] = {};
#pragma unroll
    for (int ks = 0; ks < 2; ++ks) {
      const bf16x8 a0 = *(const bf16x8*)(KTl + (rb + lr) * 68 + ks * 32 + lk * 8);
      const bf16x8 a1 = *(const bf16x8*)(KTl + (rb + 16 + lr) * 68 + ks * 32 + lk * 8);
#pragma unroll
      for (int nt = 0; nt < 4; ++nt) {
        const bf16x8 bm = *(const bf16x8*)(WTFl + ((cq + nt) * 16 + lr) * 68 + ks * 32 + lk * 8);
        acc[0][nt] = MFMA16(a0, bm, acc[0][nt]);
        acc[1][nt] = MFMA16(a1, bm, acc[1][nt]);
      }
    }
#pragma unroll
    for (int mt = 0; mt < 2; ++mt)
#pragma unroll
      for (int nt = 0; nt < 4; ++nt)
#pragma unroll
        for (int jj = 0; jj < 4; ++jj) {
          const int jr = rb + mt * 16 + lk * 4 + jj;
          const int m  = (cq + nt) * 16 + lr;
          const float v = ((jr == m) ? gc : 0.f) - acc[mt][nt][jj];
          TRB[(size_t)cb * 16384 + jr * 128 + m] = bf16s(v);
        }
  }
  {
    f32x4 acc[2][4] = {};
#pragma unroll
    for (int ks = 0; ks < 2; ++ks) {
      const bf16x8 a0 = *(const bf16x8*)(ZFl + (rb + lr) * 68 + ks * 32 + lk * 8);
      const bf16x8 a1 = *(const bf16x8*)(ZFl + (rb + 16 + lr) * 68 + ks * 32 + lk * 8);
#pragma unroll
      for (int nt = 0; nt < 4; ++nt) {
        const bf16x8 bj = *(const bf16x8*)(KTl + ((cq + nt) * 16 + lr) * 68 + ks * 32 + lk * 8);
        acc[0][nt] = MFMA16(a0, bj, acc[0][nt]);
        acc[1][nt] = MFMA16(a1, bj, acc[1][nt]);
      }
    }
#pragma unroll
    for (int mt = 0; mt < 2; ++mt)
#pragma unroll
      for (int nt = 0; nt < 4; ++nt)
#pragma unroll
        for (int jj = 0; jj < 4; ++jj) {
          const int ir = rb + mt * 16 + lk * 4 + jj;
          const int jc = (cq + nt) * 16 + lr;
          BF[(size_t)cb * 16384 + ir * 128 + jc] = acc[mt][nt][jj];
        }
  }
}

// ---------------- scan state: serial chunk recurrence, S rows independent ----
#define L2_PREFETCH(BT, BA, CC) do {                                               \
  const int cbn_ = (CC) * 8 + bh;                                                  \
  _Pragma("unroll") for (int nt = 0; nt < 2; ++nt) {                               \
    _Pragma("unroll") for (int ks = 0; ks < 4; ++ks)                               \
      BT[nt][ks] = *(const bf16x8*)(TRB + (size_t)cbn_ * 16384 +                   \
                                    (w * 32 + nt * 16 + lr) * 128 + ks * 32 + lk * 8); \
    _Pragma("unroll") for (int jj = 0; jj < 4; ++jj)                               \
      BA[nt][jj] = BF[(size_t)cbn_ * 16384 + (r0 + lk * 4 + jj) * 128 +            \
                      w * 32 + nt * 16 + lr];                                      \
  }                                                                                \
} while (0)

#define L2_STEP(BT, BA, CC, PBT, PBA) do {                                         \
  const int cb_ = (CC) * 8 + bh;                                                   \
  { const int idx = tid * 8, r = idx >> 7, jc = idx & 127;                         \
    f32x4 s0 = *(const f32x4*)&Scur[r * 132 + jc];                                 \
    f32x4 s1 = *(const f32x4*)&Scur[r * 132 + jc + 4];                             \
    *(bf16x8*)(SALL + (size_t)cb_ * 16384 + (r0 + r) * 128 + jc) = pack8(s0, s1); }\
  bf16x8 af[4];                                                                    \
  _Pragma("unroll") for (int ks = 0; ks < 4; ++ks)                                 \
    af[ks] = pack8(*(const f32x4*)&Scur[lr * 132 + ks * 32 + lk * 8],              \
                   *(const f32x4*)&Scur[lr * 132 + ks * 32 + lk * 8 + 4]);         \
  if ((CC) < 31) L2_PREFETCH(PBT, PBA, (CC) + 1);                                  \
  f32x4 acc0 = {}, acc1 = {};                                                      \
  _Pragma("unroll") for (int ks = 0; ks < 4; ++ks) {                               \
    acc0 = MFMA16(af[ks], BT[0][ks], acc0);                                        \
    acc1 = MFMA16(af[ks], BT[1][ks], acc1);                                        \
  }                                                                                \
  _Pragma("unroll") for (int jj = 0; jj < 4; ++jj) {                               \
    Snxt[(lk * 4 + jj) * 132 + w * 32 + lr]      = acc0[jj] + BA[0][jj];           \
    Snxt[(lk * 4 + jj) * 132 + w * 32 + 16 + lr] = acc1[jj] + BA[1][jj];           \
  }                                                                                \
  __syncthreads();                                                                 \
  { float* t_ = Scur; Scur = Snxt; Snxt = t_; }                                    \
} while (0)

__global__ __launch_bounds__(256)
void scan_state_kernel(const short* __restrict__ TRB, const float* __restrict__ BF,
                       const float* __restrict__ st0, short* __restrict__ SALL,
                       float* __restrict__ stout)
{
  __shared__ float Sl[2 * 16 * 132];
  const int bid = blockIdx.x;            // 64
  const int bh = bid & 7, slab = bid >> 3;
  const int r0 = slab * 16;
  const int tid = threadIdx.x, lane = tid & 63, w = tid >> 6;
  const int lr = lane & 15, lk = lane >> 4;

  float* Scur = Sl;
  float* Snxt = Sl + 16 * 132;

  // load st0 slab
  {
    const int idx = tid * 8, r = idx >> 7, jc = idx & 127;
    const float* sp = st0 + ((size_t)bh * 128 + r0 + r) * 128 + jc;
    *(f32x4*)&Scur[r * 132 + jc]     = *(const f32x4*)sp;
    *(f32x4*)&Scur[r * 132 + jc + 4] = *(const f32x4*)(sp + 4);
  }
  bf16x8 btA[2][4], btB[2][4];
  float  baA[2][4], baB[2][4];
  L2_PREFETCH(btA, baA, 0);
  __syncthreads();

  for (int c2 = 0; c2 < 16; ++c2) {
    L2_STEP(btA, baA, 2 * c2,     btB, baB);
    L2_STEP(btB, baB, 2 * c2 + 1, btA, baA);
  }

  // final state (Scur holds S_32 after 32 swaps)
  {
    const int idx = tid * 8, r = idx >> 7, jc = idx & 127;
    float* sp = stout + ((size_t)bh * 128 + r0 + r) * 128 + jc;
    *(f32x4*)sp       = *(const f32x4*)&Scur[r * 132 + jc];
    *(f32x4*)(sp + 4) = *(const f32x4*)&Scur[r * 132 + jc + 4];
  }
}

// ---------------- scan output: fully parallel over chunks ----------------
// Output obuf is bf16 now.
__global__ __launch_bounds__(512)
void scan_output_kernel(const __hip_bfloat16* __restrict__ qh,
                        const short* __restrict__ WTB, const __hip_bfloat16* __restrict__ ZB,
                        const short* __restrict__ PHB, const float* __restrict__ GV,
                        const short* __restrict__ SALL, __hip_bfloat16* __restrict__ obuf)
{
  __shared__ short Ut[128 * 72];
  const int cb = blockIdx.x;
  const int bh = cb & 7, c = cb >> 3;
  const int b = bh >> 2, h = bh & 3;
  const int tid = threadIdx.x, lane = tid & 63, w = tid >> 6;   // w 0..7
  const int lr = lane & 15, lk = lane >> 4;
  const int r0 = (w & 3) * 16;

  f32x4 Y[8] = {};
#pragma unroll
  for (int ks = 0; ks < 4; ++ks) {
    bf16x8 af;
    if (w < 4) {
      af = *(const bf16x8*)(qh + ((size_t)(b * LQ + c * CT) + r0 + lr) * 512 + h * 128 + ks * 32 + lk * 8);
    } else {
      af = *(const bf16x8*)(WTB + (size_t)cb * 8192 + (r0 + lr) * 128 + ks * 32 + lk * 8);
    }
#pragma unroll
    for (int nt = 0; nt < 8; ++nt) {
      const bf16x8 bs = *(const bf16x8*)(SALL + (size_t)cb * 16384 + (nt * 16 + lr) * 128 + ks * 32 + lk * 8);
      Y[nt] = MFMA16(af, bs, Y[nt]);
    }
  }
  if (w >= 4) {   // U = Z - Y_low -> LDS (Ut[i][s])
#pragma unroll
    for (int nt = 0; nt < 8; ++nt) {
      const int i = nt * 16 + lr;
      s16x4 up;
#pragma unroll
      for (int jj = 0; jj < 4; ++jj) {
        const int s = r0 + lk * 4 + jj;
        const float z = __bfloat162float(ZB[(size_t)cb * 8192 + s * 128 + i]);
        up[jj] = bf16s(z - Y[nt][jj]);
      }
      *(s16x4*)&Ut[i * 72 + r0 + lk * 4] = up;
    }
  }
  __syncthreads();
  if (w < 4) {
    f32x4 P2[8] = {};
#pragma unroll
    for (int ks = 0; ks < 2; ++ks) {
      const bf16x8 ap = *(const bf16x8*)(PHB + (size_t)cb * 4096 + (r0 + lr) * 64 + ks * 32 + lk * 8);
#pragma unroll
      for (int nt = 0; nt < 8; ++nt) {
        const bf16x8 bu = *(const bf16x8*)&Ut[(nt * 16 + lr) * 72 + ks * 32 + lk * 8];
        P2[nt] = MFMA16(ap, bu, P2[nt]);
      }
    }
    float gvv[4];
#pragma unroll
    for (int jj = 0; jj < 4; ++jj) gvv[jj] = GV[cb * 64 + r0 + lk * 4 + jj];
#pragma unroll
    for (int nt = 0; nt < 8; ++nt) {
      const int i = nt * 16 + lr;
#pragma unroll
      for (int jj = 0; jj < 4; ++jj) {
        const int t = r0 + lk * 4 + jj;
        ((unsigned short*)obuf)[((size_t)(b * LQ + c * CT) + t) * 512 + h * 128 + i] =
            (unsigned short)bf16s(gvv[jj] * Y[nt][jj] + P2[nt][jj]);
      }
    }
  }
}

// ---------------- gate * silu(g), LayerNorm(512), cast bf16 ----------------
__global__ __launch_bounds__(256)
void gate_ln_kernel(const __hip_bfloat16* __restrict__ obuf, const __hip_bfloat16* __restrict__ vg,
                    const __hip_bfloat16* __restrict__ C, const float* __restrict__ lnw,
                    const float* __restrict__ lnb, __hip_bfloat16* __restrict__ lno)
{
  const int bl = blockIdx.x, tid = threadIdx.x;
  const int c0 = tid * 2;
  __shared__ float red[8];
  const ushort2 ovu = *(const ushort2*)((const unsigned short*)obuf + (size_t)bl * 512 + c0);
  const ushort2 gvu = *(const ushort2*)((const unsigned short*)vg + (size_t)bl * 512 + c0);
  const ushort2 ggu = *(const ushort2*)((const unsigned short*)C + (size_t)bl * NPROJ + 2048 + c0);
  const float v0 = bfu2f(ovu.x) * bfu2f(gvu.x) * siluf(bfu2f(ggu.x));
  const float v1 = bfu2f(ovu.y) * bfu2f(gvu.y) * siluf(bfu2f(ggu.y));
  float s = v0 + v1;
  float s2 = fmaf(v1, v1, v0 * v0);
  float2 pr = make_float2(s, s2);
#pragma unroll
  for (int m = 1; m < 64; m <<= 1) { pr.x += __shfl_xor(pr.x, m); pr.y += __shfl_xor(pr.y, m); }
  if ((tid & 63) == 0) { red[(tid >> 6) * 2] = pr.x; red[(tid >> 6) * 2 + 1] = pr.y; }
  __syncthreads();
  const float S  = red[0] + red[2] + red[4] + red[6];
  const float S2 = red[1] + red[3] + red[5] + red[7];
  const float mu  = S * (1.f / 512.f);
  const float var = S2 * (1.f / 512.f) - mu * mu;
  const float rs  = rsqrtf(var + 1e-5f);
  const float2 lw = *(const float2*)(lnw + c0);
  const float2 lb = *(const float2*)(lnb + c0);
  __hip_bfloat16 o[2] = {
    __float2bfloat16(fmaf((v0 - mu) * rs, lw.x, lb.x)),
    __float2bfloat16(fmaf((v1 - mu) * rs, lw.y, lb.y)) };
  *(ushort2*)((unsigned short*)lno + (size_t)bl * 512 + c0) = *(ushort2*)o;
}

extern "C" void kernel_launch(void* const* d_in, const int* in_sizes, int n_in,
                              void* d_out, int out_size, void* d_ws, size_t ws_size,
                              hipStream_t stream)
{
  (void)in_sizes; (void)n_in; (void)out_size; (void)ws_size;
  const float* x    = (const float*)d_in[0];
  const float* st0  = (const float*)d_in[1];
  const float* Wq   = (const float*)d_in[2];
  const float* Wk   = (const float*)d_in[3];
  const float* Wv   = (const float*)d_in[4];
  const float* Wa   = (const float*)d_in[5];
  const float* Wb   = (const float*)d_in[6];
  const float* Wg   = (const float*)d_in[7];
  const float* Wo   = (const float*)d_in[8];
  const float* qcw  = (const float*)d_in[9];
  const float* qcb  = (const float*)d_in[10];
  const float* kcw  = (const float*)d_in[11];
  const float* kcb  = (const float*)d_in[12];
  const float* vcw  = (const float*)d_in[13];
  const float* vcb  = (const float*)d_in[14];
  const float* lnw  = (const float*)d_in[15];
  const float* lnb  = (const float*)d_in[16];
  float* out = (float*)d_out;

  // workspace layout (bytes); high-water ~141.2 MB
  char* ws = (char*)d_ws;
  __hip_bfloat16* XB   = (__hip_bfloat16*)(ws + 0);            // 4096x1024 bf16 (dead after proj GEMM)
  __hip_bfloat16* LNO  = (__hip_bfloat16*)(ws + 0);            // 4096x512 bf16 (aliases XB 1st half, written at gate_ln)
  short*          WTB  = (short*)(ws + 4194304);               // [256][64][128] bf16 (aliases XB 2nd half)
  __hip_bfloat16* WCAT = (__hip_bfloat16*)(ws + 8388608);      // 2688x1024 bf16
  __hip_bfloat16* WOB  = (__hip_bfloat16*)(ws + 13893632);     // 1024x512  bf16
  __hip_bfloat16* CBUFH = (__hip_bfloat16*)(ws + 14942208);    // 4096x2688 bf16
  __hip_bfloat16* QH   = (__hip_bfloat16*)(ws + 58982400);     // 4096x512 bf16
  __hip_bfloat16* KH   = (__hip_bfloat16*)(ws + 67371008);     // 4096x512 bf16
  __hip_bfloat16* VM   = (__hip_bfloat16*)(ws + 75759616);     // 4096x512 bf16
  __hip_bfloat16* VG   = (__hip_bfloat16*)(ws + 84148224);     // 4096x512 bf16
  float* AL   = (float*)(ws + 92536832);                       // 4096x4
  float* BE   = (float*)(ws + 92602368);
  __hip_bfloat16* OBUF = (__hip_bfloat16*)(ws + 92667904);     // 4096x512 bf16 (written by scan_output)
  short* TRB  = (short*)(ws + 92667904);                       // [256][128][128] bf16 (aliases OBUF; dead before scan_output)
  short* PHB  = (short*)(ws + 105250816);                      // [256][64][64] bf16
  short* ZB   = (short*)(ws + 107347968);                      // [256][64][128] bf16
  float* GV   = (float*)(ws + 111542272);                      // [256][64]
  short* SALL = (short*)(ws + 115868672);                      // [256][128][128] bf16 chunk-start states
  float* ABF  = (float*)(ws + 124257280);                      // [4096][8] f32 alpha/beta logits
  float* BF   = (float*)(ws + 124388352);                      // [256][128][128] f32 (fresh region; no aliasing)

  cast_all_kernel<<<7296, 256, 0, stream>>>(x, Wo, Wq, Wk, Wv, Wg, Wa, Wb, XB, WOB, WCAT);

  gemm_bt_kernel<__hip_bfloat16><<<dim3(32, 21), 256, 0, stream>>>(
      XB, WCAT, CBUFH, BLQ, NPROJ, KPROJ, ABF, 2560);

  conv_act_kernel<<<512, 256, 0, stream>>>(CBUFH, ABF, qcw, qcb, kcw, kcb, vcw, vcb,
                                           QH, KH, VM, VG, AL, BE);

  scan_phaseA_kernel<<<256, 512, 0, stream>>>(QH, KH, VM, AL, BE,
                                              WTB, ZB, PHB, GV, TRB, BF);

  scan_state_kernel<<<64, 256, 0, stream>>>(TRB, BF, st0, SALL, out + 4194304);

  scan_output_kernel<<<256, 512, 0, stream>>>(QH, WTB, (const __hip_bfloat16*)ZB,
                                              PHB, GV, SALL, OBUF);

  gate_ln_kernel<<<BLQ, 256, 0, stream>>>(OBUF, VG, CBUFH, lnw, lnb, LNO);

  gemm_bt_kernel<float><<<dim3(32, 8), 256, 0, stream>>>(
      LNO, WOB, out, BLQ, DMQ, TOTQ, nullptr, 0);
}